// Round 10
// baseline (1246.036 us; speedup 1.0000x reference)
//
#include <hip/hip_runtime.h>
#include <math.h>

#define B 32
#define L 2048
#define DIN 5
#define DOUT 5
#define H 256
#define NST 32
#define NLAYERS 4
#define NRES 3
#define CHUNK 128
#define NCH 16            // L / CHUNK
#define LSEQ (B*H*L)      // 16777216

typedef __attribute__((ext_vector_type(8))) _Float16 half8;
typedef __attribute__((ext_vector_type(4))) float f32x4;

__device__ __forceinline__ float gelu_exact(float v) {
    return 0.5f * v * (1.0f + erff(v * 0.7071067811865475f));
}
#define SWZ(r) ((((r) ^ ((r) >> 2)) & 3))

// ---------------- encoder weight pack ----------------
__global__ void k_wenc(const float* __restrict__ ew, _Float16* __restrict__ wenc) {
    int idx = blockIdx.x*256 + threadIdx.x;
    if (idx >= 256*96) return;
    int o = idx / 96, kk = idx % 96;
    int ci = kk >> 4, k = kk & 15;
    float v = (ci < DIN && k < 15) ? ew[(o*DIN + ci)*15 + k] : 0.f;
    wenc[idx] = (_Float16)v;
}

// ---------------- MFMA encoder conv K=15 Cin=5 ----------------
__global__ __launch_bounds__(256) void k_enc(const float* __restrict__ x,
        const _Float16* __restrict__ wenc, const float* __restrict__ bias,
        _Float16* __restrict__ out) {
    __shared__ _Float16 a_lds[3*128*32];
    __shared__ _Float16 b_lds[3*128*32];
    const int tid = threadIdx.x;
    const int mbase = blockIdx.x * 128;
    const int oh = blockIdx.y;
    const int b = mbase >> 11;
    const int lbase = mbase & 2047;
    const int lane = tid & 63;
    const int w = tid >> 6;
    const int wm = (w >> 1) * 64, wn = (w & 1) * 64;
    const int fr = lane & 15, kg = lane >> 4;

    #pragma unroll
    for (int i = 0; i < 6; ++i) {
        int g = i*256 + tid;
        int r = g / 12, rem = g % 12;
        int ks = rem >> 2, q = rem & 3;
        int kk0 = ks*32 + q*8;
        int ci = kk0 >> 4, k0 = kk0 & 15;
        half8 va;
        #pragma unroll
        for (int e = 0; e < 8; ++e) {
            int k = k0 + e;
            int l = lbase + r - 7 + k;
            float v = (ci < DIN && k < 15 && l >= 0 && l < L)
                        ? x[((size_t)(b*DIN + ci))*L + l] : 0.f;
            va[e] = (_Float16)v;
        }
        *(half8*)&a_lds[ks*4096 + r*32 + ((q ^ SWZ(r))*8)] = va;
        uint4 vb = *(const uint4*)&wenc[(size_t)(oh*128 + r)*96 + kk0];
        *(uint4*)&b_lds[ks*4096 + r*32 + ((q ^ SWZ(r))*8)] = vb;
    }
    __syncthreads();
    f32x4 acc[4][4];
    #pragma unroll
    for (int i = 0; i < 4; ++i)
        #pragma unroll
        for (int j = 0; j < 4; ++j)
            #pragma unroll
            for (int k = 0; k < 4; ++k) acc[i][j][k] = 0.f;
    #pragma unroll
    for (int ks = 0; ks < 3; ++ks) {
        half8 af[4], bfr[4];
        #pragma unroll
        for (int mf = 0; mf < 4; ++mf) {
            int ra = wm + mf*16 + fr;
            af[mf] = *(const half8*)&a_lds[ks*4096 + ra*32 + ((kg ^ SWZ(ra))*8)];
        }
        #pragma unroll
        for (int nf = 0; nf < 4; ++nf) {
            int rb = wn + nf*16 + fr;
            bfr[nf] = *(const half8*)&b_lds[ks*4096 + rb*32 + ((kg ^ SWZ(rb))*8)];
        }
        #pragma unroll
        for (int mf = 0; mf < 4; ++mf)
            #pragma unroll
            for (int nf = 0; nf < 4; ++nf)
                acc[mf][nf] = __builtin_amdgcn_mfma_f32_16x16x32_f16(af[mf], bfr[nf], acc[mf][nf], 0, 0, 0);
    }
    #pragma unroll
    for (int nf = 0; nf < 4; ++nf) {
        int o = oh*128 + wn + nf*16 + fr;
        float bo = bias[o];
        #pragma unroll
        for (int mf = 0; mf < 4; ++mf)
            #pragma unroll
            for (int rg = 0; rg < 4; ++rg) {
                size_t m = (size_t)mbase + wm + mf*16 + kg*4 + rg;
                out[m*256 + o] = (_Float16)(acc[mf][nf][rg] + bo);
            }
    }
}

// ---------------- res weight pack ----------------
__global__ void k_wpack(const float* __restrict__ w1, const float* __restrict__ w2,
                        _Float16* __restrict__ wpk) {
    int idx = blockIdx.x*256 + threadIdx.x;
    if (idx >= NRES*2*3*65536) return;
    int ci = idx & 255;
    int o  = (idx >> 8) & 255;
    int k  = (idx >> 16) % 3;
    int cv = idx / (3*65536);
    const float* src = (cv & 1) ? w2 : w1;
    wpk[idx] = (_Float16)src[(((cv>>1)*H + o)*H + ci)*3 + k];
}

// ---------------- transpose fp16 chl -> fp16 chm ----------------
__global__ __launch_bounds__(256) void k_t_cf16(const _Float16* __restrict__ in,
        _Float16* __restrict__ out) {
    __shared__ float t[64][65];
    int tid = threadIdx.x;
    int l0 = blockIdx.x*64, c0 = blockIdx.y*64, b = blockIdx.z;
    #pragma unroll
    for (int i = 0; i < 16; ++i) {
        int idx = i*256 + tid;
        int l = idx >> 6, c = idx & 63;
        t[c][l] = (float)in[((size_t)b*L + l0 + l)*256 + c0 + c];
    }
    __syncthreads();
    #pragma unroll
    for (int i = 0; i < 16; ++i) {
        int idx = i*256 + tid;
        int c = idx >> 6, l = idx & 63;
        out[((size_t)(b*H + c0 + c))*L + l0 + l] = (_Float16)t[c][l];
    }
}

// ---------------- transpose fp16 chm -> fp16 chl ----------------
__global__ __launch_bounds__(256) void k_t16(const _Float16* __restrict__ in,
                                             _Float16* __restrict__ out) {
    __shared__ float t[64][65];
    int tid = threadIdx.x;
    int l0 = blockIdx.x*64, c0 = blockIdx.y*64, b = blockIdx.z;
    #pragma unroll
    for (int i = 0; i < 16; ++i) {
        int idx = i*256 + tid;
        int c = idx >> 6, l = idx & 63;
        t[c][l] = (float)in[((size_t)(b*H + c0 + c))*L + l0 + l];
    }
    __syncthreads();
    #pragma unroll
    for (int i = 0; i < 16; ++i) {
        int idx = i*256 + tid;
        int l = idx >> 6, c = idx & 63;
        out[((size_t)b*L + l0 + l)*256 + c0 + c] = (_Float16)t[c][l];
    }
}

// ---------------- MFMA residual conv K=3: full-N tile 128m x 256o, coalesced epilogue ----------------
template<bool RESID>
__global__ __launch_bounds__(256, 2) void k_cv3(const _Float16* __restrict__ xin,
        const _Float16* __restrict__ wpk, const float* __restrict__ bias,
        const _Float16* __restrict__ resid, _Float16* __restrict__ out) {
    __shared__ _Float16 a_lds[128*32];
    __shared__ _Float16 b_lds[256*32];
    __shared__ float    ep[32*256];
    const int tid = threadIdx.x;
    const int mbase = blockIdx.x * 128;
    const int lane = tid & 63;
    const int w = tid >> 6;
    const int wm = (w >> 1) * 64, wo = (w & 1) * 128;
    const int fr = lane & 15, kg = lane >> 4;

    const int r0s = tid >> 2, q0 = tid & 3;
    const int sq = SWZ(r0s);
    const int awA0 = r0s*32 + ((q0 ^ sq) * 8);
    const int awA1 = (64 + r0s)*32 + ((q0 ^ SWZ(64 + r0s)) * 8);

    f32x4 acc[4][8];
    #pragma unroll
    for (int i = 0; i < 4; ++i)
        #pragma unroll
        for (int j = 0; j < 8; ++j)
            #pragma unroll
            for (int k = 0; k < 4; ++k) acc[i][j][k] = 0.f;

    uint4 pa0, pa1, pb[4];
    auto loadstep = [&](int kk, uint4& a0, uint4& a1, uint4 (&bb)[4]) {
        const int koff = kk >> 3, cic = kk & 7;
        const int cb = cic*32 + q0*8;
        {
            int m = mbase + r0s;
            int ll = (m & (L-1)) + koff - 1;
            a0 = (ll >= 0 && ll < L) ? *(const uint4*)&xin[((size_t)(m + koff - 1))*256 + cb]
                                     : make_uint4(0,0,0,0);
            int m1 = mbase + 64 + r0s;
            int l1 = (m1 & (L-1)) + koff - 1;
            a1 = (l1 >= 0 && l1 < L) ? *(const uint4*)&xin[((size_t)(m1 + koff - 1))*256 + cb]
                                     : make_uint4(0,0,0,0);
        }
        #pragma unroll
        for (int u = 0; u < 4; ++u)
            bb[u] = *(const uint4*)&wpk[((size_t)(koff*256 + u*64 + r0s))*256 + cb];
    };
    loadstep(0, pa0, pa1, pb);
    for (int kk = 0; kk < 24; ++kk) {
        __syncthreads();
        *(uint4*)&a_lds[awA0] = pa0;
        *(uint4*)&a_lds[awA1] = pa1;
        #pragma unroll
        for (int u = 0; u < 4; ++u)
            *(uint4*)&b_lds[(u*64 + r0s)*32 + ((q0 ^ sq)*8)] = pb[u];
        uint4 na0 = make_uint4(0,0,0,0), na1 = na0, nb[4] = {na0, na0, na0, na0};
        if (kk < 23) loadstep(kk+1, na0, na1, nb);
        __syncthreads();
        half8 af[4];
        #pragma unroll
        for (int mf = 0; mf < 4; ++mf) {
            int ra = wm + mf*16 + fr;
            af[mf] = *(const half8*)&a_lds[ra*32 + ((kg ^ SWZ(ra)) * 8)];
        }
        #pragma unroll
        for (int nf = 0; nf < 8; ++nf) {
            int rb = wo + nf*16 + fr;
            half8 bfr = *(const half8*)&b_lds[rb*32 + ((kg ^ SWZ(rb)) * 8)];
            #pragma unroll
            for (int mf = 0; mf < 4; ++mf)
                acc[mf][nf] = __builtin_amdgcn_mfma_f32_16x16x32_f16(af[mf], bfr, acc[mf][nf], 0, 0, 0);
        }
        pa0 = na0; pa1 = na1;
        #pragma unroll
        for (int u = 0; u < 4; ++u) pb[u] = nb[u];
    }
    float bo8[8];
    #pragma unroll
    for (int nf = 0; nf < 8; ++nf) bo8[nf] = bias[wo + nf*16 + fr];
    const int er = tid >> 3, eoc = (tid & 7) * 32;
    #pragma unroll
    for (int mf = 0; mf < 4; ++mf) {
        __syncthreads();
        #pragma unroll
        for (int nf = 0; nf < 8; ++nf) {
            int o = wo + nf*16 + fr;
            int srb = (w >> 1)*16 + kg*4;
            #pragma unroll
            for (int rg = 0; rg < 4; ++rg)
                ep[(srb + rg)*256 + o] = acc[mf][nf][rg] + bo8[nf];
        }
        __syncthreads();
        size_t m = (size_t)mbase + mf*16 + (er < 16 ? er : 48 + er);
        #pragma unroll
        for (int u = 0; u < 4; ++u) {
            float4 v0 = *(float4*)&ep[er*256 + eoc + u*8];
            float4 v1 = *(float4*)&ep[er*256 + eoc + u*8 + 4];
            float vv[8] = {v0.x, v0.y, v0.z, v0.w, v1.x, v1.y, v1.z, v1.w};
            if (RESID) {
                half8 rv = *(const half8*)&resid[m*256 + eoc + u*8];
                #pragma unroll
                for (int e = 0; e < 8; ++e) vv[e] += (float)rv[e];
            }
            half8 hv;
            #pragma unroll
            for (int e = 0; e < 8; ++e) hv[e] = (_Float16)fmaxf(vv[e], 0.f);
            *(half8*)&out[m*256 + eoc + u*8] = hv;
        }
    }
}

// ---------------- DSS: per-(h,n) pole z and z^CHUNK ----------------
__global__ void k_zw(const float* __restrict__ log_dt, const float* __restrict__ lam_re,
                     const float* __restrict__ lam_im, float4* __restrict__ zwbuf, int layer) {
    int idx = blockIdx.x*256 + threadIdx.x;
    if (idx >= H*NST) return;
    int hh = idx / NST, n = idx % NST;
    float dt = expf(log_dt[layer*H + hh]);
    float a  = dt * lam_re[layer*NST + n];
    float bi = dt * lam_im[layer*NST + n];
    float er = expf(a);
    float zre = er * cosf(bi), zim = er * sinf(bi);
    float eC = expf(a * (float)CHUNK);
    float bC = bi * (float)CHUNK;
    float zcre = eC * cosf(bC), zcim = eC * sinf(bC);
    zwbuf[idx] = make_float4(zre, zim, zcre, zcim);
}

// ---------------- Z-power matrix zp[h][t][j] fp16 (t = dn*2+c) ----------------
__global__ __launch_bounds__(128) void k_wzp(const float4* __restrict__ zw,
        _Float16* __restrict__ zp) {
    int hh = blockIdx.x;
    int t = threadIdx.x;
    int dn = t >> 1, c = t & 1, dir = dn >> 5, n = dn & 31;
    float4 z4 = zw[hh*NST + n];
    float zre = z4.x, zim = z4.y;
    _Float16* dst = &zp[(size_t)hh*16384 + t*128];
    float cr = 1.f, ci = 0.f;
    for (int p = 0; p < 128; ++p) {
        float val = c ? ci : cr;
        dst[dir ? p : (127 - p)] = (_Float16)val;
        float nr = cr*zre - ci*zim;
        float ni = cr*zim + ci*zre;
        cr = nr; ci = ni;
    }
}

// ---------------- W_big[h][t][256] fp16 ----------------
__global__ __launch_bounds__(128) void k_wkern(const float* __restrict__ log_dt,
        const float* __restrict__ lam_re, const float* __restrict__ lam_im,
        const float* __restrict__ W_re, const float* __restrict__ W_im,
        _Float16* __restrict__ wbig, int layer) {
    __shared__ float kf[128], kb[128];
    __shared__ float E[128*129];
    const int hh = blockIdx.x;
    const int t = threadIdx.x;
    float dt = expf(log_dt[layer*H + hh]);
    float skf = 0.f, skb = 0.f;
    for (int n = 0; n < 32; ++n) {
        float a  = dt * lam_re[layer*NST + n];
        float bi = dt * lam_im[layer*NST + n];
        float wfr = W_re[((layer*2+0)*H + hh)*NST + n];
        float wfi = W_im[((layer*2+0)*H + hh)*NST + n];
        float wbr = W_re[((layer*2+1)*H + hh)*NST + n];
        float wbi = W_im[((layer*2+1)*H + hh)*NST + n];
        float e0 = expf(a*t), s0, c0; sincosf(bi*t, &s0, &c0);
        float zr0 = e0*c0, zi0 = e0*s0;
        skf = fmaf(wfr, zr0, skf) - wfi*zi0;
        skb = fmaf(wbr, zr0, skb) - wbi*zi0;
        float e1 = expf(a*(t+1)), s1, c1; sincosf(bi*(t+1), &s1, &c1);
        float zr1 = e1*c1, zi1 = e1*s1;
        E[t*129 + n]      = wfr*zr1 - wfi*zi1;
        E[t*129 + 32 + n] = -(wfr*zi1 + wfi*zr1);
        float e2 = expf(a*(127-t)), s2, c2; sincosf(bi*(127-t), &s2, &c2);
        float zr2 = e2*c2, zi2 = e2*s2;
        E[t*129 + 64 + n] = wbr*zr2 - wbi*zi2;
        E[t*129 + 96 + n] = -(wbr*zi2 + wbi*zr2);
    }
    kf[t] = skf; kb[t] = skb;
    __syncthreads();
    _Float16* dst = &wbig[(size_t)hh*32768];
    for (int idx = t; idx < 128*256; idx += 128) {
        int tt = idx >> 8, k = idx & 255;
        float v;
        if (k < 128) v = (k <= tt) ? kf[tt - k] : kb[k - tt - 1];
        else         v = E[tt*129 + (k - 128)];
        dst[idx] = (_Float16)v;
    }
}

// ---------------- GLU weight pack ----------------
__global__ void k_wtg16(const float* __restrict__ gw, _Float16* __restrict__ wg, int layer) {
    int idx = blockIdx.x*256 + threadIdx.x;
    if (idx >= 512*256) return;
    wg[idx] = (_Float16)gw[layer*512*256 + idx];
}

// ---------------- decoder weight pack ----------------
__global__ void k_wdec(const float* __restrict__ dw, _Float16* __restrict__ wdk) {
    int idx = blockIdx.x*256 + threadIdx.x;
    if (idx >= 15*16*256) return;
    int cfull = idx & 255;
    int o = (idx >> 8) & 15;
    int k = idx >> 12;
    float v = (o < DOUT) ? dw[(o*H + cfull)*15 + k] : 0.f;
    int cc = cfull >> 5, cl = cfull & 31;
    int cq = cl >> 3, cb = cl & 7;
    wdk[cc*7680 + (k*16 + o)*32 + ((cq ^ SWZ(o))*8) + cb] = (_Float16)v;
}

// ---------------- FUSED DSS v2: single-stage zp, K=64 wbig dbuf panels (~14 barriers) ----------------
// grid (H, 8); LDS: xbuf 16KB | zsb 32KB (zp -> S f32 -> wbig dbuf) | bbuf 16KB (stp -> yst)
__global__ __launch_bounds__(256) void k_dss(const _Float16* __restrict__ hm16,
        const _Float16* __restrict__ zp, const _Float16* __restrict__ wbig,
        const float4* __restrict__ zwb, const float* __restrict__ Dv,
        _Float16* __restrict__ y16, int layer) {
    __shared__ _Float16 xbuf[4*64*32];
    __shared__ _Float16 zsb[16384];
    __shared__ _Float16 bbuf[4*64*32];

    const int tid = threadIdx.x;
    const int hh = blockIdx.x;
    const int b0 = blockIdx.y * 4;
    const int lane = tid & 63;
    const int w = tid >> 6;
    const int wn = w * 32;
    const int fr = lane & 15, kg = lane >> 4;

    // stage x (64 rows x 128 j)
    #pragma unroll
    for (int i = 0; i < 4; ++i) {
        int g = i*256 + tid;
        int m = g >> 4, gi = g & 15;
        int kc = gi >> 2, q = gi & 3;
        uint4 v = *(const uint4*)&hm16[((size_t)((b0 + (m>>4))*H + hh))*L
                                       + (m&15)*128 + kc*32 + q*8];
        *(uint4*)&xbuf[kc*2048 + m*32 + ((q ^ SWZ(m))*8)] = v;
    }
    // stage zp fully (128 t x 128 j, panel-major)
    const _Float16* zb = &zp[(size_t)hh*16384];
    #pragma unroll
    for (int i = 0; i < 8; ++i) {
        int g = i*256 + tid;
        int kc = g >> 9, rem = g & 511;
        int t = rem >> 2, q = rem & 3;
        uint4 v = *(const uint4*)&zb[t*128 + kc*32 + q*8];
        *(uint4*)&zsb[kc*4096 + t*32 + ((q ^ SWZ(t))*8)] = v;
    }
    __syncthreads();

    // ---- phase 1: S = x . zp^T (no inner barriers) ----
    f32x4 acc1[4][2];
    #pragma unroll
    for (int i = 0; i < 4; ++i)
        #pragma unroll
        for (int j = 0; j < 2; ++j)
            #pragma unroll
            for (int k = 0; k < 4; ++k) acc1[i][j][k] = 0.f;
    #pragma unroll
    for (int kc = 0; kc < 4; ++kc) {
        half8 af[4], bf2[2];
        #pragma unroll
        for (int mf = 0; mf < 4; ++mf) {
            int ra = mf*16 + fr;
            af[mf] = *(const half8*)&xbuf[kc*2048 + ra*32 + ((kg ^ SWZ(ra))*8)];
        }
        #pragma unroll
        for (int nf = 0; nf < 2; ++nf) {
            int rb = wn + nf*16 + fr;
            bf2[nf] = *(const half8*)&zsb[kc*4096 + rb*32 + ((kg ^ SWZ(rb))*8)];
        }
        #pragma unroll
        for (int mf = 0; mf < 4; ++mf)
            #pragma unroll
            for (int nf = 0; nf < 2; ++nf)
                acc1[mf][nf] = __builtin_amdgcn_mfma_f32_16x16x32_f16(af[mf], bf2[nf], acc1[mf][nf], 0, 0, 0);
    }
    __syncthreads();                // zp reads done -> reuse zsb for S (f32)
    float* sfp = (float*)zsb;
    #pragma unroll
    for (int mf = 0; mf < 4; ++mf)
        #pragma unroll
        for (int nf = 0; nf < 2; ++nf)
            #pragma unroll
            for (int rg = 0; rg < 4; ++rg)
                sfp[(mf*16 + kg*4 + rg)*128 + wn + nf*16 + fr] = acc1[mf][nf][rg];
    __syncthreads();

    // ---- phase 2: in-LDS cross-chunk scan (f32) -> stp fp16 in bbuf ----
    {
        int b_loc = tid >> 6, dn = tid & 63;
        int dir = dn >> 5, n = dn & 31;
        float4 z4 = zwb[hh*NST + n];
        float zcre = z4.z, zcim = z4.w;
        int q1 = n >> 3, e1 = n & 7;
        float pre = 0.f, pim = 0.f;
        for (int s = 0; s < NCH; ++s) {
            int ch = dir ? (NCH - 1 - s) : s;
            int m = b_loc*16 + ch;
            bbuf[(dir*2 + 0)*2048 + m*32 + ((q1 ^ SWZ(m))*8) + e1] = (_Float16)pre;
            bbuf[(dir*2 + 1)*2048 + m*32 + ((q1 ^ SWZ(m))*8) + e1] = (_Float16)pim;
            float cre = sfp[m*128 + dn*2];
            float cim = sfp[m*128 + dn*2 + 1];
            float nre = fmaf(zcre, pre, fmaf(-zcim, pim, cre));
            float nim = fmaf(zcre, pim, fmaf(zcim, pre, cim));
            pre = nre; pim = nim;
        }
    }
    __syncthreads();

    // ---- phase 3: y = [x | stp] . wbig^T, K=64 dbuf panels in zsb ----
    f32x4 acc3[4][2];
    #pragma unroll
    for (int i = 0; i < 4; ++i)
        #pragma unroll
        for (int j = 0; j < 2; ++j)
            #pragma unroll
            for (int k = 0; k < 4; ++k) acc3[i][j][k] = 0.f;
    const _Float16* wb = &wbig[(size_t)hh*32768];
    uint4 wr[4];
    auto loadW = [&](int p, uint4 (&r)[4]) {
        #pragma unroll
        for (int i = 0; i < 4; ++i) {
            int g = i*256 + tid;
            int sub = g >> 9, rem = g & 511;
            int t = rem >> 2, q = rem & 3;
            r[i] = *(const uint4*)&wb[t*256 + p*64 + sub*32 + q*8];
        }
    };
    loadW(0, wr);
    for (int p = 0; p < 4; ++p) {
        __syncthreads();
        #pragma unroll
        for (int i = 0; i < 4; ++i) {
            int g = i*256 + tid;
            int sub = g >> 9, rem = g & 511;
            int t = rem >> 2, q = rem & 3;
            *(uint4*)&zsb[(p&1)*8192 + sub*4096 + t*32 + ((q ^ SWZ(t))*8)] = wr[i];
        }
        if (p < 3) loadW(p+1, wr);
        __syncthreads();
        #pragma unroll
        for (int sub = 0; sub < 2; ++sub) {
            int kcg = p*2 + sub;
            half8 af[4], bf2[2];
            #pragma unroll
            for (int mf = 0; mf < 4; ++mf) {
                int ra = mf*16 + fr;
                af[mf] = (kcg < 4)
                    ? *(const half8*)&xbuf[kcg*2048 + ra*32 + ((kg ^ SWZ(ra))*8)]
                    : *(const half8*)&bbuf[(kcg-4)*2048 + ra*32 + ((kg ^ SWZ(ra))*8)];
            }
            #pragma unroll
            for (int nf = 0; nf < 2; ++nf) {
                int rb = wn + nf*16 + fr;
                bf2[nf] = *(const half8*)&zsb[(p&1)*8192 + sub*4096 + rb*32 + ((kg ^ SWZ(rb))*8)];
            }
            #pragma unroll
            for (int mf = 0; mf < 4; ++mf)
                #pragma unroll
                for (int nf = 0; nf < 2; ++nf)
                    acc3[mf][nf] = __builtin_amdgcn_mfma_f32_16x16x32_f16(af[mf], bf2[nf], acc3[mf][nf], 0, 0, 0);
        }
    }
    __syncthreads();                // stp reads done -> reuse bbuf for yst
    float dv = Dv[layer*H + hh];
    _Float16* yst = bbuf;
    #pragma unroll
    for (int mf = 0; mf < 4; ++mf) {
        #pragma unroll
        for (int rg = 0; rg < 4; ++rg) {
            int m = mf*16 + kg*4 + rg;
            #pragma unroll
            for (int nf = 0; nf < 2; ++nf) {
                int t = wn + nf*16 + fr;
                float xv = (float)xbuf[(t>>5)*2048 + m*32 + ((((t&31)>>3) ^ SWZ(m))*8) + (t&7)];
                float v = acc3[mf][nf][rg] + dv * xv;
                yst[m*128 + t] = (_Float16)gelu_exact(v);
            }
        }
    }
    __syncthreads();
    {
        int r = tid >> 2, tc = (tid & 3) * 32;
        size_t gb = ((size_t)((b0 + (r>>4))*H + hh))*L + (r&15)*128;
        #pragma unroll
        for (int u = 0; u < 4; ++u)
            *(half8*)&y16[gb + tc + u*8] = *(half8*)&yst[r*128 + tc + u*8];
    }
}

// ---------------- FUSED GLU+LN: y16 chm -> GLU (both halves) -> +resid -> LN -> hm16 chm ----------------
// grid B*L/64 = 1024 blocks, 256 thr. Block = 64 rows (one b, 64 consecutive l), full 256 c.
template<bool SP>
__global__ __launch_bounds__(256, 2) void k_gluln(const _Float16* __restrict__ y16,
        const _Float16* __restrict__ wg, const float* __restrict__ bias,
        _Float16* __restrict__ hm, const float* __restrict__ g, const float* __restrict__ bb,
        const int* __restrict__ xs, const float* __restrict__ emb,
        float* __restrict__ outseq) {
    __shared__ _Float16 a_lds[64*32];      // 4KB
    __shared__ _Float16 b_lds[512*32];     // 32KB
    __shared__ _Float16 hmbuf[256*72];     // 36KB (pad 72 for alignment/banks)
    __shared__ float psum[256], pss[256], mur[64], rsr[64];

    const int tid = threadIdx.x;
    const int mbase = blockIdx.x * 64;
    const int b = mbase >> 11;
    const int l0 = mbase & 2047;
    const int lane = tid & 63;
    const int w = tid >> 6;
    const int fr = lane & 15, kg = lane >> 4;
    const int ac = tid >> 3, al8 = (tid & 7) * 8;   // A staging: c_local, l-offset

    f32x4 accg[4][4], accs[4][4];
    #pragma unroll
    for (int i = 0; i < 4; ++i)
        #pragma unroll
        for (int j = 0; j < 4; ++j)
            #pragma unroll
            for (int k = 0; k < 4; ++k) { accg[i][j][k] = 0.f; accs[i][j][k] = 0.f; }

    uint4 aR, bR[8];
    auto loadA = [&](int kc) -> uint4 {
        return *(const uint4*)&y16[((size_t)(b*256 + kc*32 + ac))*2048 + l0 + al8];
    };
    auto loadB = [&](int kc, uint4 (&r)[8]) {
        #pragma unroll
        for (int i = 0; i < 8; ++i) {
            int gq = i*256 + tid;
            int row = gq >> 2, q = gq & 3;
            r[i] = *(const uint4*)&wg[(size_t)row*256 + kc*32 + q*8];
        }
    };
    aR = loadA(0); loadB(0, bR);
    for (int kc = 0; kc < 8; ++kc) {
        __syncthreads();
        {   // scatter-transpose A panel into LDS
            union { uint4 u; half8 h; } av; av.u = aR;
            int q = ac >> 3, e0 = ac & 7;
            #pragma unroll
            for (int e = 0; e < 8; ++e) {
                int l = al8 + e;
                a_lds[l*32 + ((q ^ SWZ(l))*8) + e0] = av.h[e];
            }
        }
        #pragma unroll
        for (int i = 0; i < 8; ++i) {
            int gq = i*256 + tid;
            int row = gq >> 2, q = gq & 3;
            *(uint4*)&b_lds[row*32 + ((q ^ SWZ(row))*8)] = bR[i];
        }
        if (kc < 7) { aR = loadA(kc+1); loadB(kc+1, bR); }
        __syncthreads();
        half8 af[4];
        #pragma unroll
        for (int mf = 0; mf < 4; ++mf) {
            int ra = mf*16 + fr;
            af[mf] = *(const half8*)&a_lds[ra*32 + ((kg ^ SWZ(ra))*8)];
        }
        #pragma unroll
        for (int nf = 0; nf < 4; ++nf) {
            int rg_ = w*64 + nf*16 + fr;
            half8 bg = *(const half8*)&b_lds[rg_*32 + ((kg ^ SWZ(rg_))*8)];
            int rs_ = 256 + rg_;
            half8 bs = *(const half8*)&b_lds[rs_*32 + ((kg ^ SWZ(rs_))*8)];
            #pragma unroll
            for (int mf = 0; mf < 4; ++mf) {
                accg[mf][nf] = __builtin_amdgcn_mfma_f32_16x16x32_f16(af[mf], bg, accg[mf][nf], 0, 0, 0);
                accs[mf][nf] = __builtin_amdgcn_mfma_f32_16x16x32_f16(af[mf], bs, accs[mf][nf], 0, 0, 0);
            }
        }
    }
    // stage residual hm tile (256 c x 64 m, coalesced)
    __syncthreads();
    #pragma unroll
    for (int i = 0; i < 8; ++i) {
        int gq = i*256 + tid;
        int c = gq >> 3, m8 = (gq & 7) * 8;
        half8 v = *(const half8*)&hm[((size_t)(b*256 + c))*2048 + l0 + m8];
        *(half8*)&hmbuf[c*72 + m8] = v;
    }
    // per-lane c constants & params
    int cl_[4];
    float b0v[4], b1v[4], gv[4], bbv[4], ev[4];
    int sp = SP ? xs[b] : 0;
    #pragma unroll
    for (int nf = 0; nf < 4; ++nf) {
        int c = w*64 + nf*16 + fr;
        cl_[nf] = c;
        b0v[nf] = bias[c]; b1v[nf] = bias[256 + c];
        gv[nf] = g[c]; bbv[nf] = bb[c];
        ev[nf] = SP ? emb[sp*H + c] : 0.f;
    }
    __syncthreads();
    // v = glu(z) + h; partial sums per m over this wave's 64-c slice
    float sum_m[16], ss_m[16];
    #pragma unroll
    for (int mf = 0; mf < 4; ++mf) {
        #pragma unroll
        for (int rg = 0; rg < 4; ++rg) {
            int m = mf*16 + kg*4 + rg;
            float s = 0.f, q2 = 0.f;
            #pragma unroll
            for (int nf = 0; nf < 4; ++nf) {
                float gg = accg[mf][nf][rg] + b0v[nf];
                float sg = accs[mf][nf][rg] + b1v[nf];
                float z = gg / (1.f + expf(-sg));
                float v = z + (float)hmbuf[cl_[nf]*72 + m];
                accg[mf][nf][rg] = v;
                s += v; q2 = fmaf(v, v, q2);
            }
            sum_m[mf*4 + rg] = s; ss_m[mf*4 + rg] = q2;
        }
    }
    #pragma unroll
    for (int d = 1; d < 16; d <<= 1) {
        #pragma unroll
        for (int mi = 0; mi < 16; ++mi) {
            sum_m[mi] += __shfl_xor(sum_m[mi], d);
            ss_m[mi]  += __shfl_xor(ss_m[mi], d);
        }
    }
    if (fr == 0) {
        #pragma unroll
        for (int mf = 0; mf < 4; ++mf)
            #pragma unroll
            for (int rg = 0; rg < 4; ++rg) {
                int m = mf*16 + kg*4 + rg;
                psum[m*4 + w] = sum_m[mf*4 + rg];
                pss[m*4 + w]  = ss_m[mf*4 + rg];
            }
    }
    __syncthreads();
    if (tid < 64) {
        float s = psum[tid*4] + psum[tid*4+1] + psum[tid*4+2] + psum[tid*4+3];
        float q2 = pss[tid*4] + pss[tid*4+1] + pss[tid*4+2] + pss[tid*4+3];
        float mu = s * (1.f/256.f);
        float var = q2 * (1.f/256.f) - mu*mu;
        mur[tid] = mu;
        rsr[tid] = rsqrtf(var + 1e-5f);
    }
    __syncthreads();
    #pragma unroll
    for (int mf = 0; mf < 4; ++mf) {
        #pragma unroll
        for (int rg = 0; rg < 4; ++rg) {
            int m = mf*16 + kg*4 + rg;
            float mu = mur[m], rs = rsr[m];
            #pragma unroll
            for (int nf = 0; nf < 4; ++nf) {
                float val = (accg[mf][nf][rg] - mu) * rs * gv[nf] + bbv[nf] + ev[nf];
                hmbuf[cl_[nf]*72 + m] = (_Float16)val;
            }
        }
    }
    __syncthreads();
    // coalesced write-back
    #pragma unroll
    for (int i = 0; i < 8; ++i) {
        int gq = i*256 + tid;
        int c = gq >> 3, m8 = (gq & 7) * 8;
        half8 hv = *(const half8*)&hmbuf[c*72 + m8];
        *(half8*)&hm[((size_t)(b*256 + c))*2048 + l0 + m8] = hv;
        if (SP) {
            float4 f0 = make_float4((float)hv[0], (float)hv[1], (float)hv[2], (float)hv[3]);
            float4 f1 = make_float4((float)hv[4], (float)hv[5], (float)hv[6], (float)hv[7]);
            *(float4*)&outseq[((size_t)(b*256 + c))*2048 + l0 + m8] = f0;
            *(float4*)&outseq[((size_t)(b*256 + c))*2048 + l0 + m8 + 4] = f1;
        }
    }
}

// ---------------- MFMA decoder conv K=15 ----------------
__global__ __launch_bounds__(128) void k_dec(const _Float16* __restrict__ ht,
        const _Float16* __restrict__ wdk, const float* __restrict__ bias,
        float* __restrict__ outdec) {
    __shared__ _Float16 a_lds[160*32];
    __shared__ _Float16 b_lds[15*16*32];
    const int tid = threadIdx.x;
    const int mbase = blockIdx.x * 128;
    const int b = mbase >> 11;
    const int lbase = mbase & 2047;
    const int lane = tid & 63;
    const int w = tid >> 6;
    const int fr = lane & 15, kg = lane >> 4;
    const int rs = tid >> 2, q0 = tid & 3;
    f32x4 acc[4];
    #pragma unroll
    for (int i = 0; i < 4; ++i)
        #pragma unroll
        for (int k = 0; k < 4; ++k) acc[i][k] = 0.f;
    for (int cc = 0; cc < 8; ++cc) {
        __syncthreads();
        #pragma unroll
        for (int ps = 0; ps < 5; ++ps) {
            int r = ps*32 + rs;
            if (r < 142) {
                int l = lbase - 7 + r;
                uint4 v = (l >= 0 && l < L) ? *(const uint4*)&ht[((size_t)(b*L + l))*256 + cc*32 + q0*8]
                                            : make_uint4(0,0,0,0);
                *(uint4*)&a_lds[r*32 + ((q0 ^ SWZ(r))*8)] = v;
            }
        }
        for (int jj = tid; jj < 960; jj += 128)
            *(uint4*)&b_lds[jj*8] = *(const uint4*)&wdk[cc*7680 + jj*8];
        __syncthreads();
        #pragma unroll
        for (int k = 0; k < 15; ++k) {
            half8 bfr = *(const half8*)&b_lds[(k*16 + fr)*32 + ((kg ^ SWZ(fr))*8)];
            #pragma unroll
            for (int mf = 0; mf < 4; ++mf) {
                int ra = w*64 + mf*16 + fr + k;
                half8 af = *(const half8*)&a_lds[ra*32 + ((kg ^ SWZ(ra))*8)];
                acc[mf] = __builtin_amdgcn_mfma_f32_16x16x32_f16(af, bfr, acc[mf], 0, 0, 0);
            }
        }
    }
    if (fr < DOUT) {
        float bo = bias[fr];
        #pragma unroll
        for (int mf = 0; mf < 4; ++mf)
            #pragma unroll
            for (int rg = 0; rg < 4; ++rg) {
                int m = mbase + w*64 + mf*16 + kg*4 + rg;
                outdec[((size_t)(b*DOUT + fr))*L + (m & 2047)] = acc[mf][rg] + bo;
            }
    }
}

// ---------------- mean over L (fp16 input) ----------------
__global__ __launch_bounds__(256) void k_agg(const _Float16* __restrict__ h, float* __restrict__ agg) {
    __shared__ float red[256];
    int bc = blockIdx.x;
    int tid = threadIdx.x;
    half8 v = *(const half8*)&h[(size_t)bc*L + tid*8];
    float s = 0.f;
    #pragma unroll
    for (int e = 0; e < 8; ++e) s += (float)v[e];
    red[tid] = s; __syncthreads();
    for (int k = 128; k > 0; k >>= 1) {
        if (tid < k) red[tid] += red[tid+k];
        __syncthreads();
    }
    if (tid == 0) agg[bc] = red[0] * (1.f/(float)L);
}

// ---------------- regression MLP ----------------
__global__ __launch_bounds__(128) void k_mlp(const float* __restrict__ agg,
        const float* __restrict__ w1, const float* __restrict__ b1,
        const float* __restrict__ w2, const float* __restrict__ b2,
        const float* __restrict__ w3, const float* __restrict__ b3,
        const float* __restrict__ w4, const float* __restrict__ b4,
        float* __restrict__ outreg) {
    __shared__ float a0[256], r1[128], r2[64], r3[32];
    int b = blockIdx.x, tid = threadIdx.x;
    a0[tid] = agg[b*256 + tid];
    a0[tid+128] = agg[b*256 + tid + 128];
    __syncthreads();
    {
        float s = b1[tid];
        for (int k = 0; k < 256; ++k) s = fmaf(w1[tid*256+k], a0[k], s);
        r1[tid] = s > 0.f ? s : expm1f(s);
    }
    __syncthreads();
    if (tid < 64) {
        float s = b2[tid];
        for (int k = 0; k < 128; ++k) s = fmaf(w2[tid*128+k], r1[k], s);
        r2[tid] = s > 0.f ? s : expm1f(s);
    }
    __syncthreads();
    if (tid < 32) {
        float s = b3[tid];
        for (int k = 0; k < 64; ++k) s = fmaf(w3[tid*64+k], r2[k], s);
        r3[tid] = s > 0.f ? s : expm1f(s);
    }
    __syncthreads();
    if (tid == 0) {
        float s = b4[0];
        for (int k = 0; k < 32; ++k) s = fmaf(w4[k], r3[k], s);
        outreg[b] = s;
    }
}

extern "C" void kernel_launch(void* const* d_in, const int* in_sizes, int n_in,
                              void* d_out, int out_size, void* d_ws, size_t ws_size,
                              hipStream_t stream) {
    const float* x      = (const float*)d_in[0];
    const int*   xs     = (const int*)d_in[1];
    const float* enc_w  = (const float*)d_in[2];
    const float* enc_b  = (const float*)d_in[3];
    const float* res_w1 = (const float*)d_in[4];
    const float* res_b1 = (const float*)d_in[5];
    const float* res_w2 = (const float*)d_in[6];
    const float* res_b2 = (const float*)d_in[7];
    const float* log_dt = (const float*)d_in[8];
    const float* lam_re = (const float*)d_in[9];
    const float* lam_im = (const float*)d_in[10];
    const float* W_re   = (const float*)d_in[11];
    const float* W_im   = (const float*)d_in[12];
    const float* Dv     = (const float*)d_in[13];
    const float* glu_w  = (const float*)d_in[14];
    const float* glu_b  = (const float*)d_in[15];
    const float* ln_g   = (const float*)d_in[16];
    const float* ln_b   = (const float*)d_in[17];
    const float* dec_w  = (const float*)d_in[18];
    const float* dec_b  = (const float*)d_in[19];
    const float* sp_emb = (const float*)d_in[20];
    const float* h1_w = (const float*)d_in[21]; const float* h1_b = (const float*)d_in[22];
    const float* h2_w = (const float*)d_in[23]; const float* h2_b = (const float*)d_in[24];
    const float* h3_w = (const float*)d_in[25]; const float* h3_b = (const float*)d_in[26];
    const float* h4_w = (const float*)d_in[27]; const float* h4_b = (const float*)d_in[28];

    float* ws   = (float*)d_ws;
    _Float16* hm16 = (_Float16*)ws;                    // fp16 chm residual (persistent)
    float* t1   = ws + (size_t)LSEQ;
    float* t2   = ws + (size_t)2*LSEQ;
    // res-phase:
    _Float16* xb  = (_Float16*)t1;
    _Float16* xa  = (_Float16*)t1 + (size_t)LSEQ;
    _Float16* wpk = (_Float16*)t2;
    // DSS-phase:
    _Float16* wbig = (_Float16*)t1 + (size_t)LSEQ;     // 16MB (t1 upper)
    _Float16* zp   = wbig + (size_t)H*32768;           // 8MB
    _Float16* y16  = (_Float16*)t2;                    // fp16 chm y
    _Float16* dect = (_Float16*)t1;                    // decoder chl input
    // tail:
    float* tail = ws + (size_t)3*LSEQ;
    _Float16* wg  = (_Float16*)tail;
    float4* zwb = (float4*)(tail + 65536);
    float* aggb = tail + 65536 + 32768;
    _Float16* wdk = (_Float16*)(aggb + 8192);
    _Float16* wenc = wdk + 61440;

    float* outdec = (float*)d_out;
    float* outseq = outdec + B*DOUT*L;
    float* outreg = outseq + (size_t)LSEQ;

    // encoder
    k_wenc<<<96, 256, 0, stream>>>(enc_w, wenc);
    k_enc<<<dim3(B*L/128, 2), 256, 0, stream>>>(x, wenc, enc_b, xa);

    // residual stack
    k_wpack<<<(NRES*2*3*65536 + 255)/256, 256, 0, stream>>>(res_w1, res_w2, wpk);
    for (int r = 0; r < NRES; ++r) {
        k_cv3<false><<<B*L/128, 256, 0, stream>>>(
            xa, wpk + (size_t)(r*2+0)*3*65536, res_b1 + r*H, nullptr, xb);
        k_cv3<true><<<B*L/128, 256, 0, stream>>>(
            xb, wpk + (size_t)(r*2+1)*3*65536, res_b2 + r*H, xa, xa);
    }
    k_t_cf16<<<dim3(L/64, H/64, B), 256, 0, stream>>>(xa, hm16);

    // DSS blocks
    for (int i = 0; i < NLAYERS; ++i) {
        k_zw<<<(H*NST + 255)/256, 256, 0, stream>>>(log_dt, lam_re, lam_im, zwb, i);
        k_wzp<<<H, 128, 0, stream>>>(zwb, zp);
        k_wkern<<<H, 128, 0, stream>>>(log_dt, lam_re, lam_im, W_re, W_im, wbig, i);
        k_wtg16<<<(512*256 + 255)/256, 256, 0, stream>>>(glu_w, wg, i);
        k_dss<<<dim3(H, 8), 256, 0, stream>>>(hm16, zp, wbig, zwb, Dv, y16, i);
        if (i < NLAYERS - 1)
            k_gluln<false><<<B*L/64, 256, 0, stream>>>(y16, wg, glu_b + i*512, hm16,
                    ln_g + i*H, ln_b + i*H, nullptr, nullptr, nullptr);
        else
            k_gluln<true><<<B*L/64, 256, 0, stream>>>(y16, wg, glu_b + i*512, hm16,
                    ln_g + i*H, ln_b + i*H, xs, sp_emb, outseq);
    }

    // aggregate + regression head
    k_agg<<<B*H, 256, 0, stream>>>(hm16, aggb);
    k_mlp<<<B, 128, 0, stream>>>(aggb, h1_w, h1_b, h2_w, h2_b, h3_w, h3_b, h4_w, h4_b, outreg);
    // decoder
    k_t16<<<dim3(L/64, H/64, B), 256, 0, stream>>>(hm16, dect);
    k_wdec<<<(15*16*256 + 255)/256, 256, 0, stream>>>(dec_w, wdk);
    k_dec<<<B*L/128, 128, 0, stream>>>(dect, wdk, dec_b, outdec);
}

// Round 11
// 1211.358 us; speedup vs baseline: 1.0286x; 1.0286x over previous
//
#include <hip/hip_runtime.h>
#include <math.h>

#define B 32
#define L 2048
#define DIN 5
#define DOUT 5
#define H 256
#define NST 32
#define NLAYERS 4
#define NRES 3
#define CHUNK 128
#define NCH 16            // L / CHUNK
#define LSEQ (B*H*L)      // 16777216

typedef __attribute__((ext_vector_type(8))) _Float16 half8;
typedef __attribute__((ext_vector_type(4))) float f32x4;

__device__ __forceinline__ float gelu_exact(float v) {
    return 0.5f * v * (1.0f + erff(v * 0.7071067811865475f));
}
#define SWZ(r) ((((r) ^ ((r) >> 2)) & 3))
#define LDIDX(l, c) ((l)*281 + ((c)>>5)*35 + ((c)&31))

// ---------------- encoder weight pack ----------------
__global__ void k_wenc(const float* __restrict__ ew, _Float16* __restrict__ wenc) {
    int idx = blockIdx.x*256 + threadIdx.x;
    if (idx >= 256*96) return;
    int o = idx / 96, kk = idx % 96;
    int ci = kk >> 4, k = kk & 15;
    float v = (ci < DIN && k < 15) ? ew[(o*DIN + ci)*15 + k] : 0.f;
    wenc[idx] = (_Float16)v;
}

// ---------------- MFMA encoder conv K=15 Cin=5 ----------------
__global__ __launch_bounds__(256) void k_enc(const float* __restrict__ x,
        const _Float16* __restrict__ wenc, const float* __restrict__ bias,
        _Float16* __restrict__ out) {
    __shared__ _Float16 a_lds[3*128*32];
    __shared__ _Float16 b_lds[3*128*32];
    const int tid = threadIdx.x;
    const int mbase = blockIdx.x * 128;
    const int oh = blockIdx.y;
    const int b = mbase >> 11;
    const int lbase = mbase & 2047;
    const int lane = tid & 63;
    const int w = tid >> 6;
    const int wm = (w >> 1) * 64, wn = (w & 1) * 64;
    const int fr = lane & 15, kg = lane >> 4;

    #pragma unroll
    for (int i = 0; i < 6; ++i) {
        int g = i*256 + tid;
        int r = g / 12, rem = g % 12;
        int ks = rem >> 2, q = rem & 3;
        int kk0 = ks*32 + q*8;
        int ci = kk0 >> 4, k0 = kk0 & 15;
        half8 va;
        #pragma unroll
        for (int e = 0; e < 8; ++e) {
            int k = k0 + e;
            int l = lbase + r - 7 + k;
            float v = (ci < DIN && k < 15 && l >= 0 && l < L)
                        ? x[((size_t)(b*DIN + ci))*L + l] : 0.f;
            va[e] = (_Float16)v;
        }
        *(half8*)&a_lds[ks*4096 + r*32 + ((q ^ SWZ(r))*8)] = va;
        uint4 vb = *(const uint4*)&wenc[(size_t)(oh*128 + r)*96 + kk0];
        *(uint4*)&b_lds[ks*4096 + r*32 + ((q ^ SWZ(r))*8)] = vb;
    }
    __syncthreads();
    f32x4 acc[4][4];
    #pragma unroll
    for (int i = 0; i < 4; ++i)
        #pragma unroll
        for (int j = 0; j < 4; ++j)
            #pragma unroll
            for (int k = 0; k < 4; ++k) acc[i][j][k] = 0.f;
    #pragma unroll
    for (int ks = 0; ks < 3; ++ks) {
        half8 af[4], bfr[4];
        #pragma unroll
        for (int mf = 0; mf < 4; ++mf) {
            int ra = wm + mf*16 + fr;
            af[mf] = *(const half8*)&a_lds[ks*4096 + ra*32 + ((kg ^ SWZ(ra))*8)];
        }
        #pragma unroll
        for (int nf = 0; nf < 4; ++nf) {
            int rb = wn + nf*16 + fr;
            bfr[nf] = *(const half8*)&b_lds[ks*4096 + rb*32 + ((kg ^ SWZ(rb))*8)];
        }
        #pragma unroll
        for (int mf = 0; mf < 4; ++mf)
            #pragma unroll
            for (int nf = 0; nf < 4; ++nf)
                acc[mf][nf] = __builtin_amdgcn_mfma_f32_16x16x32_f16(af[mf], bfr[nf], acc[mf][nf], 0, 0, 0);
    }
    #pragma unroll
    for (int nf = 0; nf < 4; ++nf) {
        int o = oh*128 + wn + nf*16 + fr;
        float bo = bias[o];
        #pragma unroll
        for (int mf = 0; mf < 4; ++mf)
            #pragma unroll
            for (int rg = 0; rg < 4; ++rg) {
                size_t m = (size_t)mbase + wm + mf*16 + kg*4 + rg;
                out[m*256 + o] = (_Float16)(acc[mf][nf][rg] + bo);
            }
    }
}

// ---------------- res weight pack ----------------
__global__ void k_wpack(const float* __restrict__ w1, const float* __restrict__ w2,
                        _Float16* __restrict__ wpk) {
    int idx = blockIdx.x*256 + threadIdx.x;
    if (idx >= NRES*2*3*65536) return;
    int ci = idx & 255;
    int o  = (idx >> 8) & 255;
    int k  = (idx >> 16) % 3;
    int cv = idx / (3*65536);
    const float* src = (cv & 1) ? w2 : w1;
    wpk[idx] = (_Float16)src[(((cv>>1)*H + o)*H + ci)*3 + k];
}

// ---------------- transpose fp16 chl -> fp16 chm ----------------
__global__ __launch_bounds__(256) void k_t_cf16(const _Float16* __restrict__ in,
        _Float16* __restrict__ out) {
    __shared__ float t[64][65];
    int tid = threadIdx.x;
    int l0 = blockIdx.x*64, c0 = blockIdx.y*64, b = blockIdx.z;
    #pragma unroll
    for (int i = 0; i < 16; ++i) {
        int idx = i*256 + tid;
        int l = idx >> 6, c = idx & 63;
        t[c][l] = (float)in[((size_t)b*L + l0 + l)*256 + c0 + c];
    }
    __syncthreads();
    #pragma unroll
    for (int i = 0; i < 16; ++i) {
        int idx = i*256 + tid;
        int c = idx >> 6, l = idx & 63;
        out[((size_t)(b*H + c0 + c))*L + l0 + l] = (_Float16)t[c][l];
    }
}

// ---------------- transpose fp16 chm -> fp16 chl ----------------
__global__ __launch_bounds__(256) void k_t16(const _Float16* __restrict__ in,
                                             _Float16* __restrict__ out) {
    __shared__ float t[64][65];
    int tid = threadIdx.x;
    int l0 = blockIdx.x*64, c0 = blockIdx.y*64, b = blockIdx.z;
    #pragma unroll
    for (int i = 0; i < 16; ++i) {
        int idx = i*256 + tid;
        int c = idx >> 6, l = idx & 63;
        t[c][l] = (float)in[((size_t)(b*H + c0 + c))*L + l0 + l];
    }
    __syncthreads();
    #pragma unroll
    for (int i = 0; i < 16; ++i) {
        int idx = i*256 + tid;
        int l = idx >> 6, c = idx & 63;
        out[((size_t)b*L + l0 + l)*256 + c0 + c] = (_Float16)t[c][l];
    }
}

// ---------------- MFMA residual conv K=3: full-N tile 128m x 256o, coalesced epilogue ----------------
template<bool RESID>
__global__ __launch_bounds__(256, 2) void k_cv3(const _Float16* __restrict__ xin,
        const _Float16* __restrict__ wpk, const float* __restrict__ bias,
        const _Float16* __restrict__ resid, _Float16* __restrict__ out) {
    __shared__ _Float16 a_lds[128*32];
    __shared__ _Float16 b_lds[256*32];
    __shared__ float    ep[32*256];
    const int tid = threadIdx.x;
    const int mbase = blockIdx.x * 128;
    const int lane = tid & 63;
    const int w = tid >> 6;
    const int wm = (w >> 1) * 64, wo = (w & 1) * 128;
    const int fr = lane & 15, kg = lane >> 4;

    const int r0s = tid >> 2, q0 = tid & 3;
    const int sq = SWZ(r0s);
    const int awA0 = r0s*32 + ((q0 ^ sq) * 8);
    const int awA1 = (64 + r0s)*32 + ((q0 ^ SWZ(64 + r0s)) * 8);

    f32x4 acc[4][8];
    #pragma unroll
    for (int i = 0; i < 4; ++i)
        #pragma unroll
        for (int j = 0; j < 8; ++j)
            #pragma unroll
            for (int k = 0; k < 4; ++k) acc[i][j][k] = 0.f;

    uint4 pa0, pa1, pb[4];
    auto loadstep = [&](int kk, uint4& a0, uint4& a1, uint4 (&bb)[4]) {
        const int koff = kk >> 3, cic = kk & 7;
        const int cb = cic*32 + q0*8;
        {
            int m = mbase + r0s;
            int ll = (m & (L-1)) + koff - 1;
            a0 = (ll >= 0 && ll < L) ? *(const uint4*)&xin[((size_t)(m + koff - 1))*256 + cb]
                                     : make_uint4(0,0,0,0);
            int m1 = mbase + 64 + r0s;
            int l1 = (m1 & (L-1)) + koff - 1;
            a1 = (l1 >= 0 && l1 < L) ? *(const uint4*)&xin[((size_t)(m1 + koff - 1))*256 + cb]
                                     : make_uint4(0,0,0,0);
        }
        #pragma unroll
        for (int u = 0; u < 4; ++u)
            bb[u] = *(const uint4*)&wpk[((size_t)(koff*256 + u*64 + r0s))*256 + cb];
    };
    loadstep(0, pa0, pa1, pb);
    for (int kk = 0; kk < 24; ++kk) {
        __syncthreads();
        *(uint4*)&a_lds[awA0] = pa0;
        *(uint4*)&a_lds[awA1] = pa1;
        #pragma unroll
        for (int u = 0; u < 4; ++u)
            *(uint4*)&b_lds[(u*64 + r0s)*32 + ((q0 ^ sq)*8)] = pb[u];
        uint4 na0 = make_uint4(0,0,0,0), na1 = na0, nb[4] = {na0, na0, na0, na0};
        if (kk < 23) loadstep(kk+1, na0, na1, nb);
        __syncthreads();
        half8 af[4];
        #pragma unroll
        for (int mf = 0; mf < 4; ++mf) {
            int ra = wm + mf*16 + fr;
            af[mf] = *(const half8*)&a_lds[ra*32 + ((kg ^ SWZ(ra)) * 8)];
        }
        #pragma unroll
        for (int nf = 0; nf < 8; ++nf) {
            int rb = wo + nf*16 + fr;
            half8 bfr = *(const half8*)&b_lds[rb*32 + ((kg ^ SWZ(rb)) * 8)];
            #pragma unroll
            for (int mf = 0; mf < 4; ++mf)
                acc[mf][nf] = __builtin_amdgcn_mfma_f32_16x16x32_f16(af[mf], bfr, acc[mf][nf], 0, 0, 0);
        }
        pa0 = na0; pa1 = na1;
        #pragma unroll
        for (int u = 0; u < 4; ++u) pb[u] = nb[u];
    }
    float bo8[8];
    #pragma unroll
    for (int nf = 0; nf < 8; ++nf) bo8[nf] = bias[wo + nf*16 + fr];
    const int er = tid >> 3, eoc = (tid & 7) * 32;
    #pragma unroll
    for (int mf = 0; mf < 4; ++mf) {
        __syncthreads();
        #pragma unroll
        for (int nf = 0; nf < 8; ++nf) {
            int o = wo + nf*16 + fr;
            int srb = (w >> 1)*16 + kg*4;
            #pragma unroll
            for (int rg = 0; rg < 4; ++rg)
                ep[(srb + rg)*256 + o] = acc[mf][nf][rg] + bo8[nf];
        }
        __syncthreads();
        size_t m = (size_t)mbase + mf*16 + (er < 16 ? er : 48 + er);
        #pragma unroll
        for (int u = 0; u < 4; ++u) {
            float4 v0 = *(float4*)&ep[er*256 + eoc + u*8];
            float4 v1 = *(float4*)&ep[er*256 + eoc + u*8 + 4];
            float vv[8] = {v0.x, v0.y, v0.z, v0.w, v1.x, v1.y, v1.z, v1.w};
            if (RESID) {
                half8 rv = *(const half8*)&resid[m*256 + eoc + u*8];
                #pragma unroll
                for (int e = 0; e < 8; ++e) vv[e] += (float)rv[e];
            }
            half8 hv;
            #pragma unroll
            for (int e = 0; e < 8; ++e) hv[e] = (_Float16)fmaxf(vv[e], 0.f);
            *(half8*)&out[m*256 + eoc + u*8] = hv;
        }
    }
}

// ---------------- DSS: per-(h,n) pole z and z^CHUNK ----------------
__global__ void k_zw(const float* __restrict__ log_dt, const float* __restrict__ lam_re,
                     const float* __restrict__ lam_im, float4* __restrict__ zwbuf, int layer) {
    int idx = blockIdx.x*256 + threadIdx.x;
    if (idx >= H*NST) return;
    int hh = idx / NST, n = idx % NST;
    float dt = expf(log_dt[layer*H + hh]);
    float a  = dt * lam_re[layer*NST + n];
    float bi = dt * lam_im[layer*NST + n];
    float er = expf(a);
    float zre = er * cosf(bi), zim = er * sinf(bi);
    float eC = expf(a * (float)CHUNK);
    float bC = bi * (float)CHUNK;
    float zcre = eC * cosf(bC), zcim = eC * sinf(bC);
    zwbuf[idx] = make_float4(zre, zim, zcre, zcim);
}

// ---------------- Z-power matrix zp[h][t][j] fp16 (t = dn*2+c) ----------------
__global__ __launch_bounds__(128) void k_wzp(const float4* __restrict__ zw,
        _Float16* __restrict__ zp) {
    int hh = blockIdx.x;
    int t = threadIdx.x;
    int dn = t >> 1, c = t & 1, dir = dn >> 5, n = dn & 31;
    float4 z4 = zw[hh*NST + n];
    float zre = z4.x, zim = z4.y;
    _Float16* dst = &zp[(size_t)hh*16384 + t*128];
    float cr = 1.f, ci = 0.f;
    for (int p = 0; p < 128; ++p) {
        float val = c ? ci : cr;
        dst[dir ? p : (127 - p)] = (_Float16)val;
        float nr = cr*zre - ci*zim;
        float ni = cr*zim + ci*zre;
        cr = nr; ci = ni;
    }
}

// ---------------- W_big[h][t][256] fp16 ----------------
__global__ __launch_bounds__(128) void k_wkern(const float* __restrict__ log_dt,
        const float* __restrict__ lam_re, const float* __restrict__ lam_im,
        const float* __restrict__ W_re, const float* __restrict__ W_im,
        _Float16* __restrict__ wbig, int layer) {
    __shared__ float kf[128], kb[128];
    __shared__ float E[128*129];
    const int hh = blockIdx.x;
    const int t = threadIdx.x;
    float dt = expf(log_dt[layer*H + hh]);
    float skf = 0.f, skb = 0.f;
    for (int n = 0; n < 32; ++n) {
        float a  = dt * lam_re[layer*NST + n];
        float bi = dt * lam_im[layer*NST + n];
        float wfr = W_re[((layer*2+0)*H + hh)*NST + n];
        float wfi = W_im[((layer*2+0)*H + hh)*NST + n];
        float wbr = W_re[((layer*2+1)*H + hh)*NST + n];
        float wbi = W_im[((layer*2+1)*H + hh)*NST + n];
        float e0 = expf(a*t), s0, c0; sincosf(bi*t, &s0, &c0);
        float zr0 = e0*c0, zi0 = e0*s0;
        skf = fmaf(wfr, zr0, skf) - wfi*zi0;
        skb = fmaf(wbr, zr0, skb) - wbi*zi0;
        float e1 = expf(a*(t+1)), s1, c1; sincosf(bi*(t+1), &s1, &c1);
        float zr1 = e1*c1, zi1 = e1*s1;
        E[t*129 + n]      = wfr*zr1 - wfi*zi1;
        E[t*129 + 32 + n] = -(wfr*zi1 + wfi*zr1);
        float e2 = expf(a*(127-t)), s2, c2; sincosf(bi*(127-t), &s2, &c2);
        float zr2 = e2*c2, zi2 = e2*s2;
        E[t*129 + 64 + n] = wbr*zr2 - wbi*zi2;
        E[t*129 + 96 + n] = -(wbr*zi2 + wbi*zr2);
    }
    kf[t] = skf; kb[t] = skb;
    __syncthreads();
    _Float16* dst = &wbig[(size_t)hh*32768];
    for (int idx = t; idx < 128*256; idx += 128) {
        int tt = idx >> 8, k = idx & 255;
        float v;
        if (k < 128) v = (k <= tt) ? kf[tt - k] : kb[k - tt - 1];
        else         v = E[tt*129 + (k - 128)];
        dst[idx] = (_Float16)v;
    }
}

// ---------------- GLU weight pack ----------------
__global__ void k_wtg16(const float* __restrict__ gw, _Float16* __restrict__ wg, int layer) {
    int idx = blockIdx.x*256 + threadIdx.x;
    if (idx >= 512*256) return;
    wg[idx] = (_Float16)gw[layer*512*256 + idx];
}

// ---------------- decoder weight pack ----------------
__global__ void k_wdec(const float* __restrict__ dw, _Float16* __restrict__ wdk) {
    int idx = blockIdx.x*256 + threadIdx.x;
    if (idx >= 15*16*256) return;
    int cfull = idx & 255;
    int o = (idx >> 8) & 15;
    int k = idx >> 12;
    float v = (o < DOUT) ? dw[(o*H + cfull)*15 + k] : 0.f;
    int cc = cfull >> 5, cl = cfull & 31;
    int cq = cl >> 3, cb = cl & 7;
    wdk[cc*7680 + (k*16 + o)*32 + ((cq ^ SWZ(o))*8) + cb] = (_Float16)v;
}

// ---------------- FUSED DSS v2: single-stage zp, K=64 wbig dbuf panels ----------------
__global__ __launch_bounds__(256) void k_dss(const _Float16* __restrict__ hm16,
        const _Float16* __restrict__ zp, const _Float16* __restrict__ wbig,
        const float4* __restrict__ zwb, const float* __restrict__ Dv,
        _Float16* __restrict__ y16, int layer) {
    __shared__ _Float16 xbuf[4*64*32];
    __shared__ _Float16 zsb[16384];
    __shared__ _Float16 bbuf[4*64*32];

    const int tid = threadIdx.x;
    const int hh = blockIdx.x;
    const int b0 = blockIdx.y * 4;
    const int lane = tid & 63;
    const int w = tid >> 6;
    const int wn = w * 32;
    const int fr = lane & 15, kg = lane >> 4;

    #pragma unroll
    for (int i = 0; i < 4; ++i) {
        int g = i*256 + tid;
        int m = g >> 4, gi = g & 15;
        int kc = gi >> 2, q = gi & 3;
        uint4 v = *(const uint4*)&hm16[((size_t)((b0 + (m>>4))*H + hh))*L
                                       + (m&15)*128 + kc*32 + q*8];
        *(uint4*)&xbuf[kc*2048 + m*32 + ((q ^ SWZ(m))*8)] = v;
    }
    const _Float16* zb = &zp[(size_t)hh*16384];
    #pragma unroll
    for (int i = 0; i < 8; ++i) {
        int g = i*256 + tid;
        int kc = g >> 9, rem = g & 511;
        int t = rem >> 2, q = rem & 3;
        uint4 v = *(const uint4*)&zb[t*128 + kc*32 + q*8];
        *(uint4*)&zsb[kc*4096 + t*32 + ((q ^ SWZ(t))*8)] = v;
    }
    __syncthreads();

    // ---- phase 1: S = x . zp^T ----
    f32x4 acc1[4][2];
    #pragma unroll
    for (int i = 0; i < 4; ++i)
        #pragma unroll
        for (int j = 0; j < 2; ++j)
            #pragma unroll
            for (int k = 0; k < 4; ++k) acc1[i][j][k] = 0.f;
    #pragma unroll
    for (int kc = 0; kc < 4; ++kc) {
        half8 af[4], bf2[2];
        #pragma unroll
        for (int mf = 0; mf < 4; ++mf) {
            int ra = mf*16 + fr;
            af[mf] = *(const half8*)&xbuf[kc*2048 + ra*32 + ((kg ^ SWZ(ra))*8)];
        }
        #pragma unroll
        for (int nf = 0; nf < 2; ++nf) {
            int rb = wn + nf*16 + fr;
            bf2[nf] = *(const half8*)&zsb[kc*4096 + rb*32 + ((kg ^ SWZ(rb))*8)];
        }
        #pragma unroll
        for (int mf = 0; mf < 4; ++mf)
            #pragma unroll
            for (int nf = 0; nf < 2; ++nf)
                acc1[mf][nf] = __builtin_amdgcn_mfma_f32_16x16x32_f16(af[mf], bf2[nf], acc1[mf][nf], 0, 0, 0);
    }
    __syncthreads();
    float* sfp = (float*)zsb;
    #pragma unroll
    for (int mf = 0; mf < 4; ++mf)
        #pragma unroll
        for (int nf = 0; nf < 2; ++nf)
            #pragma unroll
            for (int rg = 0; rg < 4; ++rg)
                sfp[(mf*16 + kg*4 + rg)*128 + wn + nf*16 + fr] = acc1[mf][nf][rg];
    __syncthreads();

    // ---- phase 2: in-LDS cross-chunk scan ----
    {
        int b_loc = tid >> 6, dn = tid & 63;
        int dir = dn >> 5, n = dn & 31;
        float4 z4 = zwb[hh*NST + n];
        float zcre = z4.z, zcim = z4.w;
        int q1 = n >> 3, e1 = n & 7;
        float pre = 0.f, pim = 0.f;
        for (int s = 0; s < NCH; ++s) {
            int ch = dir ? (NCH - 1 - s) : s;
            int m = b_loc*16 + ch;
            bbuf[(dir*2 + 0)*2048 + m*32 + ((q1 ^ SWZ(m))*8) + e1] = (_Float16)pre;
            bbuf[(dir*2 + 1)*2048 + m*32 + ((q1 ^ SWZ(m))*8) + e1] = (_Float16)pim;
            float cre = sfp[m*128 + dn*2];
            float cim = sfp[m*128 + dn*2 + 1];
            float nre = fmaf(zcre, pre, fmaf(-zcim, pim, cre));
            float nim = fmaf(zcre, pim, fmaf(zcim, pre, cim));
            pre = nre; pim = nim;
        }
    }
    __syncthreads();

    // ---- phase 3: y = [x | stp] . wbig^T, K=64 dbuf panels ----
    f32x4 acc3[4][2];
    #pragma unroll
    for (int i = 0; i < 4; ++i)
        #pragma unroll
        for (int j = 0; j < 2; ++j)
            #pragma unroll
            for (int k = 0; k < 4; ++k) acc3[i][j][k] = 0.f;
    const _Float16* wb = &wbig[(size_t)hh*32768];
    uint4 wr[4];
    auto loadW = [&](int p, uint4 (&r)[4]) {
        #pragma unroll
        for (int i = 0; i < 4; ++i) {
            int g = i*256 + tid;
            int sub = g >> 9, rem = g & 511;
            int t = rem >> 2, q = rem & 3;
            r[i] = *(const uint4*)&wb[t*256 + p*64 + sub*32 + q*8];
        }
    };
    loadW(0, wr);
    for (int p = 0; p < 4; ++p) {
        __syncthreads();
        #pragma unroll
        for (int i = 0; i < 4; ++i) {
            int g = i*256 + tid;
            int sub = g >> 9, rem = g & 511;
            int t = rem >> 2, q = rem & 3;
            *(uint4*)&zsb[(p&1)*8192 + sub*4096 + t*32 + ((q ^ SWZ(t))*8)] = wr[i];
        }
        if (p < 3) loadW(p+1, wr);
        __syncthreads();
        #pragma unroll
        for (int sub = 0; sub < 2; ++sub) {
            int kcg = p*2 + sub;
            half8 af[4], bf2[2];
            #pragma unroll
            for (int mf = 0; mf < 4; ++mf) {
                int ra = mf*16 + fr;
                af[mf] = (kcg < 4)
                    ? *(const half8*)&xbuf[kcg*2048 + ra*32 + ((kg ^ SWZ(ra))*8)]
                    : *(const half8*)&bbuf[(kcg-4)*2048 + ra*32 + ((kg ^ SWZ(ra))*8)];
            }
            #pragma unroll
            for (int nf = 0; nf < 2; ++nf) {
                int rb = wn + nf*16 + fr;
                bf2[nf] = *(const half8*)&zsb[(p&1)*8192 + sub*4096 + rb*32 + ((kg ^ SWZ(rb))*8)];
            }
            #pragma unroll
            for (int mf = 0; mf < 4; ++mf)
                #pragma unroll
                for (int nf = 0; nf < 2; ++nf)
                    acc3[mf][nf] = __builtin_amdgcn_mfma_f32_16x16x32_f16(af[mf], bf2[nf], acc3[mf][nf], 0, 0, 0);
        }
    }
    __syncthreads();
    float dv = Dv[layer*H + hh];
    _Float16* yst = bbuf;
    #pragma unroll
    for (int mf = 0; mf < 4; ++mf) {
        #pragma unroll
        for (int rg = 0; rg < 4; ++rg) {
            int m = mf*16 + kg*4 + rg;
            #pragma unroll
            for (int nf = 0; nf < 2; ++nf) {
                int t = wn + nf*16 + fr;
                float xv = (float)xbuf[(t>>5)*2048 + m*32 + ((((t&31)>>3) ^ SWZ(m))*8) + (t&7)];
                float v = acc3[mf][nf][rg] + dv * xv;
                yst[m*128 + t] = (_Float16)gelu_exact(v);
            }
        }
    }
    __syncthreads();
    {
        int r = tid >> 2, tc = (tid & 3) * 32;
        size_t gb = ((size_t)((b0 + (r>>4))*H + hh))*L + (r&15)*128;
        #pragma unroll
        for (int u = 0; u < 4; ++u)
            *(half8*)&y16[gb + tc + u*8] = *(half8*)&yst[r*128 + tc + u*8];
    }
}

// ---------------- GLU MFMA fp16 -> fp16 zc, coalesced epilogue; grid (B*L/128, 4) ----------------
__global__ __launch_bounds__(256) void k_glu16(const _Float16* __restrict__ yt,
        const _Float16* __restrict__ wg, const float* __restrict__ bias,
        _Float16* __restrict__ zc) {
    __shared__ _Float16 a_lds[128*32];
    __shared__ _Float16 b_lds[128*32];
    __shared__ float    ep[32*64];
    const int tid = threadIdx.x;
    const int mbase = blockIdx.x * 128;
    const int o0 = blockIdx.y * 64;
    const int lane = tid & 63;
    const int w = tid >> 6;
    const int wm = (w >> 1) * 64, wn = (w & 1) * 32;
    const int fr = lane & 15, kg = lane >> 4;
    const int r0s = tid >> 2, q0 = tid & 3;
    const int r1s = 64 + r0s;
    const int aw0 = r0s*32 + ((q0 ^ SWZ(r0s)) * 8);
    const int aw1 = r1s*32 + ((q0 ^ SWZ(r1s)) * 8);
    const int og0 = o0 + r0s;
    const int og1 = 256 + o0 + r0s;

    f32x4 accg[4][2], accs[4][2];
    #pragma unroll
    for (int i = 0; i < 4; ++i)
        #pragma unroll
        for (int j = 0; j < 2; ++j)
            #pragma unroll
            for (int k = 0; k < 4; ++k) { accg[i][j][k] = 0.f; accs[i][j][k] = 0.f; }

    uint4 pa0, pa1, pb0, pb1;
    auto loadstep = [&](int kc, uint4& a0, uint4& a1, uint4& b0, uint4& b1) {
        const int cb = kc*32 + q0*8;
        a0 = *(const uint4*)&yt[((size_t)(mbase + r0s))*256 + cb];
        a1 = *(const uint4*)&yt[((size_t)(mbase + r1s))*256 + cb];
        b0 = *(const uint4*)&wg[((size_t)og0)*256 + cb];
        b1 = *(const uint4*)&wg[((size_t)og1)*256 + cb];
    };
    loadstep(0, pa0, pa1, pb0, pb1);
    for (int kc = 0; kc < 8; ++kc) {
        __syncthreads();
        *(uint4*)&a_lds[aw0] = pa0;
        *(uint4*)&a_lds[aw1] = pa1;
        *(uint4*)&b_lds[aw0] = pb0;
        *(uint4*)&b_lds[aw1] = pb1;
        uint4 na0 = make_uint4(0,0,0,0), na1 = na0, nb0 = na0, nb1 = na0;
        if (kc < 7) loadstep(kc+1, na0, na1, nb0, nb1);
        __syncthreads();
        half8 af[4], bg[2], bs[2];
        #pragma unroll
        for (int mf = 0; mf < 4; ++mf) {
            int ra = wm + mf*16 + fr;
            af[mf] = *(const half8*)&a_lds[ra*32 + ((kg ^ SWZ(ra)) * 8)];
        }
        #pragma unroll
        for (int nf = 0; nf < 2; ++nf) {
            int rb = wn + nf*16 + fr;
            bg[nf] = *(const half8*)&b_lds[rb*32 + ((kg ^ SWZ(rb)) * 8)];
            int rb2 = 64 + rb;
            bs[nf] = *(const half8*)&b_lds[rb2*32 + ((kg ^ SWZ(rb2)) * 8)];
        }
        #pragma unroll
        for (int mf = 0; mf < 4; ++mf)
            #pragma unroll
            for (int nf = 0; nf < 2; ++nf) {
                accg[mf][nf] = __builtin_amdgcn_mfma_f32_16x16x32_f16(af[mf], bg[nf], accg[mf][nf], 0, 0, 0);
                accs[mf][nf] = __builtin_amdgcn_mfma_f32_16x16x32_f16(af[mf], bs[nf], accs[mf][nf], 0, 0, 0);
            }
        pa0 = na0; pa1 = na1; pb0 = nb0; pb1 = nb1;
    }
    float b0v[2], b1v[2];
    #pragma unroll
    for (int nf = 0; nf < 2; ++nf) {
        int o = o0 + wn + nf*16 + fr;
        b0v[nf] = bias[o]; b1v[nf] = bias[256 + o];
    }
    const int er = tid >> 3, eoc = (tid & 7) * 8;
    #pragma unroll
    for (int mf = 0; mf < 4; ++mf) {
        __syncthreads();
        #pragma unroll
        for (int nf = 0; nf < 2; ++nf) {
            int ol = wn + nf*16 + fr;
            int srb = (w >> 1)*16 + kg*4;
            #pragma unroll
            for (int rg = 0; rg < 4; ++rg) {
                float g = accg[mf][nf][rg] + b0v[nf];
                float s = accs[mf][nf][rg] + b1v[nf];
                ep[(srb + rg)*64 + ol] = g / (1.f + expf(-s));
            }
        }
        __syncthreads();
        size_t m = (size_t)mbase + mf*16 + (er < 16 ? er : 48 + er);
        float4 v0 = *(float4*)&ep[er*64 + eoc];
        float4 v1 = *(float4*)&ep[er*64 + eoc + 4];
        half8 hv;
        hv[0]=(_Float16)v0.x; hv[1]=(_Float16)v0.y; hv[2]=(_Float16)v0.z; hv[3]=(_Float16)v0.w;
        hv[4]=(_Float16)v1.x; hv[5]=(_Float16)v1.y; hv[6]=(_Float16)v1.z; hv[7]=(_Float16)v1.w;
        *(half8*)&zc[m*256 + o0 + eoc] = hv;
    }
}

// ---------------- LayerNorm: fp16 residual stream; last layer adds species + outseq f32 ----------------
template<bool SP>
__global__ __launch_bounds__(256) void k_ln2(const _Float16* __restrict__ zc,
        _Float16* __restrict__ hm, const float* __restrict__ g, const float* __restrict__ bb,
        const int* __restrict__ xs, const float* __restrict__ emb,
        float* __restrict__ outseq) {
    __shared__ float tl[8992];
    int tid = threadIdx.x;
    int b = blockIdx.y;
    int l0 = blockIdx.x * 32;
    for (int j = tid; j < 1024; j += 256) {
        int c = j >> 2, l8 = (j & 3) * 8;
        half8 v = *(const half8*)&hm[((size_t)(b*H + c))*L + l0 + l8];
        #pragma unroll
        for (int e = 0; e < 8; ++e) tl[LDIDX(l8 + e, c)] = (float)v[e];
    }
    __syncthreads();
    int r = tid >> 3, p = tid & 7;
    float v[32];
    float sum = 0.f, ss = 0.f;
    const _Float16* zrow = &zc[((size_t)(b*L + l0 + r))*256 + p*32];
    #pragma unroll
    for (int q = 0; q < 4; ++q) {
        half8 z8 = *(const half8*)&zrow[q*8];
        #pragma unroll
        for (int i = 0; i < 8; ++i) {
            float hv = tl[LDIDX(r, p*32 + q*8 + i)];
            float vv = (float)z8[i] + hv;
            v[q*8+i] = vv;
            sum += vv; ss = fmaf(vv, vv, ss);
        }
    }
    sum += __shfl_xor(sum, 1); ss += __shfl_xor(ss, 1);
    sum += __shfl_xor(sum, 2); ss += __shfl_xor(ss, 2);
    sum += __shfl_xor(sum, 4); ss += __shfl_xor(ss, 4);
    float mu = sum * (1.f/256.f);
    float var = ss * (1.f/256.f) - mu*mu;
    float rs = rsqrtf(var + 1e-5f);
    int sp = SP ? xs[b] : 0;
    #pragma unroll
    for (int q = 0; q < 32; ++q) {
        int c = p*32 + q;
        float val = (v[q] - mu) * rs * g[c] + bb[c];
        if (SP) val += emb[sp*H + c];
        tl[LDIDX(r, c)] = val;
    }
    __syncthreads();
    for (int j = tid; j < 1024; j += 256) {
        int c = j >> 2, l8 = (j & 3) * 8;
        float fv[8];
        half8 hv;
        #pragma unroll
        for (int e = 0; e < 8; ++e) {
            fv[e] = tl[LDIDX(l8 + e, c)];
            hv[e] = (_Float16)fv[e];
        }
        *(half8*)&hm[((size_t)(b*H + c))*L + l0 + l8] = hv;
        if (SP) {
            *(float4*)&outseq[((size_t)(b*H + c))*L + l0 + l8] = make_float4(fv[0],fv[1],fv[2],fv[3]);
            *(float4*)&outseq[((size_t)(b*H + c))*L + l0 + l8 + 4] = make_float4(fv[4],fv[5],fv[6],fv[7]);
        }
    }
}

// ---------------- MFMA decoder conv K=15 ----------------
__global__ __launch_bounds__(128) void k_dec(const _Float16* __restrict__ ht,
        const _Float16* __restrict__ wdk, const float* __restrict__ bias,
        float* __restrict__ outdec) {
    __shared__ _Float16 a_lds[160*32];
    __shared__ _Float16 b_lds[15*16*32];
    const int tid = threadIdx.x;
    const int mbase = blockIdx.x * 128;
    const int b = mbase >> 11;
    const int lbase = mbase & 2047;
    const int lane = tid & 63;
    const int w = tid >> 6;
    const int fr = lane & 15, kg = lane >> 4;
    const int rs = tid >> 2, q0 = tid & 3;
    f32x4 acc[4];
    #pragma unroll
    for (int i = 0; i < 4; ++i)
        #pragma unroll
        for (int k = 0; k < 4; ++k) acc[i][k] = 0.f;
    for (int cc = 0; cc < 8; ++cc) {
        __syncthreads();
        #pragma unroll
        for (int ps = 0; ps < 5; ++ps) {
            int r = ps*32 + rs;
            if (r < 142) {
                int l = lbase - 7 + r;
                uint4 v = (l >= 0 && l < L) ? *(const uint4*)&ht[((size_t)(b*L + l))*256 + cc*32 + q0*8]
                                            : make_uint4(0,0,0,0);
                *(uint4*)&a_lds[r*32 + ((q0 ^ SWZ(r))*8)] = v;
            }
        }
        for (int jj = tid; jj < 960; jj += 128)
            *(uint4*)&b_lds[jj*8] = *(const uint4*)&wdk[cc*7680 + jj*8];
        __syncthreads();
        #pragma unroll
        for (int k = 0; k < 15; ++k) {
            half8 bfr = *(const half8*)&b_lds[(k*16 + fr)*32 + ((kg ^ SWZ(fr))*8)];
            #pragma unroll
            for (int mf = 0; mf < 4; ++mf) {
                int ra = w*64 + mf*16 + fr + k;
                half8 af = *(const half8*)&a_lds[ra*32 + ((kg ^ SWZ(ra))*8)];
                acc[mf] = __builtin_amdgcn_mfma_f32_16x16x32_f16(af, bfr, acc[mf], 0, 0, 0);
            }
        }
    }
    if (fr < DOUT) {
        float bo = bias[fr];
        #pragma unroll
        for (int mf = 0; mf < 4; ++mf)
            #pragma unroll
            for (int rg = 0; rg < 4; ++rg) {
                int m = mbase + w*64 + mf*16 + kg*4 + rg;
                outdec[((size_t)(b*DOUT + fr))*L + (m & 2047)] = acc[mf][rg] + bo;
            }
    }
}

// ---------------- mean over L (fp16 input) ----------------
__global__ __launch_bounds__(256) void k_agg(const _Float16* __restrict__ h, float* __restrict__ agg) {
    __shared__ float red[256];
    int bc = blockIdx.x;
    int tid = threadIdx.x;
    half8 v = *(const half8*)&h[(size_t)bc*L + tid*8];
    float s = 0.f;
    #pragma unroll
    for (int e = 0; e < 8; ++e) s += (float)v[e];
    red[tid] = s; __syncthreads();
    for (int k = 128; k > 0; k >>= 1) {
        if (tid < k) red[tid] += red[tid+k];
        __syncthreads();
    }
    if (tid == 0) agg[bc] = red[0] * (1.f/(float)L);
}

// ---------------- regression MLP ----------------
__global__ __launch_bounds__(128) void k_mlp(const float* __restrict__ agg,
        const float* __restrict__ w1, const float* __restrict__ b1,
        const float* __restrict__ w2, const float* __restrict__ b2,
        const float* __restrict__ w3, const float* __restrict__ b3,
        const float* __restrict__ w4, const float* __restrict__ b4,
        float* __restrict__ outreg) {
    __shared__ float a0[256], r1[128], r2[64], r3[32];
    int b = blockIdx.x, tid = threadIdx.x;
    a0[tid] = agg[b*256 + tid];
    a0[tid+128] = agg[b*256 + tid + 128];
    __syncthreads();
    {
        float s = b1[tid];
        for (int k = 0; k < 256; ++k) s = fmaf(w1[tid*256+k], a0[k], s);
        r1[tid] = s > 0.f ? s : expm1f(s);
    }
    __syncthreads();
    if (tid < 64) {
        float s = b2[tid];
        for (int k = 0; k < 128; ++k) s = fmaf(w2[tid*128+k], r1[k], s);
        r2[tid] = s > 0.f ? s : expm1f(s);
    }
    __syncthreads();
    if (tid < 32) {
        float s = b3[tid];
        for (int k = 0; k < 64; ++k) s = fmaf(w3[tid*64+k], r2[k], s);
        r3[tid] = s > 0.f ? s : expm1f(s);
    }
    __syncthreads();
    if (tid == 0) {
        float s = b4[0];
        for (int k = 0; k < 32; ++k) s = fmaf(w4[k], r3[k], s);
        outreg[b] = s;
    }
}

extern "C" void kernel_launch(void* const* d_in, const int* in_sizes, int n_in,
                              void* d_out, int out_size, void* d_ws, size_t ws_size,
                              hipStream_t stream) {
    const float* x      = (const float*)d_in[0];
    const int*   xs     = (const int*)d_in[1];
    const float* enc_w  = (const float*)d_in[2];
    const float* enc_b  = (const float*)d_in[3];
    const float* res_w1 = (const float*)d_in[4];
    const float* res_b1 = (const float*)d_in[5];
    const float* res_w2 = (const float*)d_in[6];
    const float* res_b2 = (const float*)d_in[7];
    const float* log_dt = (const float*)d_in[8];
    const float* lam_re = (const float*)d_in[9];
    const float* lam_im = (const float*)d_in[10];
    const float* W_re   = (const float*)d_in[11];
    const float* W_im   = (const float*)d_in[12];
    const float* Dv     = (const float*)d_in[13];
    const float* glu_w  = (const float*)d_in[14];
    const float* glu_b  = (const float*)d_in[15];
    const float* ln_g   = (const float*)d_in[16];
    const float* ln_b   = (const float*)d_in[17];
    const float* dec_w  = (const float*)d_in[18];
    const float* dec_b  = (const float*)d_in[19];
    const float* sp_emb = (const float*)d_in[20];
    const float* h1_w = (const float*)d_in[21]; const float* h1_b = (const float*)d_in[22];
    const float* h2_w = (const float*)d_in[23]; const float* h2_b = (const float*)d_in[24];
    const float* h3_w = (const float*)d_in[25]; const float* h3_b = (const float*)d_in[26];
    const float* h4_w = (const float*)d_in[27]; const float* h4_b = (const float*)d_in[28];

    float* ws   = (float*)d_ws;
    _Float16* hm16 = (_Float16*)ws;                    // fp16 chm residual (persistent)
    float* t1   = ws + (size_t)LSEQ;
    float* t2   = ws + (size_t)2*LSEQ;
    // res-phase:
    _Float16* xb  = (_Float16*)t1;
    _Float16* xa  = (_Float16*)t1 + (size_t)LSEQ;
    _Float16* wpk = (_Float16*)t2;
    // DSS-phase:
    _Float16* yt   = (_Float16*)t1;                    // fp16 chl y (t1 lower)
    _Float16* wbig = (_Float16*)t1 + (size_t)LSEQ;     // 16MB (t1 upper)
    _Float16* zp   = wbig + (size_t)H*32768;           // 8MB
    _Float16* y16  = (_Float16*)t2;                    // fp16 chm y
    _Float16* zc16 = (_Float16*)t2;                    // glu out fp16 chl (y16 dead)
    _Float16* dect = (_Float16*)t1;                    // decoder chl input
    // tail:
    float* tail = ws + (size_t)3*LSEQ;
    _Float16* wg  = (_Float16*)tail;
    float4* zwb = (float4*)(tail + 65536);
    float* aggb = tail + 65536 + 32768;
    _Float16* wdk = (_Float16*)(aggb + 8192);
    _Float16* wenc = wdk + 61440;

    float* outdec = (float*)d_out;
    float* outseq = outdec + B*DOUT*L;
    float* outreg = outseq + (size_t)LSEQ;

    // encoder
    k_wenc<<<96, 256, 0, stream>>>(enc_w, wenc);
    k_enc<<<dim3(B*L/128, 2), 256, 0, stream>>>(x, wenc, enc_b, xa);

    // residual stack
    k_wpack<<<(NRES*2*3*65536 + 255)/256, 256, 0, stream>>>(res_w1, res_w2, wpk);
    for (int r = 0; r < NRES; ++r) {
        k_cv3<false><<<B*L/128, 256, 0, stream>>>(
            xa, wpk + (size_t)(r*2+0)*3*65536, res_b1 + r*H, nullptr, xb);
        k_cv3<true><<<B*L/128, 256, 0, stream>>>(
            xb, wpk + (size_t)(r*2+1)*3*65536, res_b2 + r*H, xa, xa);
    }
    k_t_cf16<<<dim3(L/64, H/64, B), 256, 0, stream>>>(xa, hm16);

    // DSS blocks
    for (int i = 0; i < NLAYERS; ++i) {
        k_zw<<<(H*NST + 255)/256, 256, 0, stream>>>(log_dt, lam_re, lam_im, zwb, i);
        k_wzp<<<H, 128, 0, stream>>>(zwb, zp);
        k_wkern<<<H, 128, 0, stream>>>(log_dt, lam_re, lam_im, W_re, W_im, wbig, i);
        k_wtg16<<<(512*256 + 255)/256, 256, 0, stream>>>(glu_w, wg, i);
        k_dss<<<dim3(H, 8), 256, 0, stream>>>(hm16, zp, wbig, zwb, Dv, y16, i);
        k_t16<<<dim3(L/64, H/64, B), 256, 0, stream>>>(y16, yt);
        k_glu16<<<dim3(B*L/128, 4), 256, 0, stream>>>(yt, wg, glu_b + i*512, zc16);
        if (i < NLAYERS - 1)
            k_ln2<false><<<dim3(L/32, B), 256, 0, stream>>>(zc16, hm16, ln_g + i*H, ln_b + i*H,
                                                            nullptr, nullptr, nullptr);
        else
            k_ln2<true><<<dim3(L/32, B), 256, 0, stream>>>(zc16, hm16, ln_g + i*H, ln_b + i*H,
                                                           xs, sp_emb, outseq);
    }

    // aggregate + regression head
    k_agg<<<B*H, 256, 0, stream>>>(hm16, aggb);
    k_mlp<<<B, 128, 0, stream>>>(aggb, h1_w, h1_b, h2_w, h2_b, h3_w, h3_b, h4_w, h4_b, outreg);
    // decoder
    k_t16<<<dim3(L/64, H/64, B), 256, 0, stream>>>(hm16, dect);
    k_wdec<<<(15*16*256 + 255)/256, 256, 0, stream>>>(dec_w, wdk);
    k_dec<<<B*L/128, 128, 0, stream>>>(dect, wdk, dec_b, outdec);
}

// Round 12
// 1125.938 us; speedup vs baseline: 1.1067x; 1.0759x over previous
//
#include <hip/hip_runtime.h>
#include <math.h>

#define B 32
#define L 2048
#define DIN 5
#define DOUT 5
#define H 256
#define NST 32
#define NLAYERS 4
#define NRES 3
#define CHUNK 128
#define NCH 16            // L / CHUNK
#define LSEQ (B*H*L)      // 16777216

typedef __attribute__((ext_vector_type(8))) _Float16 half8;
typedef __attribute__((ext_vector_type(4))) float f32x4;

__device__ __forceinline__ float gelu_exact(float v) {
    return 0.5f * v * (1.0f + erff(v * 0.7071067811865475f));
}
#define SWZ(r) ((((r) ^ ((r) >> 2)) & 3))
#define LDIDX(l, c) ((l)*281 + ((c)>>5)*35 + ((c)&31))

// ---------------- encoder weight pack ----------------
__global__ void k_wenc(const float* __restrict__ ew, _Float16* __restrict__ wenc) {
    int idx = blockIdx.x*256 + threadIdx.x;
    if (idx >= 256*96) return;
    int o = idx / 96, kk = idx % 96;
    int ci = kk >> 4, k = kk & 15;
    float v = (ci < DIN && k < 15) ? ew[(o*DIN + ci)*15 + k] : 0.f;
    wenc[idx] = (_Float16)v;
}

// ---------------- MFMA encoder conv K=15 Cin=5 ----------------
__global__ __launch_bounds__(256) void k_enc(const float* __restrict__ x,
        const _Float16* __restrict__ wenc, const float* __restrict__ bias,
        _Float16* __restrict__ out) {
    __shared__ _Float16 a_lds[3*128*32];
    __shared__ _Float16 b_lds[3*128*32];
    const int tid = threadIdx.x;
    const int mbase = blockIdx.x * 128;
    const int oh = blockIdx.y;
    const int b = mbase >> 11;
    const int lbase = mbase & 2047;
    const int lane = tid & 63;
    const int w = tid >> 6;
    const int wm = (w >> 1) * 64, wn = (w & 1) * 64;
    const int fr = lane & 15, kg = lane >> 4;

    #pragma unroll
    for (int i = 0; i < 6; ++i) {
        int g = i*256 + tid;
        int r = g / 12, rem = g % 12;
        int ks = rem >> 2, q = rem & 3;
        int kk0 = ks*32 + q*8;
        int ci = kk0 >> 4, k0 = kk0 & 15;
        half8 va;
        #pragma unroll
        for (int e = 0; e < 8; ++e) {
            int k = k0 + e;
            int l = lbase + r - 7 + k;
            float v = (ci < DIN && k < 15 && l >= 0 && l < L)
                        ? x[((size_t)(b*DIN + ci))*L + l] : 0.f;
            va[e] = (_Float16)v;
        }
        *(half8*)&a_lds[ks*4096 + r*32 + ((q ^ SWZ(r))*8)] = va;
        uint4 vb = *(const uint4*)&wenc[(size_t)(oh*128 + r)*96 + kk0];
        *(uint4*)&b_lds[ks*4096 + r*32 + ((q ^ SWZ(r))*8)] = vb;
    }
    __syncthreads();
    f32x4 acc[4][4];
    #pragma unroll
    for (int i = 0; i < 4; ++i)
        #pragma unroll
        for (int j = 0; j < 4; ++j)
            #pragma unroll
            for (int k = 0; k < 4; ++k) acc[i][j][k] = 0.f;
    #pragma unroll
    for (int ks = 0; ks < 3; ++ks) {
        half8 af[4], bfr[4];
        #pragma unroll
        for (int mf = 0; mf < 4; ++mf) {
            int ra = wm + mf*16 + fr;
            af[mf] = *(const half8*)&a_lds[ks*4096 + ra*32 + ((kg ^ SWZ(ra))*8)];
        }
        #pragma unroll
        for (int nf = 0; nf < 4; ++nf) {
            int rb = wn + nf*16 + fr;
            bfr[nf] = *(const half8*)&b_lds[ks*4096 + rb*32 + ((kg ^ SWZ(rb))*8)];
        }
        #pragma unroll
        for (int mf = 0; mf < 4; ++mf)
            #pragma unroll
            for (int nf = 0; nf < 4; ++nf)
                acc[mf][nf] = __builtin_amdgcn_mfma_f32_16x16x32_f16(af[mf], bfr[nf], acc[mf][nf], 0, 0, 0);
    }
    #pragma unroll
    for (int nf = 0; nf < 4; ++nf) {
        int o = oh*128 + wn + nf*16 + fr;
        float bo = bias[o];
        #pragma unroll
        for (int mf = 0; mf < 4; ++mf)
            #pragma unroll
            for (int rg = 0; rg < 4; ++rg) {
                size_t m = (size_t)mbase + wm + mf*16 + kg*4 + rg;
                out[m*256 + o] = (_Float16)(acc[mf][nf][rg] + bo);
            }
    }
}

// ---------------- res weight pack ----------------
__global__ void k_wpack(const float* __restrict__ w1, const float* __restrict__ w2,
                        _Float16* __restrict__ wpk) {
    int idx = blockIdx.x*256 + threadIdx.x;
    if (idx >= NRES*2*3*65536) return;
    int ci = idx & 255;
    int o  = (idx >> 8) & 255;
    int k  = (idx >> 16) % 3;
    int cv = idx / (3*65536);
    const float* src = (cv & 1) ? w2 : w1;
    wpk[idx] = (_Float16)src[(((cv>>1)*H + o)*H + ci)*3 + k];
}

// ---------------- transpose fp16 chl -> fp16 chm ----------------
__global__ __launch_bounds__(256) void k_t_cf16(const _Float16* __restrict__ in,
        _Float16* __restrict__ out) {
    __shared__ float t[64][65];
    int tid = threadIdx.x;
    int l0 = blockIdx.x*64, c0 = blockIdx.y*64, b = blockIdx.z;
    #pragma unroll
    for (int i = 0; i < 16; ++i) {
        int idx = i*256 + tid;
        int l = idx >> 6, c = idx & 63;
        t[c][l] = (float)in[((size_t)b*L + l0 + l)*256 + c0 + c];
    }
    __syncthreads();
    #pragma unroll
    for (int i = 0; i < 16; ++i) {
        int idx = i*256 + tid;
        int c = idx >> 6, l = idx & 63;
        out[((size_t)(b*H + c0 + c))*L + l0 + l] = (_Float16)t[c][l];
    }
}

// ---------------- transpose fp16 chm -> fp16 chl ----------------
__global__ __launch_bounds__(256) void k_t16(const _Float16* __restrict__ in,
                                             _Float16* __restrict__ out) {
    __shared__ float t[64][65];
    int tid = threadIdx.x;
    int l0 = blockIdx.x*64, c0 = blockIdx.y*64, b = blockIdx.z;
    #pragma unroll
    for (int i = 0; i < 16; ++i) {
        int idx = i*256 + tid;
        int c = idx >> 6, l = idx & 63;
        t[c][l] = (float)in[((size_t)(b*H + c0 + c))*L + l0 + l];
    }
    __syncthreads();
    #pragma unroll
    for (int i = 0; i < 16; ++i) {
        int idx = i*256 + tid;
        int l = idx >> 6, c = idx & 63;
        out[((size_t)b*L + l0 + l)*256 + c0 + c] = (_Float16)t[c][l];
    }
}

// ---------------- MFMA residual conv K=3: full-N tile 128m x 256o, coalesced epilogue ----------------
template<bool RESID>
__global__ __launch_bounds__(256, 2) void k_cv3(const _Float16* __restrict__ xin,
        const _Float16* __restrict__ wpk, const float* __restrict__ bias,
        const _Float16* __restrict__ resid, _Float16* __restrict__ out) {
    __shared__ _Float16 a_lds[128*32];
    __shared__ _Float16 b_lds[256*32];
    __shared__ float    ep[32*256];
    const int tid = threadIdx.x;
    const int mbase = blockIdx.x * 128;
    const int lane = tid & 63;
    const int w = tid >> 6;
    const int wm = (w >> 1) * 64, wo = (w & 1) * 128;
    const int fr = lane & 15, kg = lane >> 4;

    const int r0s = tid >> 2, q0 = tid & 3;
    const int sq = SWZ(r0s);
    const int awA0 = r0s*32 + ((q0 ^ sq) * 8);
    const int awA1 = (64 + r0s)*32 + ((q0 ^ SWZ(64 + r0s)) * 8);

    f32x4 acc[4][8];
    #pragma unroll
    for (int i = 0; i < 4; ++i)
        #pragma unroll
        for (int j = 0; j < 8; ++j)
            #pragma unroll
            for (int k = 0; k < 4; ++k) acc[i][j][k] = 0.f;

    uint4 pa0, pa1, pb[4];
    auto loadstep = [&](int kk, uint4& a0, uint4& a1, uint4 (&bb)[4]) {
        const int koff = kk >> 3, cic = kk & 7;
        const int cb = cic*32 + q0*8;
        {
            int m = mbase + r0s;
            int ll = (m & (L-1)) + koff - 1;
            a0 = (ll >= 0 && ll < L) ? *(const uint4*)&xin[((size_t)(m + koff - 1))*256 + cb]
                                     : make_uint4(0,0,0,0);
            int m1 = mbase + 64 + r0s;
            int l1 = (m1 & (L-1)) + koff - 1;
            a1 = (l1 >= 0 && l1 < L) ? *(const uint4*)&xin[((size_t)(m1 + koff - 1))*256 + cb]
                                     : make_uint4(0,0,0,0);
        }
        #pragma unroll
        for (int u = 0; u < 4; ++u)
            bb[u] = *(const uint4*)&wpk[((size_t)(koff*256 + u*64 + r0s))*256 + cb];
    };
    loadstep(0, pa0, pa1, pb);
    for (int kk = 0; kk < 24; ++kk) {
        __syncthreads();
        *(uint4*)&a_lds[awA0] = pa0;
        *(uint4*)&a_lds[awA1] = pa1;
        #pragma unroll
        for (int u = 0; u < 4; ++u)
            *(uint4*)&b_lds[(u*64 + r0s)*32 + ((q0 ^ sq)*8)] = pb[u];
        uint4 na0 = make_uint4(0,0,0,0), na1 = na0, nb[4] = {na0, na0, na0, na0};
        if (kk < 23) loadstep(kk+1, na0, na1, nb);
        __syncthreads();
        half8 af[4];
        #pragma unroll
        for (int mf = 0; mf < 4; ++mf) {
            int ra = wm + mf*16 + fr;
            af[mf] = *(const half8*)&a_lds[ra*32 + ((kg ^ SWZ(ra)) * 8)];
        }
        #pragma unroll
        for (int nf = 0; nf < 8; ++nf) {
            int rb = wo + nf*16 + fr;
            half8 bfr = *(const half8*)&b_lds[rb*32 + ((kg ^ SWZ(rb)) * 8)];
            #pragma unroll
            for (int mf = 0; mf < 4; ++mf)
                acc[mf][nf] = __builtin_amdgcn_mfma_f32_16x16x32_f16(af[mf], bfr, acc[mf][nf], 0, 0, 0);
        }
        pa0 = na0; pa1 = na1;
        #pragma unroll
        for (int u = 0; u < 4; ++u) pb[u] = nb[u];
    }
    float bo8[8];
    #pragma unroll
    for (int nf = 0; nf < 8; ++nf) bo8[nf] = bias[wo + nf*16 + fr];
    const int er = tid >> 3, eoc = (tid & 7) * 32;
    #pragma unroll
    for (int mf = 0; mf < 4; ++mf) {
        __syncthreads();
        #pragma unroll
        for (int nf = 0; nf < 8; ++nf) {
            int o = wo + nf*16 + fr;
            int srb = (w >> 1)*16 + kg*4;
            #pragma unroll
            for (int rg = 0; rg < 4; ++rg)
                ep[(srb + rg)*256 + o] = acc[mf][nf][rg] + bo8[nf];
        }
        __syncthreads();
        size_t m = (size_t)mbase + mf*16 + (er < 16 ? er : 48 + er);
        #pragma unroll
        for (int u = 0; u < 4; ++u) {
            float4 v0 = *(float4*)&ep[er*256 + eoc + u*8];
            float4 v1 = *(float4*)&ep[er*256 + eoc + u*8 + 4];
            float vv[8] = {v0.x, v0.y, v0.z, v0.w, v1.x, v1.y, v1.z, v1.w};
            if (RESID) {
                half8 rv = *(const half8*)&resid[m*256 + eoc + u*8];
                #pragma unroll
                for (int e = 0; e < 8; ++e) vv[e] += (float)rv[e];
            }
            half8 hv;
            #pragma unroll
            for (int e = 0; e < 8; ++e) hv[e] = (_Float16)fmaxf(vv[e], 0.f);
            *(half8*)&out[m*256 + eoc + u*8] = hv;
        }
    }
}

// ---------------- Z-power matrix + pole table (merged k_zw): zp[h][t][j] fp16, zwb ----------------
__global__ __launch_bounds__(128) void k_wzp(const float* __restrict__ log_dt,
        const float* __restrict__ lam_re, const float* __restrict__ lam_im,
        _Float16* __restrict__ zp, float4* __restrict__ zwbuf, int layer) {
    int hh = blockIdx.x;
    int t = threadIdx.x;
    int dn = t >> 1, c = t & 1, dir = dn >> 5, n = dn & 31;
    float dt = expf(log_dt[layer*H + hh]);
    float a  = dt * lam_re[layer*NST + n];
    float bi = dt * lam_im[layer*NST + n];
    float er = expf(a);
    float zre = er * cosf(bi), zim = er * sinf(bi);
    if (c == 0 && dir == 0) {
        float eC = expf(a * (float)CHUNK);
        float s, co; sincosf(bi * (float)CHUNK, &s, &co);
        zwbuf[hh*NST + n] = make_float4(zre, zim, eC*co, eC*s);
    }
    _Float16* dst = &zp[(size_t)hh*16384 + t*128];
    float cr = 1.f, ci = 0.f;
    for (int p = 0; p < 128; ++p) {
        float val = c ? ci : cr;
        dst[dir ? p : (127 - p)] = (_Float16)val;
        float nr = cr*zre - ci*zim;
        float ni = cr*zim + ci*zre;
        cr = nr; ci = ni;
    }
}

// ---------------- W_big[h][t][256] fp16 (+D folded into kf[0], +wg copy) ----------------
__global__ __launch_bounds__(128) void k_wkern(const float* __restrict__ log_dt,
        const float* __restrict__ lam_re, const float* __restrict__ lam_im,
        const float* __restrict__ W_re, const float* __restrict__ W_im,
        const float* __restrict__ Dv, const float* __restrict__ gw,
        _Float16* __restrict__ wbig, _Float16* __restrict__ wg, int layer) {
    __shared__ float kf[128], kb[128];
    __shared__ float E[128*129];
    const int hh = blockIdx.x;
    const int t = threadIdx.x;
    float dt = expf(log_dt[layer*H + hh]);
    float skf = 0.f, skb = 0.f;
    for (int n = 0; n < 32; ++n) {
        float a  = dt * lam_re[layer*NST + n];
        float bi = dt * lam_im[layer*NST + n];
        float wfr = W_re[((layer*2+0)*H + hh)*NST + n];
        float wfi = W_im[((layer*2+0)*H + hh)*NST + n];
        float wbr = W_re[((layer*2+1)*H + hh)*NST + n];
        float wbi = W_im[((layer*2+1)*H + hh)*NST + n];
        float e0 = expf(a*t), s0, c0; sincosf(bi*t, &s0, &c0);
        float zr0 = e0*c0, zi0 = e0*s0;
        skf = fmaf(wfr, zr0, skf) - wfi*zi0;
        skb = fmaf(wbr, zr0, skb) - wbi*zi0;
        float e1 = expf(a*(t+1)), s1, c1; sincosf(bi*(t+1), &s1, &c1);
        float zr1 = e1*c1, zi1 = e1*s1;
        E[t*129 + n]      = wfr*zr1 - wfi*zi1;
        E[t*129 + 32 + n] = -(wfr*zi1 + wfi*zr1);
        float e2 = expf(a*(127-t)), s2, c2; sincosf(bi*(127-t), &s2, &c2);
        float zr2 = e2*c2, zi2 = e2*s2;
        E[t*129 + 64 + n] = wbr*zr2 - wbi*zi2;
        E[t*129 + 96 + n] = -(wbr*zi2 + wbi*zr2);
    }
    // fold D*x into the Toeplitz diagonal: T[t][t] = kf[0] += D
    kf[t] = skf + ((t == 0) ? Dv[layer*H + hh] : 0.f);
    kb[t] = skb;
    __syncthreads();
    _Float16* dst = &wbig[(size_t)hh*32768];
    for (int idx = t; idx < 128*256; idx += 128) {
        int tt = idx >> 8, k = idx & 255;
        float v;
        if (k < 128) v = (k <= tt) ? kf[tt - k] : kb[k - tt - 1];
        else         v = E[tt*129 + (k - 128)];
        dst[idx] = (_Float16)v;
    }
    // glu weight pack: block hh copies rows o = 2hh, 2hh+1
    const float* gsrc = &gw[(size_t)layer*131072 + (size_t)hh*512];
    _Float16* gdst = &wg[(size_t)hh*512];
    for (int j = t; j < 512; j += 128) gdst[j] = (_Float16)gsrc[j];
}

// ---------------- decoder weight pack ----------------
__global__ void k_wdec(const float* __restrict__ dw, _Float16* __restrict__ wdk) {
    int idx = blockIdx.x*256 + threadIdx.x;
    if (idx >= 15*16*256) return;
    int cfull = idx & 255;
    int o = (idx >> 8) & 15;
    int k = idx >> 12;
    float v = (o < DOUT) ? dw[(o*H + cfull)*15 + k] : 0.f;
    int cc = cfull >> 5, cl = cfull & 31;
    int cq = cl >> 3, cb = cl & 7;
    wdk[cc*7680 + (k*16 + o)*32 + ((cq ^ SWZ(o))*8) + cb] = (_Float16)v;
}

// ---------------- FUSED DSS (v1 + conflict fixes); grid (H, 8) ----------------
// epilogue: D already folded into wbig diagonal -> pure gelu; yst padded stride 136 in sbuf.
__global__ __launch_bounds__(256) void k_dss(const _Float16* __restrict__ hm16,
        const _Float16* __restrict__ zp, const _Float16* __restrict__ wbig,
        const float4* __restrict__ zwb, _Float16* __restrict__ y16, int layer) {
    __shared__ _Float16 xbuf[4*64*32];    // 16KB
    __shared__ _Float16 bbuf[2*128*32];   // 16KB: zp dbuf -> stp
    __shared__ float    sbuf[64*128];     // 32KB: S f32 -> wbig dbuf -> yst (stride 136)
    _Float16* sb16 = (_Float16*)sbuf;

    const int tid = threadIdx.x;
    const int hh = blockIdx.x;
    const int b0 = blockIdx.y * 4;
    const int lane = tid & 63;
    const int w = tid >> 6;
    const int wn = w * 32;
    const int fr = lane & 15, kg = lane >> 4;

    #pragma unroll
    for (int i = 0; i < 4; ++i) {
        int g = i*256 + tid;
        int m = g >> 4, gi = g & 15;
        int kc = gi >> 2, q = gi & 3;
        uint4 v = *(const uint4*)&hm16[((size_t)((b0 + (m>>4))*H + hh))*L
                                       + (m&15)*128 + kc*32 + q*8];
        *(uint4*)&xbuf[kc*2048 + m*32 + ((q ^ SWZ(m))*8)] = v;
    }

    // ---- phase 1: S = x . zp^T ----
    f32x4 acc1[4][2];
    #pragma unroll
    for (int i = 0; i < 4; ++i)
        #pragma unroll
        for (int j = 0; j < 2; ++j)
            #pragma unroll
            for (int k = 0; k < 4; ++k) acc1[i][j][k] = 0.f;
    const _Float16* zb = &zp[(size_t)hh*16384];
    const int gr0 = tid >> 2, gq0 = tid & 3;
    const int gr1 = 64 + gr0;
    uint4 pb0 = *(const uint4*)&zb[gr0*128 + gq0*8];
    uint4 pb1 = *(const uint4*)&zb[gr1*128 + gq0*8];
    for (int kc = 0; kc < 4; ++kc) {
        __syncthreads();
        *(uint4*)&bbuf[(kc&1)*4096 + gr0*32 + ((gq0 ^ SWZ(gr0))*8)] = pb0;
        *(uint4*)&bbuf[(kc&1)*4096 + gr1*32 + ((gq0 ^ SWZ(gr1))*8)] = pb1;
        if (kc < 3) {
            pb0 = *(const uint4*)&zb[gr0*128 + (kc+1)*32 + gq0*8];
            pb1 = *(const uint4*)&zb[gr1*128 + (kc+1)*32 + gq0*8];
        }
        __syncthreads();
        half8 af[4], bf2[2];
        #pragma unroll
        for (int mf = 0; mf < 4; ++mf) {
            int ra = mf*16 + fr;
            af[mf] = *(const half8*)&xbuf[kc*2048 + ra*32 + ((kg ^ SWZ(ra))*8)];
        }
        #pragma unroll
        for (int nf = 0; nf < 2; ++nf) {
            int rb = wn + nf*16 + fr;
            bf2[nf] = *(const half8*)&bbuf[(kc&1)*4096 + rb*32 + ((kg ^ SWZ(rb))*8)];
        }
        #pragma unroll
        for (int mf = 0; mf < 4; ++mf)
            #pragma unroll
            for (int nf = 0; nf < 2; ++nf)
                acc1[mf][nf] = __builtin_amdgcn_mfma_f32_16x16x32_f16(af[mf], bf2[nf], acc1[mf][nf], 0, 0, 0);
    }
    #pragma unroll
    for (int mf = 0; mf < 4; ++mf)
        #pragma unroll
        for (int nf = 0; nf < 2; ++nf)
            #pragma unroll
            for (int rg = 0; rg < 4; ++rg)
                sbuf[(mf*16 + kg*4 + rg)*128 + wn + nf*16 + fr] = acc1[mf][nf][rg];
    __syncthreads();

    // ---- phase 2: in-LDS cross-chunk scan (f32) -> stp fp16 in bbuf ----
    {
        int b_loc = tid >> 6, dn = tid & 63;
        int dir = dn >> 5, n = dn & 31;
        float4 z4 = zwb[hh*NST + n];
        float zcre = z4.z, zcim = z4.w;
        int q1 = n >> 3, e1 = n & 7;
        float pre = 0.f, pim = 0.f;
        for (int s = 0; s < NCH; ++s) {
            int ch = dir ? (NCH - 1 - s) : s;
            int m = b_loc*16 + ch;
            bbuf[(dir*2 + 0)*2048 + m*32 + ((q1 ^ SWZ(m))*8) + e1] = (_Float16)pre;
            bbuf[(dir*2 + 1)*2048 + m*32 + ((q1 ^ SWZ(m))*8) + e1] = (_Float16)pim;
            float cre = sbuf[m*128 + dn*2];
            float cim = sbuf[m*128 + dn*2 + 1];
            float nre = fmaf(zcre, pre, fmaf(-zcim, pim, cre));
            float nim = fmaf(zcre, pim, fmaf(zcim, pre, cim));
            pre = nre; pim = nim;
        }
    }
    __syncthreads();

    // ---- phase 3: y = [x | stp] . wbig^T ----
    f32x4 acc3[4][2];
    #pragma unroll
    for (int i = 0; i < 4; ++i)
        #pragma unroll
        for (int j = 0; j < 2; ++j)
            #pragma unroll
            for (int k = 0; k < 4; ++k) acc3[i][j][k] = 0.f;
    const _Float16* wb = &wbig[(size_t)hh*32768];
    pb0 = *(const uint4*)&wb[gr0*256 + gq0*8];
    pb1 = *(const uint4*)&wb[gr1*256 + gq0*8];
    for (int kc = 0; kc < 8; ++kc) {
        __syncthreads();
        *(uint4*)&sb16[(kc&1)*4096 + gr0*32 + ((gq0 ^ SWZ(gr0))*8)] = pb0;
        *(uint4*)&sb16[(kc&1)*4096 + gr1*32 + ((gq0 ^ SWZ(gr1))*8)] = pb1;
        if (kc < 7) {
            pb0 = *(const uint4*)&wb[gr0*256 + (kc+1)*32 + gq0*8];
            pb1 = *(const uint4*)&wb[gr1*256 + (kc+1)*32 + gq0*8];
        }
        __syncthreads();
        half8 af[4], bf2[2];
        #pragma unroll
        for (int mf = 0; mf < 4; ++mf) {
            int ra = mf*16 + fr;
            af[mf] = (kc < 4)
                ? *(const half8*)&xbuf[kc*2048 + ra*32 + ((kg ^ SWZ(ra))*8)]
                : *(const half8*)&bbuf[(kc-4)*2048 + ra*32 + ((kg ^ SWZ(ra))*8)];
        }
        #pragma unroll
        for (int nf = 0; nf < 2; ++nf) {
            int rb = wn + nf*16 + fr;
            bf2[nf] = *(const half8*)&sb16[(kc&1)*4096 + rb*32 + ((kg ^ SWZ(rb))*8)];
        }
        #pragma unroll
        for (int mf = 0; mf < 4; ++mf)
            #pragma unroll
            for (int nf = 0; nf < 2; ++nf)
                acc3[mf][nf] = __builtin_amdgcn_mfma_f32_16x16x32_f16(af[mf], bf2[nf], acc3[mf][nf], 0, 0, 0);
    }
    __syncthreads();                       // all sb16 panel reads complete
    _Float16* yst = sb16;                  // 64 rows x stride 136 (bank-spread)
    #pragma unroll
    for (int mf = 0; mf < 4; ++mf) {
        #pragma unroll
        for (int rg = 0; rg < 4; ++rg) {
            int m = mf*16 + kg*4 + rg;
            #pragma unroll
            for (int nf = 0; nf < 2; ++nf) {
                int t = wn + nf*16 + fr;
                yst[m*136 + t] = (_Float16)gelu_exact(acc3[mf][nf][rg]);
            }
        }
    }
    __syncthreads();
    {
        int r = tid >> 2, tc = (tid & 3) * 32;
        size_t gb = ((size_t)((b0 + (r>>4))*H + hh))*L + (r&15)*128;
        #pragma unroll
        for (int u = 0; u < 4; ++u)
            *(half8*)&y16[gb + tc + u*8] = *(half8*)&yst[r*136 + tc + u*8];
    }
}

// ---------------- GLU MFMA fp16 -> fp16 zc, coalesced epilogue; grid (B*L/128, 4) ----------------
__global__ __launch_bounds__(256) void k_glu16(const _Float16* __restrict__ yt,
        const _Float16* __restrict__ wg, const float* __restrict__ bias,
        _Float16* __restrict__ zc) {
    __shared__ _Float16 a_lds[128*32];
    __shared__ _Float16 b_lds[128*32];
    __shared__ float    ep[32*64];
    const int tid = threadIdx.x;
    const int mbase = blockIdx.x * 128;
    const int o0 = blockIdx.y * 64;
    const int lane = tid & 63;
    const int w = tid >> 6;
    const int wm = (w >> 1) * 64, wn = (w & 1) * 32;
    const int fr = lane & 15, kg = lane >> 4;
    const int r0s = tid >> 2, q0 = tid & 3;
    const int r1s = 64 + r0s;
    const int aw0 = r0s*32 + ((q0 ^ SWZ(r0s)) * 8);
    const int aw1 = r1s*32 + ((q0 ^ SWZ(r1s)) * 8);
    const int og0 = o0 + r0s;
    const int og1 = 256 + o0 + r0s;

    f32x4 accg[4][2], accs[4][2];
    #pragma unroll
    for (int i = 0; i < 4; ++i)
        #pragma unroll
        for (int j = 0; j < 2; ++j)
            #pragma unroll
            for (int k = 0; k < 4; ++k) { accg[i][j][k] = 0.f; accs[i][j][k] = 0.f; }

    uint4 pa0, pa1, pb0, pb1;
    auto loadstep = [&](int kc, uint4& a0, uint4& a1, uint4& b0, uint4& b1) {
        const int cb = kc*32 + q0*8;
        a0 = *(const uint4*)&yt[((size_t)(mbase + r0s))*256 + cb];
        a1 = *(const uint4*)&yt[((size_t)(mbase + r1s))*256 + cb];
        b0 = *(const uint4*)&wg[((size_t)og0)*256 + cb];
        b1 = *(const uint4*)&wg[((size_t)og1)*256 + cb];
    };
    loadstep(0, pa0, pa1, pb0, pb1);
    for (int kc = 0; kc < 8; ++kc) {
        __syncthreads();
        *(uint4*)&a_lds[aw0] = pa0;
        *(uint4*)&a_lds[aw1] = pa1;
        *(uint4*)&b_lds[aw0] = pb0;
        *(uint4*)&b_lds[aw1] = pb1;
        uint4 na0 = make_uint4(0,0,0,0), na1 = na0, nb0 = na0, nb1 = na0;
        if (kc < 7) loadstep(kc+1, na0, na1, nb0, nb1);
        __syncthreads();
        half8 af[4], bg[2], bs[2];
        #pragma unroll
        for (int mf = 0; mf < 4; ++mf) {
            int ra = wm + mf*16 + fr;
            af[mf] = *(const half8*)&a_lds[ra*32 + ((kg ^ SWZ(ra)) * 8)];
        }
        #pragma unroll
        for (int nf = 0; nf < 2; ++nf) {
            int rb = wn + nf*16 + fr;
            bg[nf] = *(const half8*)&b_lds[rb*32 + ((kg ^ SWZ(rb)) * 8)];
            int rb2 = 64 + rb;
            bs[nf] = *(const half8*)&b_lds[rb2*32 + ((kg ^ SWZ(rb2)) * 8)];
        }
        #pragma unroll
        for (int mf = 0; mf < 4; ++mf)
            #pragma unroll
            for (int nf = 0; nf < 2; ++nf) {
                accg[mf][nf] = __builtin_amdgcn_mfma_f32_16x16x32_f16(af[mf], bg[nf], accg[mf][nf], 0, 0, 0);
                accs[mf][nf] = __builtin_amdgcn_mfma_f32_16x16x32_f16(af[mf], bs[nf], accs[mf][nf], 0, 0, 0);
            }
        pa0 = na0; pa1 = na1; pb0 = nb0; pb1 = nb1;
    }
    float b0v[2], b1v[2];
    #pragma unroll
    for (int nf = 0; nf < 2; ++nf) {
        int o = o0 + wn + nf*16 + fr;
        b0v[nf] = bias[o]; b1v[nf] = bias[256 + o];
    }
    const int er = tid >> 3, eoc = (tid & 7) * 8;
    #pragma unroll
    for (int mf = 0; mf < 4; ++mf) {
        __syncthreads();
        #pragma unroll
        for (int nf = 0; nf < 2; ++nf) {
            int ol = wn + nf*16 + fr;
            int srb = (w >> 1)*16 + kg*4;
            #pragma unroll
            for (int rg = 0; rg < 4; ++rg) {
                float g = accg[mf][nf][rg] + b0v[nf];
                float s = accs[mf][nf][rg] + b1v[nf];
                ep[(srb + rg)*64 + ol] = g / (1.f + expf(-s));
            }
        }
        __syncthreads();
        size_t m = (size_t)mbase + mf*16 + (er < 16 ? er : 48 + er);
        float4 v0 = *(float4*)&ep[er*64 + eoc];
        float4 v1 = *(float4*)&ep[er*64 + eoc + 4];
        half8 hv;
        hv[0]=(_Float16)v0.x; hv[1]=(_Float16)v0.y; hv[2]=(_Float16)v0.z; hv[3]=(_Float16)v0.w;
        hv[4]=(_Float16)v1.x; hv[5]=(_Float16)v1.y; hv[6]=(_Float16)v1.z; hv[7]=(_Float16)v1.w;
        *(half8*)&zc[m*256 + o0 + eoc] = hv;
    }
}

// ---------------- LayerNorm: fp16 residual stream; last layer adds species + outseq f32 ----------------
template<bool SP>
__global__ __launch_bounds__(256) void k_ln2(const _Float16* __restrict__ zc,
        _Float16* __restrict__ hm, const float* __restrict__ g, const float* __restrict__ bb,
        const int* __restrict__ xs, const float* __restrict__ emb,
        float* __restrict__ outseq) {
    __shared__ float tl[8992];
    int tid = threadIdx.x;
    int b = blockIdx.y;
    int l0 = blockIdx.x * 32;
    for (int j = tid; j < 1024; j += 256) {
        int c = j >> 2, l8 = (j & 3) * 8;
        half8 v = *(const half8*)&hm[((size_t)(b*H + c))*L + l0 + l8];
        #pragma unroll
        for (int e = 0; e < 8; ++e) tl[LDIDX(l8 + e, c)] = (float)v[e];
    }
    __syncthreads();
    int r = tid >> 3, p = tid & 7;
    float v[32];
    float sum = 0.f, ss = 0.f;
    const _Float16* zrow = &zc[((size_t)(b*L + l0 + r))*256 + p*32];
    #pragma unroll
    for (int q = 0; q < 4; ++q) {
        half8 z8 = *(const half8*)&zrow[q*8];
        #pragma unroll
        for (int i = 0; i < 8; ++i) {
            float hv = tl[LDIDX(r, p*32 + q*8 + i)];
            float vv = (float)z8[i] + hv;
            v[q*8+i] = vv;
            sum += vv; ss = fmaf(vv, vv, ss);
        }
    }
    sum += __shfl_xor(sum, 1); ss += __shfl_xor(ss, 1);
    sum += __shfl_xor(sum, 2); ss += __shfl_xor(ss, 2);
    sum += __shfl_xor(sum, 4); ss += __shfl_xor(ss, 4);
    float mu = sum * (1.f/256.f);
    float var = ss * (1.f/256.f) - mu*mu;
    float rs = rsqrtf(var + 1e-5f);
    int sp = SP ? xs[b] : 0;
    #pragma unroll
    for (int q = 0; q < 32; ++q) {
        int c = p*32 + q;
        float val = (v[q] - mu) * rs * g[c] + bb[c];
        if (SP) val += emb[sp*H + c];
        tl[LDIDX(r, c)] = val;
    }
    __syncthreads();
    for (int j = tid; j < 1024; j += 256) {
        int c = j >> 2, l8 = (j & 3) * 8;
        float fv[8];
        half8 hv;
        #pragma unroll
        for (int e = 0; e < 8; ++e) {
            fv[e] = tl[LDIDX(l8 + e, c)];
            hv[e] = (_Float16)fv[e];
        }
        *(half8*)&hm[((size_t)(b*H + c))*L + l0 + l8] = hv;
        if (SP) {
            *(float4*)&outseq[((size_t)(b*H + c))*L + l0 + l8] = make_float4(fv[0],fv[1],fv[2],fv[3]);
            *(float4*)&outseq[((size_t)(b*H + c))*L + l0 + l8 + 4] = make_float4(fv[4],fv[5],fv[6],fv[7]);
        }
    }
}

// ---------------- MFMA decoder conv K=15 ----------------
__global__ __launch_bounds__(128) void k_dec(const _Float16* __restrict__ ht,
        const _Float16* __restrict__ wdk, const float* __restrict__ bias,
        float* __restrict__ outdec) {
    __shared__ _Float16 a_lds[160*32];
    __shared__ _Float16 b_lds[15*16*32];
    const int tid = threadIdx.x;
    const int mbase = blockIdx.x * 128;
    const int b = mbase >> 11;
    const int lbase = mbase & 2047;
    const int lane = tid & 63;
    const int w = tid >> 6;
    const int fr = lane & 15, kg = lane >> 4;
    const int rs = tid >> 2, q0 = tid & 3;
    f32x4 acc[4];
    #pragma unroll
    for (int i = 0; i < 4; ++i)
        #pragma unroll
        for (int k = 0; k < 4; ++k) acc[i][k] = 0.f;
    for (int cc = 0; cc < 8; ++cc) {
        __syncthreads();
        #pragma unroll
        for (int ps = 0; ps < 5; ++ps) {
            int r = ps*32 + rs;
            if (r < 142) {
                int l = lbase - 7 + r;
                uint4 v = (l >= 0 && l < L) ? *(const uint4*)&ht[((size_t)(b*L + l))*256 + cc*32 + q0*8]
                                            : make_uint4(0,0,0,0);
                *(uint4*)&a_lds[r*32 + ((q0 ^ SWZ(r))*8)] = v;
            }
        }
        for (int jj = tid; jj < 960; jj += 128)
            *(uint4*)&b_lds[jj*8] = *(const uint4*)&wdk[cc*7680 + jj*8];
        __syncthreads();
        #pragma unroll
        for (int k = 0; k < 15; ++k) {
            half8 bfr = *(const half8*)&b_lds[(k*16 + fr)*32 + ((kg ^ SWZ(fr))*8)];
            #pragma unroll
            for (int mf = 0; mf < 4; ++mf) {
                int ra = w*64 + mf*16 + fr + k;
                half8 af = *(const half8*)&a_lds[ra*32 + ((kg ^ SWZ(ra))*8)];
                acc[mf] = __builtin_amdgcn_mfma_f32_16x16x32_f16(af, bfr, acc[mf], 0, 0, 0);
            }
        }
    }
    if (fr < DOUT) {
        float bo = bias[fr];
        #pragma unroll
        for (int mf = 0; mf < 4; ++mf)
            #pragma unroll
            for (int rg = 0; rg < 4; ++rg) {
                int m = mbase + w*64 + mf*16 + kg*4 + rg;
                outdec[((size_t)(b*DOUT + fr))*L + (m & 2047)] = acc[mf][rg] + bo;
            }
    }
}

// ---------------- mean over L (fp16 input) ----------------
__global__ __launch_bounds__(256) void k_agg(const _Float16* __restrict__ h, float* __restrict__ agg) {
    __shared__ float red[256];
    int bc = blockIdx.x;
    int tid = threadIdx.x;
    half8 v = *(const half8*)&h[(size_t)bc*L + tid*8];
    float s = 0.f;
    #pragma unroll
    for (int e = 0; e < 8; ++e) s += (float)v[e];
    red[tid] = s; __syncthreads();
    for (int k = 128; k > 0; k >>= 1) {
        if (tid < k) red[tid] += red[tid+k];
        __syncthreads();
    }
    if (tid == 0) agg[bc] = red[0] * (1.f/(float)L);
}

// ---------------- regression MLP ----------------
__global__ __launch_bounds__(128) void k_mlp(const float* __restrict__ agg,
        const float* __restrict__ w1, const float* __restrict__ b1,
        const float* __restrict__ w2, const float* __restrict__ b2,
        const float* __restrict__ w3, const float* __restrict__ b3,
        const float* __restrict__ w4, const float* __restrict__ b4,
        float* __restrict__ outreg) {
    __shared__ float a0[256], r1[128], r2[64], r3[32];
    int b = blockIdx.x, tid = threadIdx.x;
    a0[tid] = agg[b*256 + tid];
    a0[tid+128] = agg[b*256 + tid + 128];
    __syncthreads();
    {
        float s = b1[tid];
        for (int k = 0; k < 256; ++k) s = fmaf(w1[tid*256+k], a0[k], s);
        r1[tid] = s > 0.f ? s : expm1f(s);
    }
    __syncthreads();
    if (tid < 64) {
        float s = b2[tid];
        for (int k = 0; k < 128; ++k) s = fmaf(w2[tid*128+k], r1[k], s);
        r2[tid] = s > 0.f ? s : expm1f(s);
    }
    __syncthreads();
    if (tid < 32) {
        float s = b3[tid];
        for (int k = 0; k < 64; ++k) s = fmaf(w3[tid*64+k], r2[k], s);
        r3[tid] = s > 0.f ? s : expm1f(s);
    }
    __syncthreads();
    if (tid == 0) {
        float s = b4[0];
        for (int k = 0; k < 32; ++k) s = fmaf(w4[k], r3[k], s);
        outreg[b] = s;
    }
}

extern "C" void kernel_launch(void* const* d_in, const int* in_sizes, int n_in,
                              void* d_out, int out_size, void* d_ws, size_t ws_size,
                              hipStream_t stream) {
    const float* x      = (const float*)d_in[0];
    const int*   xs     = (const int*)d_in[1];
    const float* enc_w  = (const float*)d_in[2];
    const float* enc_b  = (const float*)d_in[3];
    const float* res_w1 = (const float*)d_in[4];
    const float* res_b1 = (const float*)d_in[5];
    const float* res_w2 = (const float*)d_in[6];
    const float* res_b2 = (const float*)d_in[7];
    const float* log_dt = (const float*)d_in[8];
    const float* lam_re = (const float*)d_in[9];
    const float* lam_im = (const float*)d_in[10];
    const float* W_re   = (const float*)d_in[11];
    const float* W_im   = (const float*)d_in[12];
    const float* Dv     = (const float*)d_in[13];
    const float* glu_w  = (const float*)d_in[14];
    const float* glu_b  = (const float*)d_in[15];
    const float* ln_g   = (const float*)d_in[16];
    const float* ln_b   = (const float*)d_in[17];
    const float* dec_w  = (const float*)d_in[18];
    const float* dec_b  = (const float*)d_in[19];
    const float* sp_emb = (const float*)d_in[20];
    const float* h1_w = (const float*)d_in[21]; const float* h1_b = (const float*)d_in[22];
    const float* h2_w = (const float*)d_in[23]; const float* h2_b = (const float*)d_in[24];
    const float* h3_w = (const float*)d_in[25]; const float* h3_b = (const float*)d_in[26];
    const float* h4_w = (const float*)d_in[27]; const float* h4_b = (const float*)d_in[28];

    float* ws   = (float*)d_ws;
    _Float16* hm16 = (_Float16*)ws;                    // fp16 chm residual (persistent)
    float* t1   = ws + (size_t)LSEQ;
    float* t2   = ws + (size_t)2*LSEQ;
    // res-phase:
    _Float16* xb  = (_Float16*)t1;
    _Float16* xa  = (_Float16*)t1 + (size_t)LSEQ;
    _Float16* wpk = (_Float16*)t2;
    // DSS-phase:
    _Float16* yt   = (_Float16*)t1;                    // fp16 chl y (t1 lower)
    _Float16* wbig = (_Float16*)t1 + (size_t)LSEQ;     // 16MB (t1 upper)
    _Float16* zp   = wbig + (size_t)H*32768;           // 8MB
    _Float16* y16  = (_Float16*)t2;                    // fp16 chm y
    _Float16* zc16 = (_Float16*)t2;                    // glu out fp16 chl (y16 dead)
    _Float16* dect = (_Float16*)t1;                    // decoder chl input
    // tail:
    float* tail = ws + (size_t)3*LSEQ;
    _Float16* wg  = (_Float16*)tail;
    float4* zwb = (float4*)(tail + 65536);
    float* aggb = tail + 65536 + 32768;
    _Float16* wdk = (_Float16*)(aggb + 8192);
    _Float16* wenc = wdk + 61440;

    float* outdec = (float*)d_out;
    float* outseq = outdec + B*DOUT*L;
    float* outreg = outseq + (size_t)LSEQ;

    // encoder
    k_wenc<<<96, 256, 0, stream>>>(enc_w, wenc);
    k_enc<<<dim3(B*L/128, 2), 256, 0, stream>>>(x, wenc, enc_b, xa);

    // residual stack
    k_wpack<<<(NRES*2*3*65536 + 255)/256, 256, 0, stream>>>(res_w1, res_w2, wpk);
    for (int r = 0; r < NRES; ++r) {
        k_cv3<false><<<B*L/128, 256, 0, stream>>>(
            xa, wpk + (size_t)(r*2+0)*3*65536, res_b1 + r*H, nullptr, xb);
        k_cv3<true><<<B*L/128, 256, 0, stream>>>(
            xb, wpk + (size_t)(r*2+1)*3*65536, res_b2 + r*H, xa, xa);
    }
    k_t_cf16<<<dim3(L/64, H/64, B), 256, 0, stream>>>(xa, hm16);

    // DSS blocks
    for (int i = 0; i < NLAYERS; ++i) {
        k_wzp<<<H, 128, 0, stream>>>(log_dt, lam_re, lam_im, zp, zwb, i);
        k_wkern<<<H, 128, 0, stream>>>(log_dt, lam_re, lam_im, W_re, W_im, Dv, glu_w,
                                       wbig, wg, i);
        k_dss<<<dim3(H, 8), 256, 0, stream>>>(hm16, zp, wbig, zwb, y16, i);
        k_t16<<<dim3(L/64, H/64, B), 256, 0, stream>>>(y16, yt);
        k_glu16<<<dim3(B*L/128, 4), 256, 0, stream>>>(yt, wg, glu_b + i*512, zc16);
        if (i < NLAYERS - 1)
            k_ln2<false><<<dim3(L/32, B), 256, 0, stream>>>(zc16, hm16, ln_g + i*H, ln_b + i*H,
                                                            nullptr, nullptr, nullptr);
        else
            k_ln2<true><<<dim3(L/32, B), 256, 0, stream>>>(zc16, hm16, ln_g + i*H, ln_b + i*H,
                                                           xs, sp_emb, outseq);
    }

    // aggregate + regression head
    k_agg<<<B*H, 256, 0, stream>>>(hm16, aggb);
    k_mlp<<<B, 128, 0, stream>>>(aggb, h1_w, h1_b, h2_w, h2_b, h3_w, h3_b, h4_w, h4_b, outreg);
    // decoder
    k_t16<<<dim3(L/64, H/64, B), 256, 0, stream>>>(hm16, dect);
    k_wdec<<<(15*16*256 + 255)/256, 256, 0, stream>>>(dec_w, wdk);
    k_dec<<<B*L/128, 128, 0, stream>>>(dect, wdk, dec_b, outdec);
}

// Round 13
// 1091.676 us; speedup vs baseline: 1.1414x; 1.0314x over previous
//
#include <hip/hip_runtime.h>
#include <math.h>

#define B 32
#define L 2048
#define DIN 5
#define DOUT 5
#define H 256
#define NST 32
#define NLAYERS 4
#define NRES 3
#define CHUNK 128
#define NCH 16            // L / CHUNK
#define LSEQ (B*H*L)      // 16777216

typedef __attribute__((ext_vector_type(8))) _Float16 half8;
typedef __attribute__((ext_vector_type(4))) float f32x4;

__device__ __forceinline__ float gelu_exact(float v) {
    return 0.5f * v * (1.0f + erff(v * 0.7071067811865475f));
}
#define SWZ(r) ((((r) ^ ((r) >> 2)) & 3))
#define LDIDX(l, c) ((l)*281 + ((c)>>5)*35 + ((c)&31))

// ---------------- encoder weight pack ----------------
__global__ void k_wenc(const float* __restrict__ ew, _Float16* __restrict__ wenc) {
    int idx = blockIdx.x*256 + threadIdx.x;
    if (idx >= 256*96) return;
    int o = idx / 96, kk = idx % 96;
    int ci = kk >> 4, k = kk & 15;
    float v = (ci < DIN && k < 15) ? ew[(o*DIN + ci)*15 + k] : 0.f;
    wenc[idx] = (_Float16)v;
}

// ---------------- MFMA encoder conv K=15 Cin=5 ----------------
__global__ __launch_bounds__(256) void k_enc(const float* __restrict__ x,
        const _Float16* __restrict__ wenc, const float* __restrict__ bias,
        _Float16* __restrict__ out) {
    __shared__ _Float16 a_lds[3*128*32];
    __shared__ _Float16 b_lds[3*128*32];
    const int tid = threadIdx.x;
    const int mbase = blockIdx.x * 128;
    const int oh = blockIdx.y;
    const int b = mbase >> 11;
    const int lbase = mbase & 2047;
    const int lane = tid & 63;
    const int w = tid >> 6;
    const int wm = (w >> 1) * 64, wn = (w & 1) * 64;
    const int fr = lane & 15, kg = lane >> 4;

    #pragma unroll
    for (int i = 0; i < 6; ++i) {
        int g = i*256 + tid;
        int r = g / 12, rem = g % 12;
        int ks = rem >> 2, q = rem & 3;
        int kk0 = ks*32 + q*8;
        int ci = kk0 >> 4, k0 = kk0 & 15;
        half8 va;
        #pragma unroll
        for (int e = 0; e < 8; ++e) {
            int k = k0 + e;
            int l = lbase + r - 7 + k;
            float v = (ci < DIN && k < 15 && l >= 0 && l < L)
                        ? x[((size_t)(b*DIN + ci))*L + l] : 0.f;
            va[e] = (_Float16)v;
        }
        *(half8*)&a_lds[ks*4096 + r*32 + ((q ^ SWZ(r))*8)] = va;
        uint4 vb = *(const uint4*)&wenc[(size_t)(oh*128 + r)*96 + kk0];
        *(uint4*)&b_lds[ks*4096 + r*32 + ((q ^ SWZ(r))*8)] = vb;
    }
    __syncthreads();
    f32x4 acc[4][4];
    #pragma unroll
    for (int i = 0; i < 4; ++i)
        #pragma unroll
        for (int j = 0; j < 4; ++j)
            #pragma unroll
            for (int k = 0; k < 4; ++k) acc[i][j][k] = 0.f;
    #pragma unroll
    for (int ks = 0; ks < 3; ++ks) {
        half8 af[4], bfr[4];
        #pragma unroll
        for (int mf = 0; mf < 4; ++mf) {
            int ra = wm + mf*16 + fr;
            af[mf] = *(const half8*)&a_lds[ks*4096 + ra*32 + ((kg ^ SWZ(ra))*8)];
        }
        #pragma unroll
        for (int nf = 0; nf < 4; ++nf) {
            int rb = wn + nf*16 + fr;
            bfr[nf] = *(const half8*)&b_lds[ks*4096 + rb*32 + ((kg ^ SWZ(rb))*8)];
        }
        #pragma unroll
        for (int mf = 0; mf < 4; ++mf)
            #pragma unroll
            for (int nf = 0; nf < 4; ++nf)
                acc[mf][nf] = __builtin_amdgcn_mfma_f32_16x16x32_f16(af[mf], bfr[nf], acc[mf][nf], 0, 0, 0);
    }
    #pragma unroll
    for (int nf = 0; nf < 4; ++nf) {
        int o = oh*128 + wn + nf*16 + fr;
        float bo = bias[o];
        #pragma unroll
        for (int mf = 0; mf < 4; ++mf)
            #pragma unroll
            for (int rg = 0; rg < 4; ++rg) {
                size_t m = (size_t)mbase + wm + mf*16 + kg*4 + rg;
                out[m*256 + o] = (_Float16)(acc[mf][nf][rg] + bo);
            }
    }
}

// ---------------- res weight pack ----------------
__global__ void k_wpack(const float* __restrict__ w1, const float* __restrict__ w2,
                        _Float16* __restrict__ wpk) {
    int idx = blockIdx.x*256 + threadIdx.x;
    if (idx >= NRES*2*3*65536) return;
    int ci = idx & 255;
    int o  = (idx >> 8) & 255;
    int k  = (idx >> 16) % 3;
    int cv = idx / (3*65536);
    const float* src = (cv & 1) ? w2 : w1;
    wpk[idx] = (_Float16)src[(((cv>>1)*H + o)*H + ci)*3 + k];
}

// ---------------- transpose fp16 chl -> fp16 chm ----------------
__global__ __launch_bounds__(256) void k_t_cf16(const _Float16* __restrict__ in,
        _Float16* __restrict__ out) {
    __shared__ float t[64][65];
    int tid = threadIdx.x;
    int l0 = blockIdx.x*64, c0 = blockIdx.y*64, b = blockIdx.z;
    #pragma unroll
    for (int i = 0; i < 16; ++i) {
        int idx = i*256 + tid;
        int l = idx >> 6, c = idx & 63;
        t[c][l] = (float)in[((size_t)b*L + l0 + l)*256 + c0 + c];
    }
    __syncthreads();
    #pragma unroll
    for (int i = 0; i < 16; ++i) {
        int idx = i*256 + tid;
        int c = idx >> 6, l = idx & 63;
        out[((size_t)(b*H + c0 + c))*L + l0 + l] = (_Float16)t[c][l];
    }
}

// ---------------- transpose fp16 chm -> fp16 chl ----------------
__global__ __launch_bounds__(256) void k_t16(const _Float16* __restrict__ in,
                                             _Float16* __restrict__ out) {
    __shared__ float t[64][65];
    int tid = threadIdx.x;
    int l0 = blockIdx.x*64, c0 = blockIdx.y*64, b = blockIdx.z;
    #pragma unroll
    for (int i = 0; i < 16; ++i) {
        int idx = i*256 + tid;
        int c = idx >> 6, l = idx & 63;
        t[c][l] = (float)in[((size_t)(b*H + c0 + c))*L + l0 + l];
    }
    __syncthreads();
    #pragma unroll
    for (int i = 0; i < 16; ++i) {
        int idx = i*256 + tid;
        int l = idx >> 6, c = idx & 63;
        out[((size_t)b*L + l0 + l)*256 + c0 + c] = (_Float16)t[c][l];
    }
}

// ---------------- MFMA residual conv K=3: full-N tile 128m x 256o, coalesced epilogue ----------------
template<bool RESID>
__global__ __launch_bounds__(256, 2) void k_cv3(const _Float16* __restrict__ xin,
        const _Float16* __restrict__ wpk, const float* __restrict__ bias,
        const _Float16* __restrict__ resid, _Float16* __restrict__ out) {
    __shared__ _Float16 a_lds[128*32];
    __shared__ _Float16 b_lds[256*32];
    __shared__ float    ep[32*256];
    const int tid = threadIdx.x;
    const int mbase = blockIdx.x * 128;
    const int lane = tid & 63;
    const int w = tid >> 6;
    const int wm = (w >> 1) * 64, wo = (w & 1) * 128;
    const int fr = lane & 15, kg = lane >> 4;

    const int r0s = tid >> 2, q0 = tid & 3;
    const int sq = SWZ(r0s);
    const int awA0 = r0s*32 + ((q0 ^ sq) * 8);
    const int awA1 = (64 + r0s)*32 + ((q0 ^ SWZ(64 + r0s)) * 8);

    f32x4 acc[4][8];
    #pragma unroll
    for (int i = 0; i < 4; ++i)
        #pragma unroll
        for (int j = 0; j < 8; ++j)
            #pragma unroll
            for (int k = 0; k < 4; ++k) acc[i][j][k] = 0.f;

    uint4 pa0, pa1, pb[4];
    auto loadstep = [&](int kk, uint4& a0, uint4& a1, uint4 (&bb)[4]) {
        const int koff = kk >> 3, cic = kk & 7;
        const int cb = cic*32 + q0*8;
        {
            int m = mbase + r0s;
            int ll = (m & (L-1)) + koff - 1;
            a0 = (ll >= 0 && ll < L) ? *(const uint4*)&xin[((size_t)(m + koff - 1))*256 + cb]
                                     : make_uint4(0,0,0,0);
            int m1 = mbase + 64 + r0s;
            int l1 = (m1 & (L-1)) + koff - 1;
            a1 = (l1 >= 0 && l1 < L) ? *(const uint4*)&xin[((size_t)(m1 + koff - 1))*256 + cb]
                                     : make_uint4(0,0,0,0);
        }
        #pragma unroll
        for (int u = 0; u < 4; ++u)
            bb[u] = *(const uint4*)&wpk[((size_t)(koff*256 + u*64 + r0s))*256 + cb];
    };
    loadstep(0, pa0, pa1, pb);
    for (int kk = 0; kk < 24; ++kk) {
        __syncthreads();
        *(uint4*)&a_lds[awA0] = pa0;
        *(uint4*)&a_lds[awA1] = pa1;
        #pragma unroll
        for (int u = 0; u < 4; ++u)
            *(uint4*)&b_lds[(u*64 + r0s)*32 + ((q0 ^ sq)*8)] = pb[u];
        uint4 na0 = make_uint4(0,0,0,0), na1 = na0, nb[4] = {na0, na0, na0, na0};
        if (kk < 23) loadstep(kk+1, na0, na1, nb);
        __syncthreads();
        half8 af[4];
        #pragma unroll
        for (int mf = 0; mf < 4; ++mf) {
            int ra = wm + mf*16 + fr;
            af[mf] = *(const half8*)&a_lds[ra*32 + ((kg ^ SWZ(ra)) * 8)];
        }
        #pragma unroll
        for (int nf = 0; nf < 8; ++nf) {
            int rb = wo + nf*16 + fr;
            half8 bfr = *(const half8*)&b_lds[rb*32 + ((kg ^ SWZ(rb)) * 8)];
            #pragma unroll
            for (int mf = 0; mf < 4; ++mf)
                acc[mf][nf] = __builtin_amdgcn_mfma_f32_16x16x32_f16(af[mf], bfr, acc[mf][nf], 0, 0, 0);
        }
        pa0 = na0; pa1 = na1;
        #pragma unroll
        for (int u = 0; u < 4; ++u) pb[u] = nb[u];
    }
    float bo8[8];
    #pragma unroll
    for (int nf = 0; nf < 8; ++nf) bo8[nf] = bias[wo + nf*16 + fr];
    const int er = tid >> 3, eoc = (tid & 7) * 32;
    #pragma unroll
    for (int mf = 0; mf < 4; ++mf) {
        __syncthreads();
        #pragma unroll
        for (int nf = 0; nf < 8; ++nf) {
            int o = wo + nf*16 + fr;
            int srb = (w >> 1)*16 + kg*4;
            #pragma unroll
            for (int rg = 0; rg < 4; ++rg)
                ep[(srb + rg)*256 + o] = acc[mf][nf][rg] + bo8[nf];
        }
        __syncthreads();
        size_t m = (size_t)mbase + mf*16 + (er < 16 ? er : 48 + er);
        #pragma unroll
        for (int u = 0; u < 4; ++u) {
            float4 v0 = *(float4*)&ep[er*256 + eoc + u*8];
            float4 v1 = *(float4*)&ep[er*256 + eoc + u*8 + 4];
            float vv[8] = {v0.x, v0.y, v0.z, v0.w, v1.x, v1.y, v1.z, v1.w};
            if (RESID) {
                half8 rv = *(const half8*)&resid[m*256 + eoc + u*8];
                #pragma unroll
                for (int e = 0; e < 8; ++e) vv[e] += (float)rv[e];
            }
            half8 hv;
            #pragma unroll
            for (int e = 0; e < 8; ++e) hv[e] = (_Float16)fmaxf(vv[e], 0.f);
            *(half8*)&out[m*256 + eoc + u*8] = hv;
        }
    }
}

// ---------------- Z-power matrix + pole table: zp[h][t][j] fp16, zwb ----------------
__global__ __launch_bounds__(128) void k_wzp(const float* __restrict__ log_dt,
        const float* __restrict__ lam_re, const float* __restrict__ lam_im,
        _Float16* __restrict__ zp, float4* __restrict__ zwbuf, int layer) {
    int hh = blockIdx.x;
    int t = threadIdx.x;
    int dn = t >> 1, c = t & 1, dir = dn >> 5, n = dn & 31;
    float dt = expf(log_dt[layer*H + hh]);
    float a  = dt * lam_re[layer*NST + n];
    float bi = dt * lam_im[layer*NST + n];
    float er = expf(a);
    float zre = er * cosf(bi), zim = er * sinf(bi);
    if (c == 0 && dir == 0) {
        float eC = expf(a * (float)CHUNK);
        float s, co; sincosf(bi * (float)CHUNK, &s, &co);
        zwbuf[hh*NST + n] = make_float4(zre, zim, eC*co, eC*s);
    }
    _Float16* dst = &zp[(size_t)hh*16384 + t*128];
    float cr = 1.f, ci = 0.f;
    for (int p = 0; p < 128; ++p) {
        float val = c ? ci : cr;
        dst[dir ? p : (127 - p)] = (_Float16)val;
        float nr = cr*zre - ci*zim;
        float ni = cr*zim + ci*zre;
        cr = nr; ci = ni;
    }
}

// ---------------- W_big[h][t][256] fp16 (+D folded into kf[0], +wg copy) ----------------
__global__ __launch_bounds__(128) void k_wkern(const float* __restrict__ log_dt,
        const float* __restrict__ lam_re, const float* __restrict__ lam_im,
        const float* __restrict__ W_re, const float* __restrict__ W_im,
        const float* __restrict__ Dv, const float* __restrict__ gw,
        _Float16* __restrict__ wbig, _Float16* __restrict__ wg, int layer) {
    __shared__ float kf[128], kb[128];
    __shared__ float E[128*129];
    const int hh = blockIdx.x;
    const int t = threadIdx.x;
    float dt = expf(log_dt[layer*H + hh]);
    float skf = 0.f, skb = 0.f;
    for (int n = 0; n < 32; ++n) {
        float a  = dt * lam_re[layer*NST + n];
        float bi = dt * lam_im[layer*NST + n];
        float wfr = W_re[((layer*2+0)*H + hh)*NST + n];
        float wfi = W_im[((layer*2+0)*H + hh)*NST + n];
        float wbr = W_re[((layer*2+1)*H + hh)*NST + n];
        float wbi = W_im[((layer*2+1)*H + hh)*NST + n];
        float e0 = expf(a*t), s0, c0; sincosf(bi*t, &s0, &c0);
        float zr0 = e0*c0, zi0 = e0*s0;
        skf = fmaf(wfr, zr0, skf) - wfi*zi0;
        skb = fmaf(wbr, zr0, skb) - wbi*zi0;
        float e1 = expf(a*(t+1)), s1, c1; sincosf(bi*(t+1), &s1, &c1);
        float zr1 = e1*c1, zi1 = e1*s1;
        E[t*129 + n]      = wfr*zr1 - wfi*zi1;
        E[t*129 + 32 + n] = -(wfr*zi1 + wfi*zr1);
        float e2 = expf(a*(127-t)), s2, c2; sincosf(bi*(127-t), &s2, &c2);
        float zr2 = e2*c2, zi2 = e2*s2;
        E[t*129 + 64 + n] = wbr*zr2 - wbi*zi2;
        E[t*129 + 96 + n] = -(wbr*zi2 + wbi*zr2);
    }
    kf[t] = skf + ((t == 0) ? Dv[layer*H + hh] : 0.f);
    kb[t] = skb;
    __syncthreads();
    _Float16* dst = &wbig[(size_t)hh*32768];
    for (int idx = t; idx < 128*256; idx += 128) {
        int tt = idx >> 8, k = idx & 255;
        float v;
        if (k < 128) v = (k <= tt) ? kf[tt - k] : kb[k - tt - 1];
        else         v = E[tt*129 + (k - 128)];
        dst[idx] = (_Float16)v;
    }
    const float* gsrc = &gw[(size_t)layer*131072 + (size_t)hh*512];
    _Float16* gdst = &wg[(size_t)hh*512];
    for (int j = t; j < 512; j += 128) gdst[j] = (_Float16)gsrc[j];
}

// ---------------- decoder weight pack ----------------
__global__ void k_wdec(const float* __restrict__ dw, _Float16* __restrict__ wdk) {
    int idx = blockIdx.x*256 + threadIdx.x;
    if (idx >= 15*16*256) return;
    int cfull = idx & 255;
    int o = (idx >> 8) & 15;
    int k = idx >> 12;
    float v = (o < DOUT) ? dw[(o*H + cfull)*15 + k] : 0.f;
    int cc = cfull >> 5, cl = cfull & 31;
    int cq = cl >> 3, cb = cl & 7;
    wdk[cc*7680 + (k*16 + o)*32 + ((cq ^ SWZ(o))*8) + cb] = (_Float16)v;
}

// ---------------- FUSED DSS v3: M=32 (grid H x 16), 40KB LDS (4 blk/CU), single-barrier dbuf ----------------
__global__ __launch_bounds__(256, 4) void k_dss(const _Float16* __restrict__ hm16,
        const _Float16* __restrict__ zp, const _Float16* __restrict__ wbig,
        const float4* __restrict__ zwb, _Float16* __restrict__ y16, int layer) {
    __shared__ _Float16 xbuf[4*32*32];    // 8KB: x fp16, 4 K-panels of 32 rows
    __shared__ _Float16 bbuf[2*128*32];   // 16KB: zp dbuf slots -> stp (4 panels 32x32)
    __shared__ float    sbuf[32*128];     // 16KB: S f32 -> wbig dbuf (sb16) -> yst
    _Float16* sb16 = (_Float16*)sbuf;

    const int tid = threadIdx.x;
    const int hh = blockIdx.x;
    const int b0 = blockIdx.y * 2;
    const int lane = tid & 63;
    const int w = tid >> 6;
    const int wn = w * 32;
    const int fr = lane & 15, kg = lane >> 4;

    // stage x (32 rows x 128 j)
    #pragma unroll
    for (int i = 0; i < 2; ++i) {
        int g = i*256 + tid;
        int m = g >> 4, gi = g & 15;
        int kc = gi >> 2, q = gi & 3;
        uint4 v = *(const uint4*)&hm16[((size_t)((b0 + (m>>4))*H + hh))*L
                                       + (m&15)*128 + kc*32 + q*8];
        *(uint4*)&xbuf[kc*1024 + m*32 + ((q ^ SWZ(m))*8)] = v;
    }

    // ---- phase 1: S = x . zp^T (single-barrier dbuf) ----
    f32x4 acc1[2][2];
    #pragma unroll
    for (int i = 0; i < 2; ++i)
        #pragma unroll
        for (int j = 0; j < 2; ++j)
            #pragma unroll
            for (int k = 0; k < 4; ++k) acc1[i][j][k] = 0.f;
    const _Float16* zb = &zp[(size_t)hh*16384];
    const int gr0 = tid >> 2, gq0 = tid & 3;
    const int gr1 = 64 + gr0;
    const int bw0 = gr0*32 + ((gq0 ^ SWZ(gr0))*8);
    const int bw1 = gr1*32 + ((gq0 ^ SWZ(gr1))*8);
    uint4 pb0 = *(const uint4*)&zb[gr0*128 + gq0*8];
    uint4 pb1 = *(const uint4*)&zb[gr1*128 + gq0*8];
    *(uint4*)&bbuf[bw0] = pb0;
    *(uint4*)&bbuf[bw1] = pb1;
    pb0 = *(const uint4*)&zb[gr0*128 + 32 + gq0*8];
    pb1 = *(const uint4*)&zb[gr1*128 + 32 + gq0*8];
    __syncthreads();
    for (int kc = 0; kc < 4; ++kc) {
        if (kc < 3) {
            *(uint4*)&bbuf[((kc+1)&1)*4096 + bw0] = pb0;
            *(uint4*)&bbuf[((kc+1)&1)*4096 + bw1] = pb1;
            if (kc < 2) {
                pb0 = *(const uint4*)&zb[gr0*128 + (kc+2)*32 + gq0*8];
                pb1 = *(const uint4*)&zb[gr1*128 + (kc+2)*32 + gq0*8];
            }
        }
        half8 af[2], bf2[2];
        #pragma unroll
        for (int mf = 0; mf < 2; ++mf) {
            int ra = mf*16 + fr;
            af[mf] = *(const half8*)&xbuf[kc*1024 + ra*32 + ((kg ^ SWZ(ra))*8)];
        }
        #pragma unroll
        for (int nf = 0; nf < 2; ++nf) {
            int rb = wn + nf*16 + fr;
            bf2[nf] = *(const half8*)&bbuf[(kc&1)*4096 + rb*32 + ((kg ^ SWZ(rb))*8)];
        }
        #pragma unroll
        for (int mf = 0; mf < 2; ++mf)
            #pragma unroll
            for (int nf = 0; nf < 2; ++nf)
                acc1[mf][nf] = __builtin_amdgcn_mfma_f32_16x16x32_f16(af[mf], bf2[nf], acc1[mf][nf], 0, 0, 0);
        __syncthreads();
    }
    // dump S (f32)
    #pragma unroll
    for (int mf = 0; mf < 2; ++mf)
        #pragma unroll
        for (int nf = 0; nf < 2; ++nf)
            #pragma unroll
            for (int rg = 0; rg < 4; ++rg)
                sbuf[(mf*16 + kg*4 + rg)*128 + wn + nf*16 + fr] = acc1[mf][nf][rg];
    __syncthreads();

    // ---- phase 2: in-LDS cross-chunk scan (f32) -> stp fp16 in bbuf (threads 0-127) ----
    {
        int b_loc = tid >> 6, dn = tid & 63;
        if (b_loc < 2) {
            int dir = dn >> 5, n = dn & 31;
            float4 z4 = zwb[hh*NST + n];
            float zcre = z4.z, zcim = z4.w;
            int q1 = n >> 3, e1 = n & 7;
            float pre = 0.f, pim = 0.f;
            for (int s = 0; s < NCH; ++s) {
                int ch = dir ? (NCH - 1 - s) : s;
                int m = b_loc*16 + ch;
                bbuf[(dir*2 + 0)*1024 + m*32 + ((q1 ^ SWZ(m))*8) + e1] = (_Float16)pre;
                bbuf[(dir*2 + 1)*1024 + m*32 + ((q1 ^ SWZ(m))*8) + e1] = (_Float16)pim;
                float cre = sbuf[m*128 + dn*2];
                float cim = sbuf[m*128 + dn*2 + 1];
                float nre = fmaf(zcre, pre, fmaf(-zcim, pim, cre));
                float nim = fmaf(zcre, pim, fmaf(zcim, pre, cim));
                pre = nre; pim = nim;
            }
        }
    }
    __syncthreads();

    // ---- phase 3: y = [x | stp] . wbig^T (single-barrier dbuf, 8 K-panels) ----
    f32x4 acc3[2][2];
    #pragma unroll
    for (int i = 0; i < 2; ++i)
        #pragma unroll
        for (int j = 0; j < 2; ++j)
            #pragma unroll
            for (int k = 0; k < 4; ++k) acc3[i][j][k] = 0.f;
    const _Float16* wb = &wbig[(size_t)hh*32768];
    pb0 = *(const uint4*)&wb[gr0*256 + gq0*8];
    pb1 = *(const uint4*)&wb[gr1*256 + gq0*8];
    *(uint4*)&sb16[bw0] = pb0;
    *(uint4*)&sb16[bw1] = pb1;
    pb0 = *(const uint4*)&wb[gr0*256 + 32 + gq0*8];
    pb1 = *(const uint4*)&wb[gr1*256 + 32 + gq0*8];
    __syncthreads();
    for (int kc = 0; kc < 8; ++kc) {
        if (kc < 7) {
            *(uint4*)&sb16[((kc+1)&1)*4096 + bw0] = pb0;
            *(uint4*)&sb16[((kc+1)&1)*4096 + bw1] = pb1;
            if (kc < 6) {
                pb0 = *(const uint4*)&wb[gr0*256 + (kc+2)*32 + gq0*8];
                pb1 = *(const uint4*)&wb[gr1*256 + (kc+2)*32 + gq0*8];
            }
        }
        half8 af[2], bf2[2];
        #pragma unroll
        for (int mf = 0; mf < 2; ++mf) {
            int ra = mf*16 + fr;
            af[mf] = (kc < 4)
                ? *(const half8*)&xbuf[kc*1024 + ra*32 + ((kg ^ SWZ(ra))*8)]
                : *(const half8*)&bbuf[(kc-4)*1024 + ra*32 + ((kg ^ SWZ(ra))*8)];
        }
        #pragma unroll
        for (int nf = 0; nf < 2; ++nf) {
            int rb = wn + nf*16 + fr;
            bf2[nf] = *(const half8*)&sb16[(kc&1)*4096 + rb*32 + ((kg ^ SWZ(rb))*8)];
        }
        #pragma unroll
        for (int mf = 0; mf < 2; ++mf)
            #pragma unroll
            for (int nf = 0; nf < 2; ++nf)
                acc3[mf][nf] = __builtin_amdgcn_mfma_f32_16x16x32_f16(af[mf], bf2[nf], acc3[mf][nf], 0, 0, 0);
        __syncthreads();
    }
    // epilogue: gelu (D folded into diag), yst stride 136, coalesced stores
    _Float16* yst = sb16;
    #pragma unroll
    for (int mf = 0; mf < 2; ++mf) {
        #pragma unroll
        for (int rg = 0; rg < 4; ++rg) {
            int m = mf*16 + kg*4 + rg;
            #pragma unroll
            for (int nf = 0; nf < 2; ++nf) {
                int t = wn + nf*16 + fr;
                yst[m*136 + t] = (_Float16)gelu_exact(acc3[mf][nf][rg]);
            }
        }
    }
    __syncthreads();
    {
        int r = tid >> 3, tc = (tid & 7) * 16;
        size_t gb = ((size_t)((b0 + (r>>4))*H + hh))*L + (r&15)*128;
        *(half8*)&y16[gb + tc]     = *(half8*)&yst[r*136 + tc];
        *(half8*)&y16[gb + tc + 8] = *(half8*)&yst[r*136 + tc + 8];
    }
}

// ---------------- GLU MFMA fp16 -> fp16 zc, coalesced epilogue; grid (B*L/128, 4) ----------------
__global__ __launch_bounds__(256) void k_glu16(const _Float16* __restrict__ yt,
        const _Float16* __restrict__ wg, const float* __restrict__ bias,
        _Float16* __restrict__ zc) {
    __shared__ _Float16 a_lds[128*32];
    __shared__ _Float16 b_lds[128*32];
    __shared__ float    ep[32*64];
    const int tid = threadIdx.x;
    const int mbase = blockIdx.x * 128;
    const int o0 = blockIdx.y * 64;
    const int lane = tid & 63;
    const int w = tid >> 6;
    const int wm = (w >> 1) * 64, wn = (w & 1) * 32;
    const int fr = lane & 15, kg = lane >> 4;
    const int r0s = tid >> 2, q0 = tid & 3;
    const int r1s = 64 + r0s;
    const int aw0 = r0s*32 + ((q0 ^ SWZ(r0s)) * 8);
    const int aw1 = r1s*32 + ((q0 ^ SWZ(r1s)) * 8);
    const int og0 = o0 + r0s;
    const int og1 = 256 + o0 + r0s;

    f32x4 accg[4][2], accs[4][2];
    #pragma unroll
    for (int i = 0; i < 4; ++i)
        #pragma unroll
        for (int j = 0; j < 2; ++j)
            #pragma unroll
            for (int k = 0; k < 4; ++k) { accg[i][j][k] = 0.f; accs[i][j][k] = 0.f; }

    uint4 pa0, pa1, pb0, pb1;
    auto loadstep = [&](int kc, uint4& a0, uint4& a1, uint4& b0, uint4& b1) {
        const int cb = kc*32 + q0*8;
        a0 = *(const uint4*)&yt[((size_t)(mbase + r0s))*256 + cb];
        a1 = *(const uint4*)&yt[((size_t)(mbase + r1s))*256 + cb];
        b0 = *(const uint4*)&wg[((size_t)og0)*256 + cb];
        b1 = *(const uint4*)&wg[((size_t)og1)*256 + cb];
    };
    loadstep(0, pa0, pa1, pb0, pb1);
    for (int kc = 0; kc < 8; ++kc) {
        __syncthreads();
        *(uint4*)&a_lds[aw0] = pa0;
        *(uint4*)&a_lds[aw1] = pa1;
        *(uint4*)&b_lds[aw0] = pb0;
        *(uint4*)&b_lds[aw1] = pb1;
        uint4 na0 = make_uint4(0,0,0,0), na1 = na0, nb0 = na0, nb1 = na0;
        if (kc < 7) loadstep(kc+1, na0, na1, nb0, nb1);
        __syncthreads();
        half8 af[4], bg[2], bs[2];
        #pragma unroll
        for (int mf = 0; mf < 4; ++mf) {
            int ra = wm + mf*16 + fr;
            af[mf] = *(const half8*)&a_lds[ra*32 + ((kg ^ SWZ(ra)) * 8)];
        }
        #pragma unroll
        for (int nf = 0; nf < 2; ++nf) {
            int rb = wn + nf*16 + fr;
            bg[nf] = *(const half8*)&b_lds[rb*32 + ((kg ^ SWZ(rb)) * 8)];
            int rb2 = 64 + rb;
            bs[nf] = *(const half8*)&b_lds[rb2*32 + ((kg ^ SWZ(rb2)) * 8)];
        }
        #pragma unroll
        for (int mf = 0; mf < 4; ++mf)
            #pragma unroll
            for (int nf = 0; nf < 2; ++nf) {
                accg[mf][nf] = __builtin_amdgcn_mfma_f32_16x16x32_f16(af[mf], bg[nf], accg[mf][nf], 0, 0, 0);
                accs[mf][nf] = __builtin_amdgcn_mfma_f32_16x16x32_f16(af[mf], bs[nf], accs[mf][nf], 0, 0, 0);
            }
        pa0 = na0; pa1 = na1; pb0 = nb0; pb1 = nb1;
    }
    float b0v[2], b1v[2];
    #pragma unroll
    for (int nf = 0; nf < 2; ++nf) {
        int o = o0 + wn + nf*16 + fr;
        b0v[nf] = bias[o]; b1v[nf] = bias[256 + o];
    }
    const int er = tid >> 3, eoc = (tid & 7) * 8;
    #pragma unroll
    for (int mf = 0; mf < 4; ++mf) {
        __syncthreads();
        #pragma unroll
        for (int nf = 0; nf < 2; ++nf) {
            int ol = wn + nf*16 + fr;
            int srb = (w >> 1)*16 + kg*4;
            #pragma unroll
            for (int rg = 0; rg < 4; ++rg) {
                float g = accg[mf][nf][rg] + b0v[nf];
                float s = accs[mf][nf][rg] + b1v[nf];
                ep[(srb + rg)*64 + ol] = g / (1.f + expf(-s));
            }
        }
        __syncthreads();
        size_t m = (size_t)mbase + mf*16 + (er < 16 ? er : 48 + er);
        float4 v0 = *(float4*)&ep[er*64 + eoc];
        float4 v1 = *(float4*)&ep[er*64 + eoc + 4];
        half8 hv;
        hv[0]=(_Float16)v0.x; hv[1]=(_Float16)v0.y; hv[2]=(_Float16)v0.z; hv[3]=(_Float16)v0.w;
        hv[4]=(_Float16)v1.x; hv[5]=(_Float16)v1.y; hv[6]=(_Float16)v1.z; hv[7]=(_Float16)v1.w;
        *(half8*)&zc[m*256 + o0 + eoc] = hv;
    }
}

// ---------------- LayerNorm: fp16 residual stream; last layer adds species + outseq f32 ----------------
template<bool SP>
__global__ __launch_bounds__(256) void k_ln2(const _Float16* __restrict__ zc,
        _Float16* __restrict__ hm, const float* __restrict__ g, const float* __restrict__ bb,
        const int* __restrict__ xs, const float* __restrict__ emb,
        float* __restrict__ outseq) {
    __shared__ float tl[8992];
    int tid = threadIdx.x;
    int b = blockIdx.y;
    int l0 = blockIdx.x * 32;
    for (int j = tid; j < 1024; j += 256) {
        int c = j >> 2, l8 = (j & 3) * 8;
        half8 v = *(const half8*)&hm[((size_t)(b*H + c))*L + l0 + l8];
        #pragma unroll
        for (int e = 0; e < 8; ++e) tl[LDIDX(l8 + e, c)] = (float)v[e];
    }
    __syncthreads();
    int r = tid >> 3, p = tid & 7;
    float v[32];
    float sum = 0.f, ss = 0.f;
    const _Float16* zrow = &zc[((size_t)(b*L + l0 + r))*256 + p*32];
    #pragma unroll
    for (int q = 0; q < 4; ++q) {
        half8 z8 = *(const half8*)&zrow[q*8];
        #pragma unroll
        for (int i = 0; i < 8; ++i) {
            float hv = tl[LDIDX(r, p*32 + q*8 + i)];
            float vv = (float)z8[i] + hv;
            v[q*8+i] = vv;
            sum += vv; ss = fmaf(vv, vv, ss);
        }
    }
    sum += __shfl_xor(sum, 1); ss += __shfl_xor(ss, 1);
    sum += __shfl_xor(sum, 2); ss += __shfl_xor(ss, 2);
    sum += __shfl_xor(sum, 4); ss += __shfl_xor(ss, 4);
    float mu = sum * (1.f/256.f);
    float var = ss * (1.f/256.f) - mu*mu;
    float rs = rsqrtf(var + 1e-5f);
    int sp = SP ? xs[b] : 0;
    #pragma unroll
    for (int q = 0; q < 32; ++q) {
        int c = p*32 + q;
        float val = (v[q] - mu) * rs * g[c] + bb[c];
        if (SP) val += emb[sp*H + c];
        tl[LDIDX(r, c)] = val;
    }
    __syncthreads();
    for (int j = tid; j < 1024; j += 256) {
        int c = j >> 2, l8 = (j & 3) * 8;
        float fv[8];
        half8 hv;
        #pragma unroll
        for (int e = 0; e < 8; ++e) {
            fv[e] = tl[LDIDX(l8 + e, c)];
            hv[e] = (_Float16)fv[e];
        }
        *(half8*)&hm[((size_t)(b*H + c))*L + l0 + l8] = hv;
        if (SP) {
            *(float4*)&outseq[((size_t)(b*H + c))*L + l0 + l8] = make_float4(fv[0],fv[1],fv[2],fv[3]);
            *(float4*)&outseq[((size_t)(b*H + c))*L + l0 + l8 + 4] = make_float4(fv[4],fv[5],fv[6],fv[7]);
        }
    }
}

// ---------------- MFMA decoder conv K=15 ----------------
__global__ __launch_bounds__(128) void k_dec(const _Float16* __restrict__ ht,
        const _Float16* __restrict__ wdk, const float* __restrict__ bias,
        float* __restrict__ outdec) {
    __shared__ _Float16 a_lds[160*32];
    __shared__ _Float16 b_lds[15*16*32];
    const int tid = threadIdx.x;
    const int mbase = blockIdx.x * 128;
    const int b = mbase >> 11;
    const int lbase = mbase & 2047;
    const int lane = tid & 63;
    const int w = tid >> 6;
    const int fr = lane & 15, kg = lane >> 4;
    const int rs = tid >> 2, q0 = tid & 3;
    f32x4 acc[4];
    #pragma unroll
    for (int i = 0; i < 4; ++i)
        #pragma unroll
        for (int k = 0; k < 4; ++k) acc[i][k] = 0.f;
    for (int cc = 0; cc < 8; ++cc) {
        __syncthreads();
        #pragma unroll
        for (int ps = 0; ps < 5; ++ps) {
            int r = ps*32 + rs;
            if (r < 142) {
                int l = lbase - 7 + r;
                uint4 v = (l >= 0 && l < L) ? *(const uint4*)&ht[((size_t)(b*L + l))*256 + cc*32 + q0*8]
                                            : make_uint4(0,0,0,0);
                *(uint4*)&a_lds[r*32 + ((q0 ^ SWZ(r))*8)] = v;
            }
        }
        for (int jj = tid; jj < 960; jj += 128)
            *(uint4*)&b_lds[jj*8] = *(const uint4*)&wdk[cc*7680 + jj*8];
        __syncthreads();
        #pragma unroll
        for (int k = 0; k < 15; ++k) {
            half8 bfr = *(const half8*)&b_lds[(k*16 + fr)*32 + ((kg ^ SWZ(fr))*8)];
            #pragma unroll
            for (int mf = 0; mf < 4; ++mf) {
                int ra = w*64 + mf*16 + fr + k;
                half8 af = *(const half8*)&a_lds[ra*32 + ((kg ^ SWZ(ra))*8)];
                acc[mf] = __builtin_amdgcn_mfma_f32_16x16x32_f16(af, bfr, acc[mf], 0, 0, 0);
            }
        }
    }
    if (fr < DOUT) {
        float bo = bias[fr];
        #pragma unroll
        for (int mf = 0; mf < 4; ++mf)
            #pragma unroll
            for (int rg = 0; rg < 4; ++rg) {
                int m = mbase + w*64 + mf*16 + kg*4 + rg;
                outdec[((size_t)(b*DOUT + fr))*L + (m & 2047)] = acc[mf][rg] + bo;
            }
    }
}

// ---------------- mean over L (fp16 input) ----------------
__global__ __launch_bounds__(256) void k_agg(const _Float16* __restrict__ h, float* __restrict__ agg) {
    __shared__ float red[256];
    int bc = blockIdx.x;
    int tid = threadIdx.x;
    half8 v = *(const half8*)&h[(size_t)bc*L + tid*8];
    float s = 0.f;
    #pragma unroll
    for (int e = 0; e < 8; ++e) s += (float)v[e];
    red[tid] = s; __syncthreads();
    for (int k = 128; k > 0; k >>= 1) {
        if (tid < k) red[tid] += red[tid+k];
        __syncthreads();
    }
    if (tid == 0) agg[bc] = red[0] * (1.f/(float)L);
}

// ---------------- regression MLP ----------------
__global__ __launch_bounds__(128) void k_mlp(const float* __restrict__ agg,
        const float* __restrict__ w1, const float* __restrict__ b1,
        const float* __restrict__ w2, const float* __restrict__ b2,
        const float* __restrict__ w3, const float* __restrict__ b3,
        const float* __restrict__ w4, const float* __restrict__ b4,
        float* __restrict__ outreg) {
    __shared__ float a0[256], r1[128], r2[64], r3[32];
    int b = blockIdx.x, tid = threadIdx.x;
    a0[tid] = agg[b*256 + tid];
    a0[tid+128] = agg[b*256 + tid + 128];
    __syncthreads();
    {
        float s = b1[tid];
        for (int k = 0; k < 256; ++k) s = fmaf(w1[tid*256+k], a0[k], s);
        r1[tid] = s > 0.f ? s : expm1f(s);
    }
    __syncthreads();
    if (tid < 64) {
        float s = b2[tid];
        for (int k = 0; k < 128; ++k) s = fmaf(w2[tid*128+k], r1[k], s);
        r2[tid] = s > 0.f ? s : expm1f(s);
    }
    __syncthreads();
    if (tid < 32) {
        float s = b3[tid];
        for (int k = 0; k < 64; ++k) s = fmaf(w3[tid*64+k], r2[k], s);
        r3[tid] = s > 0.f ? s : expm1f(s);
    }
    __syncthreads();
    if (tid == 0) {
        float s = b4[0];
        for (int k = 0; k < 32; ++k) s = fmaf(w4[k], r3[k], s);
        outreg[b] = s;
    }
}

extern "C" void kernel_launch(void* const* d_in, const int* in_sizes, int n_in,
                              void* d_out, int out_size, void* d_ws, size_t ws_size,
                              hipStream_t stream) {
    const float* x      = (const float*)d_in[0];
    const int*   xs     = (const int*)d_in[1];
    const float* enc_w  = (const float*)d_in[2];
    const float* enc_b  = (const float*)d_in[3];
    const float* res_w1 = (const float*)d_in[4];
    const float* res_b1 = (const float*)d_in[5];
    const float* res_w2 = (const float*)d_in[6];
    const float* res_b2 = (const float*)d_in[7];
    const float* log_dt = (const float*)d_in[8];
    const float* lam_re = (const float*)d_in[9];
    const float* lam_im = (const float*)d_in[10];
    const float* W_re   = (const float*)d_in[11];
    const float* W_im   = (const float*)d_in[12];
    const float* Dv     = (const float*)d_in[13];
    const float* glu_w  = (const float*)d_in[14];
    const float* glu_b  = (const float*)d_in[15];
    const float* ln_g   = (const float*)d_in[16];
    const float* ln_b   = (const float*)d_in[17];
    const float* dec_w  = (const float*)d_in[18];
    const float* dec_b  = (const float*)d_in[19];
    const float* sp_emb = (const float*)d_in[20];
    const float* h1_w = (const float*)d_in[21]; const float* h1_b = (const float*)d_in[22];
    const float* h2_w = (const float*)d_in[23]; const float* h2_b = (const float*)d_in[24];
    const float* h3_w = (const float*)d_in[25]; const float* h3_b = (const float*)d_in[26];
    const float* h4_w = (const float*)d_in[27]; const float* h4_b = (const float*)d_in[28];

    float* ws   = (float*)d_ws;
    _Float16* hm16 = (_Float16*)ws;                    // fp16 chm residual (persistent)
    float* t1   = ws + (size_t)LSEQ;
    float* t2   = ws + (size_t)2*LSEQ;
    // res-phase:
    _Float16* xb  = (_Float16*)t1;
    _Float16* xa  = (_Float16*)t1 + (size_t)LSEQ;
    _Float16* wpk = (_Float16*)t2;
    // DSS-phase:
    _Float16* yt   = (_Float16*)t1;                    // fp16 chl y (t1 lower)
    _Float16* wbig = (_Float16*)t1 + (size_t)LSEQ;     // 16MB (t1 upper)
    _Float16* zp   = wbig + (size_t)H*32768;           // 8MB
    _Float16* y16  = (_Float16*)t2;                    // fp16 chm y
    _Float16* zc16 = (_Float16*)t2;                    // glu out fp16 chl (y16 dead)
    _Float16* dect = (_Float16*)t1;                    // decoder chl input
    // tail:
    float* tail = ws + (size_t)3*LSEQ;
    _Float16* wg  = (_Float16*)tail;
    float4* zwb = (float4*)(tail + 65536);
    float* aggb = tail + 65536 + 32768;
    _Float16* wdk = (_Float16*)(aggb + 8192);
    _Float16* wenc = wdk + 61440;

    float* outdec = (float*)d_out;
    float* outseq = outdec + B*DOUT*L;
    float* outreg = outseq + (size_t)LSEQ;

    // encoder
    k_wenc<<<96, 256, 0, stream>>>(enc_w, wenc);
    k_enc<<<dim3(B*L/128, 2), 256, 0, stream>>>(x, wenc, enc_b, xa);

    // residual stack
    k_wpack<<<(NRES*2*3*65536 + 255)/256, 256, 0, stream>>>(res_w1, res_w2, wpk);
    for (int r = 0; r < NRES; ++r) {
        k_cv3<false><<<B*L/128, 256, 0, stream>>>(
            xa, wpk + (size_t)(r*2+0)*3*65536, res_b1 + r*H, nullptr, xb);
        k_cv3<true><<<B*L/128, 256, 0, stream>>>(
            xb, wpk + (size_t)(r*2+1)*3*65536, res_b2 + r*H, xa, xa);
    }
    k_t_cf16<<<dim3(L/64, H/64, B), 256, 0, stream>>>(xa, hm16);

    // DSS blocks
    for (int i = 0; i < NLAYERS; ++i) {
        k_wzp<<<H, 128, 0, stream>>>(log_dt, lam_re, lam_im, zp, zwb, i);
        k_wkern<<<H, 128, 0, stream>>>(log_dt, lam_re, lam_im, W_re, W_im, Dv, glu_w,
                                       wbig, wg, i);
        k_dss<<<dim3(H, 16), 256, 0, stream>>>(hm16, zp, wbig, zwb, y16, i);
        k_t16<<<dim3(L/64, H/64, B), 256, 0, stream>>>(y16, yt);
        k_glu16<<<dim3(B*L/128, 4), 256, 0, stream>>>(yt, wg, glu_b + i*512, zc16);
        if (i < NLAYERS - 1)
            k_ln2<false><<<dim3(L/32, B), 256, 0, stream>>>(zc16, hm16, ln_g + i*H, ln_b + i*H,
                                                            nullptr, nullptr, nullptr);
        else
            k_ln2<true><<<dim3(L/32, B), 256, 0, stream>>>(zc16, hm16, ln_g + i*H, ln_b + i*H,
                                                           xs, sp_emb, outseq);
    }

    // aggregate + regression head
    k_agg<<<B*H, 256, 0, stream>>>(hm16, aggb);
    k_mlp<<<B, 128, 0, stream>>>(aggb, h1_w, h1_b, h2_w, h2_b, h3_w, h3_b, h4_w, h4_b, outreg);
    // decoder
    k_t16<<<dim3(L/64, H/64, B), 256, 0, stream>>>(hm16, dect);
    k_wdec<<<(15*16*256 + 255)/256, 256, 0, stream>>>(dec_w, wdk);
    k_dec<<<B*L/128, 128, 0, stream>>>(dect, wdk, dec_b, outdec);
}

// Round 14
// 1079.020 us; speedup vs baseline: 1.1548x; 1.0117x over previous
//
#include <hip/hip_runtime.h>
#include <math.h>

#define B 32
#define L 2048
#define DIN 5
#define DOUT 5
#define H 256
#define NST 32
#define NLAYERS 4
#define NRES 3
#define CHUNK 128
#define NCH 16            // L / CHUNK
#define LSEQ (B*H*L)      // 16777216

typedef __attribute__((ext_vector_type(8))) _Float16 half8;
typedef __attribute__((ext_vector_type(4))) float f32x4;

__device__ __forceinline__ float gelu_exact(float v) {
    return 0.5f * v * (1.0f + erff(v * 0.7071067811865475f));
}
// A&S 7.1.26: |erf err| < 1.5e-7 -> gelu err ~1e-7, invisible vs fp16 rounding (5e-4)
__device__ __forceinline__ float gelu_fast(float v) {
    float x = v * 0.7071067811865475f;
    float ax = fabsf(x);
    float t = 1.f / fmaf(0.3275911f, ax, 1.f);
    float poly = t*(0.254829592f + t*(-0.284496736f + t*(1.421413741f +
                 t*(-1.453152027f + t*1.061405429f))));
    float e = __expf(-ax*ax);
    float erfv = copysignf(1.f - poly*e, x);
    return 0.5f * v * (1.f + erfv);
}
#define SWZ(r) ((((r) ^ ((r) >> 2)) & 3))
#define LDIDX(l, c) ((l)*281 + ((c)>>5)*35 + ((c)&31))

// ---------------- encoder weight pack ----------------
__global__ void k_wenc(const float* __restrict__ ew, _Float16* __restrict__ wenc) {
    int idx = blockIdx.x*256 + threadIdx.x;
    if (idx >= 256*96) return;
    int o = idx / 96, kk = idx % 96;
    int ci = kk >> 4, k = kk & 15;
    float v = (ci < DIN && k < 15) ? ew[(o*DIN + ci)*15 + k] : 0.f;
    wenc[idx] = (_Float16)v;
}

// ---------------- MFMA encoder conv K=15 Cin=5 ----------------
__global__ __launch_bounds__(256) void k_enc(const float* __restrict__ x,
        const _Float16* __restrict__ wenc, const float* __restrict__ bias,
        _Float16* __restrict__ out) {
    __shared__ _Float16 a_lds[3*128*32];
    __shared__ _Float16 b_lds[3*128*32];
    const int tid = threadIdx.x;
    const int mbase = blockIdx.x * 128;
    const int oh = blockIdx.y;
    const int b = mbase >> 11;
    const int lbase = mbase & 2047;
    const int lane = tid & 63;
    const int w = tid >> 6;
    const int wm = (w >> 1) * 64, wn = (w & 1) * 64;
    const int fr = lane & 15, kg = lane >> 4;

    #pragma unroll
    for (int i = 0; i < 6; ++i) {
        int g = i*256 + tid;
        int r = g / 12, rem = g % 12;
        int ks = rem >> 2, q = rem & 3;
        int kk0 = ks*32 + q*8;
        int ci = kk0 >> 4, k0 = kk0 & 15;
        half8 va;
        #pragma unroll
        for (int e = 0; e < 8; ++e) {
            int k = k0 + e;
            int l = lbase + r - 7 + k;
            float v = (ci < DIN && k < 15 && l >= 0 && l < L)
                        ? x[((size_t)(b*DIN + ci))*L + l] : 0.f;
            va[e] = (_Float16)v;
        }
        *(half8*)&a_lds[ks*4096 + r*32 + ((q ^ SWZ(r))*8)] = va;
        uint4 vb = *(const uint4*)&wenc[(size_t)(oh*128 + r)*96 + kk0];
        *(uint4*)&b_lds[ks*4096 + r*32 + ((q ^ SWZ(r))*8)] = vb;
    }
    __syncthreads();
    f32x4 acc[4][4];
    #pragma unroll
    for (int i = 0; i < 4; ++i)
        #pragma unroll
        for (int j = 0; j < 4; ++j)
            #pragma unroll
            for (int k = 0; k < 4; ++k) acc[i][j][k] = 0.f;
    #pragma unroll
    for (int ks = 0; ks < 3; ++ks) {
        half8 af[4], bfr[4];
        #pragma unroll
        for (int mf = 0; mf < 4; ++mf) {
            int ra = wm + mf*16 + fr;
            af[mf] = *(const half8*)&a_lds[ks*4096 + ra*32 + ((kg ^ SWZ(ra))*8)];
        }
        #pragma unroll
        for (int nf = 0; nf < 4; ++nf) {
            int rb = wn + nf*16 + fr;
            bfr[nf] = *(const half8*)&b_lds[ks*4096 + rb*32 + ((kg ^ SWZ(rb))*8)];
        }
        #pragma unroll
        for (int mf = 0; mf < 4; ++mf)
            #pragma unroll
            for (int nf = 0; nf < 4; ++nf)
                acc[mf][nf] = __builtin_amdgcn_mfma_f32_16x16x32_f16(af[mf], bfr[nf], acc[mf][nf], 0, 0, 0);
    }
    #pragma unroll
    for (int nf = 0; nf < 4; ++nf) {
        int o = oh*128 + wn + nf*16 + fr;
        float bo = bias[o];
        #pragma unroll
        for (int mf = 0; mf < 4; ++mf)
            #pragma unroll
            for (int rg = 0; rg < 4; ++rg) {
                size_t m = (size_t)mbase + wm + mf*16 + kg*4 + rg;
                out[m*256 + o] = (_Float16)(acc[mf][nf][rg] + bo);
            }
    }
}

// ---------------- res weight pack ----------------
__global__ void k_wpack(const float* __restrict__ w1, const float* __restrict__ w2,
                        _Float16* __restrict__ wpk) {
    int idx = blockIdx.x*256 + threadIdx.x;
    if (idx >= NRES*2*3*65536) return;
    int ci = idx & 255;
    int o  = (idx >> 8) & 255;
    int k  = (idx >> 16) % 3;
    int cv = idx / (3*65536);
    const float* src = (cv & 1) ? w2 : w1;
    wpk[idx] = (_Float16)src[(((cv>>1)*H + o)*H + ci)*3 + k];
}

// ---------------- transpose fp16 chl -> fp16 chm (half8 global both sides) ----------------
__global__ __launch_bounds__(256) void k_t_cf16(const _Float16* __restrict__ in,
        _Float16* __restrict__ out) {
    __shared__ float t[64][65];
    int tid = threadIdx.x;
    int l0 = blockIdx.x*64, c0 = blockIdx.y*64, b = blockIdx.z;
    #pragma unroll
    for (int i = 0; i < 2; ++i) {
        int g = i*256 + tid;
        int c8 = (g & 7) * 8, l = g >> 3;
        half8 v = *(const half8*)&in[((size_t)b*L + l0 + l)*256 + c0 + c8];
        #pragma unroll
        for (int e = 0; e < 8; ++e) t[c8 + e][l] = (float)v[e];
    }
    __syncthreads();
    #pragma unroll
    for (int i = 0; i < 2; ++i) {
        int g = i*256 + tid;
        int l8 = (g & 7) * 8, c = g >> 3;
        half8 hv;
        #pragma unroll
        for (int e = 0; e < 8; ++e) hv[e] = (_Float16)t[c][l8 + e];
        *(half8*)&out[((size_t)(b*H + c0 + c))*L + l0 + l8] = hv;
    }
}

// ---------------- transpose fp16 chm -> fp16 chl (half8 global both sides) ----------------
__global__ __launch_bounds__(256) void k_t16(const _Float16* __restrict__ in,
                                             _Float16* __restrict__ out) {
    __shared__ float t[64][65];
    int tid = threadIdx.x;
    int l0 = blockIdx.x*64, c0 = blockIdx.y*64, b = blockIdx.z;
    #pragma unroll
    for (int i = 0; i < 2; ++i) {
        int g = i*256 + tid;
        int l8 = (g & 7) * 8, c = g >> 3;
        half8 v = *(const half8*)&in[((size_t)(b*H + c0 + c))*L + l0 + l8];
        #pragma unroll
        for (int e = 0; e < 8; ++e) t[c][l8 + e] = (float)v[e];
    }
    __syncthreads();
    #pragma unroll
    for (int i = 0; i < 2; ++i) {
        int g = i*256 + tid;
        int c8 = (g & 7) * 8, l = g >> 3;
        half8 hv;
        #pragma unroll
        for (int e = 0; e < 8; ++e) hv[e] = (_Float16)t[c8 + e][l];
        *(half8*)&out[((size_t)b*L + l0 + l)*256 + c0 + c8] = hv;
    }
}

// ---------------- MFMA residual conv K=3: full-N tile 128m x 256o, coalesced epilogue ----------------
template<bool RESID>
__global__ __launch_bounds__(256, 2) void k_cv3(const _Float16* __restrict__ xin,
        const _Float16* __restrict__ wpk, const float* __restrict__ bias,
        const _Float16* __restrict__ resid, _Float16* __restrict__ out) {
    __shared__ _Float16 a_lds[128*32];
    __shared__ _Float16 b_lds[256*32];
    __shared__ float    ep[32*256];
    const int tid = threadIdx.x;
    const int mbase = blockIdx.x * 128;
    const int lane = tid & 63;
    const int w = tid >> 6;
    const int wm = (w >> 1) * 64, wo = (w & 1) * 128;
    const int fr = lane & 15, kg = lane >> 4;

    const int r0s = tid >> 2, q0 = tid & 3;
    const int sq = SWZ(r0s);
    const int awA0 = r0s*32 + ((q0 ^ sq) * 8);
    const int awA1 = (64 + r0s)*32 + ((q0 ^ SWZ(64 + r0s)) * 8);

    f32x4 acc[4][8];
    #pragma unroll
    for (int i = 0; i < 4; ++i)
        #pragma unroll
        for (int j = 0; j < 8; ++j)
            #pragma unroll
            for (int k = 0; k < 4; ++k) acc[i][j][k] = 0.f;

    uint4 pa0, pa1, pb[4];
    auto loadstep = [&](int kk, uint4& a0, uint4& a1, uint4 (&bb)[4]) {
        const int koff = kk >> 3, cic = kk & 7;
        const int cb = cic*32 + q0*8;
        {
            int m = mbase + r0s;
            int ll = (m & (L-1)) + koff - 1;
            a0 = (ll >= 0 && ll < L) ? *(const uint4*)&xin[((size_t)(m + koff - 1))*256 + cb]
                                     : make_uint4(0,0,0,0);
            int m1 = mbase + 64 + r0s;
            int l1 = (m1 & (L-1)) + koff - 1;
            a1 = (l1 >= 0 && l1 < L) ? *(const uint4*)&xin[((size_t)(m1 + koff - 1))*256 + cb]
                                     : make_uint4(0,0,0,0);
        }
        #pragma unroll
        for (int u = 0; u < 4; ++u)
            bb[u] = *(const uint4*)&wpk[((size_t)(koff*256 + u*64 + r0s))*256 + cb];
    };
    loadstep(0, pa0, pa1, pb);
    for (int kk = 0; kk < 24; ++kk) {
        __syncthreads();
        *(uint4*)&a_lds[awA0] = pa0;
        *(uint4*)&a_lds[awA1] = pa1;
        #pragma unroll
        for (int u = 0; u < 4; ++u)
            *(uint4*)&b_lds[(u*64 + r0s)*32 + ((q0 ^ sq)*8)] = pb[u];
        uint4 na0 = make_uint4(0,0,0,0), na1 = na0, nb[4] = {na0, na0, na0, na0};
        if (kk < 23) loadstep(kk+1, na0, na1, nb);
        __syncthreads();
        half8 af[4];
        #pragma unroll
        for (int mf = 0; mf < 4; ++mf) {
            int ra = wm + mf*16 + fr;
            af[mf] = *(const half8*)&a_lds[ra*32 + ((kg ^ SWZ(ra)) * 8)];
        }
        #pragma unroll
        for (int nf = 0; nf < 8; ++nf) {
            int rb = wo + nf*16 + fr;
            half8 bfr = *(const half8*)&b_lds[rb*32 + ((kg ^ SWZ(rb)) * 8)];
            #pragma unroll
            for (int mf = 0; mf < 4; ++mf)
                acc[mf][nf] = __builtin_amdgcn_mfma_f32_16x16x32_f16(af[mf], bfr, acc[mf][nf], 0, 0, 0);
        }
        pa0 = na0; pa1 = na1;
        #pragma unroll
        for (int u = 0; u < 4; ++u) pb[u] = nb[u];
    }
    float bo8[8];
    #pragma unroll
    for (int nf = 0; nf < 8; ++nf) bo8[nf] = bias[wo + nf*16 + fr];
    const int er = tid >> 3, eoc = (tid & 7) * 32;
    #pragma unroll
    for (int mf = 0; mf < 4; ++mf) {
        __syncthreads();
        #pragma unroll
        for (int nf = 0; nf < 8; ++nf) {
            int o = wo + nf*16 + fr;
            int srb = (w >> 1)*16 + kg*4;
            #pragma unroll
            for (int rg = 0; rg < 4; ++rg)
                ep[(srb + rg)*256 + o] = acc[mf][nf][rg] + bo8[nf];
        }
        __syncthreads();
        size_t m = (size_t)mbase + mf*16 + (er < 16 ? er : 48 + er);
        #pragma unroll
        for (int u = 0; u < 4; ++u) {
            float4 v0 = *(float4*)&ep[er*256 + eoc + u*8];
            float4 v1 = *(float4*)&ep[er*256 + eoc + u*8 + 4];
            float vv[8] = {v0.x, v0.y, v0.z, v0.w, v1.x, v1.y, v1.z, v1.w};
            if (RESID) {
                half8 rv = *(const half8*)&resid[m*256 + eoc + u*8];
                #pragma unroll
                for (int e = 0; e < 8; ++e) vv[e] += (float)rv[e];
            }
            half8 hv;
            #pragma unroll
            for (int e = 0; e < 8; ++e) hv[e] = (_Float16)fmaxf(vv[e], 0.f);
            *(half8*)&out[m*256 + eoc + u*8] = hv;
        }
    }
}

// ---------------- W_big + zp + zwb + wg, one kernel per h ----------------
__global__ __launch_bounds__(128) void k_wkern(const float* __restrict__ log_dt,
        const float* __restrict__ lam_re, const float* __restrict__ lam_im,
        const float* __restrict__ W_re, const float* __restrict__ W_im,
        const float* __restrict__ Dv, const float* __restrict__ gw,
        _Float16* __restrict__ wbig, _Float16* __restrict__ wg,
        _Float16* __restrict__ zp, float4* __restrict__ zwbuf, int layer) {
    __shared__ float kf[128], kb[128];
    __shared__ float E[128*129];
    const int hh = blockIdx.x;
    const int t = threadIdx.x;
    float dt = expf(log_dt[layer*H + hh]);
    float skf = 0.f, skb = 0.f;
    for (int n = 0; n < 32; ++n) {
        float a  = dt * lam_re[layer*NST + n];
        float bi = dt * lam_im[layer*NST + n];
        float wfr = W_re[((layer*2+0)*H + hh)*NST + n];
        float wfi = W_im[((layer*2+0)*H + hh)*NST + n];
        float wbr = W_re[((layer*2+1)*H + hh)*NST + n];
        float wbi = W_im[((layer*2+1)*H + hh)*NST + n];
        float e0 = expf(a*t), s0, c0; sincosf(bi*t, &s0, &c0);
        float zr0 = e0*c0, zi0 = e0*s0;
        skf = fmaf(wfr, zr0, skf) - wfi*zi0;
        skb = fmaf(wbr, zr0, skb) - wbi*zi0;
        float e1 = expf(a*(t+1)), s1, c1; sincosf(bi*(t+1), &s1, &c1);
        float zr1 = e1*c1, zi1 = e1*s1;
        E[t*129 + n]      = wfr*zr1 - wfi*zi1;
        E[t*129 + 32 + n] = -(wfr*zi1 + wfi*zr1);
        float e2 = expf(a*(127-t)), s2, c2; sincosf(bi*(127-t), &s2, &c2);
        float zr2 = e2*c2, zi2 = e2*s2;
        E[t*129 + 64 + n] = wbr*zr2 - wbi*zi2;
        E[t*129 + 96 + n] = -(wbr*zi2 + wbi*zr2);
    }
    kf[t] = skf + ((t == 0) ? Dv[layer*H + hh] : 0.f);
    kb[t] = skb;
    __syncthreads();
    _Float16* dst = &wbig[(size_t)hh*32768];
    for (int idx = t; idx < 128*256; idx += 128) {
        int tt = idx >> 8, k = idx & 255;
        float v;
        if (k < 128) v = (k <= tt) ? kf[tt - k] : kb[k - tt - 1];
        else         v = E[tt*129 + (k - 128)];
        dst[idx] = (_Float16)v;
    }
    const float* gsrc = &gw[(size_t)layer*131072 + (size_t)hh*512];
    _Float16* gdst = &wg[(size_t)hh*512];
    for (int j = t; j < 512; j += 128) gdst[j] = (_Float16)gsrc[j];
    // --- merged wzp: zp[h][t][j], zwb (per-thread independent) ---
    {
        int dn = t >> 1, c = t & 1, dir = dn >> 5, n = dn & 31;
        float a  = dt * lam_re[layer*NST + n];
        float bi = dt * lam_im[layer*NST + n];
        float er = expf(a);
        float zre = er * cosf(bi), zim = er * sinf(bi);
        if (c == 0 && dir == 0) {
            float eC = expf(a * (float)CHUNK);
            float s, co; sincosf(bi * (float)CHUNK, &s, &co);
            zwbuf[hh*NST + n] = make_float4(zre, zim, eC*co, eC*s);
        }
        _Float16* zdst = &zp[(size_t)hh*16384 + t*128];
        float cr = 1.f, ci = 0.f;
        for (int p = 0; p < 128; ++p) {
            float val = c ? ci : cr;
            zdst[dir ? p : (127 - p)] = (_Float16)val;
            float nr = cr*zre - ci*zim;
            float ni = cr*zim + ci*zre;
            cr = nr; ci = ni;
        }
    }
}

// ---------------- decoder weight pack ----------------
__global__ void k_wdec(const float* __restrict__ dw, _Float16* __restrict__ wdk) {
    int idx = blockIdx.x*256 + threadIdx.x;
    if (idx >= 15*16*256) return;
    int cfull = idx & 255;
    int o = (idx >> 8) & 15;
    int k = idx >> 12;
    float v = (o < DOUT) ? dw[(o*H + cfull)*15 + k] : 0.f;
    int cc = cfull >> 5, cl = cfull & 31;
    int cq = cl >> 3, cb = cl & 7;
    wdk[cc*7680 + (k*16 + o)*32 + ((cq ^ SWZ(o))*8) + cb] = (_Float16)v;
}

// ---------------- FUSED DSS v3: M=32 (grid H x 16), 40KB LDS, single-barrier dbuf ----------------
__global__ __launch_bounds__(256, 4) void k_dss(const _Float16* __restrict__ hm16,
        const _Float16* __restrict__ zp, const _Float16* __restrict__ wbig,
        const float4* __restrict__ zwb, _Float16* __restrict__ y16, int layer) {
    __shared__ _Float16 xbuf[4*32*32];
    __shared__ _Float16 bbuf[2*128*32];
    __shared__ float    sbuf[32*128];
    _Float16* sb16 = (_Float16*)sbuf;

    const int tid = threadIdx.x;
    const int hh = blockIdx.x;
    const int b0 = blockIdx.y * 2;
    const int lane = tid & 63;
    const int w = tid >> 6;
    const int wn = w * 32;
    const int fr = lane & 15, kg = lane >> 4;

    #pragma unroll
    for (int i = 0; i < 2; ++i) {
        int g = i*256 + tid;
        int m = g >> 4, gi = g & 15;
        int kc = gi >> 2, q = gi & 3;
        uint4 v = *(const uint4*)&hm16[((size_t)((b0 + (m>>4))*H + hh))*L
                                       + (m&15)*128 + kc*32 + q*8];
        *(uint4*)&xbuf[kc*1024 + m*32 + ((q ^ SWZ(m))*8)] = v;
    }

    // ---- phase 1: S = x . zp^T ----
    f32x4 acc1[2][2];
    #pragma unroll
    for (int i = 0; i < 2; ++i)
        #pragma unroll
        for (int j = 0; j < 2; ++j)
            #pragma unroll
            for (int k = 0; k < 4; ++k) acc1[i][j][k] = 0.f;
    const _Float16* zb = &zp[(size_t)hh*16384];
    const int gr0 = tid >> 2, gq0 = tid & 3;
    const int gr1 = 64 + gr0;
    const int bw0 = gr0*32 + ((gq0 ^ SWZ(gr0))*8);
    const int bw1 = gr1*32 + ((gq0 ^ SWZ(gr1))*8);
    uint4 pb0 = *(const uint4*)&zb[gr0*128 + gq0*8];
    uint4 pb1 = *(const uint4*)&zb[gr1*128 + gq0*8];
    *(uint4*)&bbuf[bw0] = pb0;
    *(uint4*)&bbuf[bw1] = pb1;
    pb0 = *(const uint4*)&zb[gr0*128 + 32 + gq0*8];
    pb1 = *(const uint4*)&zb[gr1*128 + 32 + gq0*8];
    __syncthreads();
    for (int kc = 0; kc < 4; ++kc) {
        if (kc < 3) {
            *(uint4*)&bbuf[((kc+1)&1)*4096 + bw0] = pb0;
            *(uint4*)&bbuf[((kc+1)&1)*4096 + bw1] = pb1;
            if (kc < 2) {
                pb0 = *(const uint4*)&zb[gr0*128 + (kc+2)*32 + gq0*8];
                pb1 = *(const uint4*)&zb[gr1*128 + (kc+2)*32 + gq0*8];
            }
        }
        half8 af[2], bf2[2];
        #pragma unroll
        for (int mf = 0; mf < 2; ++mf) {
            int ra = mf*16 + fr;
            af[mf] = *(const half8*)&xbuf[kc*1024 + ra*32 + ((kg ^ SWZ(ra))*8)];
        }
        #pragma unroll
        for (int nf = 0; nf < 2; ++nf) {
            int rb = wn + nf*16 + fr;
            bf2[nf] = *(const half8*)&bbuf[(kc&1)*4096 + rb*32 + ((kg ^ SWZ(rb))*8)];
        }
        #pragma unroll
        for (int mf = 0; mf < 2; ++mf)
            #pragma unroll
            for (int nf = 0; nf < 2; ++nf)
                acc1[mf][nf] = __builtin_amdgcn_mfma_f32_16x16x32_f16(af[mf], bf2[nf], acc1[mf][nf], 0, 0, 0);
        __syncthreads();
    }
    #pragma unroll
    for (int mf = 0; mf < 2; ++mf)
        #pragma unroll
        for (int nf = 0; nf < 2; ++nf)
            #pragma unroll
            for (int rg = 0; rg < 4; ++rg)
                sbuf[(mf*16 + kg*4 + rg)*128 + wn + nf*16 + fr] = acc1[mf][nf][rg];
    __syncthreads();

    // ---- phase 2: in-LDS cross-chunk scan ----
    {
        int b_loc = tid >> 6, dn = tid & 63;
        if (b_loc < 2) {
            int dir = dn >> 5, n = dn & 31;
            float4 z4 = zwb[hh*NST + n];
            float zcre = z4.z, zcim = z4.w;
            int q1 = n >> 3, e1 = n & 7;
            float pre = 0.f, pim = 0.f;
            for (int s = 0; s < NCH; ++s) {
                int ch = dir ? (NCH - 1 - s) : s;
                int m = b_loc*16 + ch;
                bbuf[(dir*2 + 0)*1024 + m*32 + ((q1 ^ SWZ(m))*8) + e1] = (_Float16)pre;
                bbuf[(dir*2 + 1)*1024 + m*32 + ((q1 ^ SWZ(m))*8) + e1] = (_Float16)pim;
                float cre = sbuf[m*128 + dn*2];
                float cim = sbuf[m*128 + dn*2 + 1];
                float nre = fmaf(zcre, pre, fmaf(-zcim, pim, cre));
                float nim = fmaf(zcre, pim, fmaf(zcim, pre, cim));
                pre = nre; pim = nim;
            }
        }
    }
    __syncthreads();

    // ---- phase 3: y = [x | stp] . wbig^T ----
    f32x4 acc3[2][2];
    #pragma unroll
    for (int i = 0; i < 2; ++i)
        #pragma unroll
        for (int j = 0; j < 2; ++j)
            #pragma unroll
            for (int k = 0; k < 4; ++k) acc3[i][j][k] = 0.f;
    const _Float16* wb = &wbig[(size_t)hh*32768];
    pb0 = *(const uint4*)&wb[gr0*256 + gq0*8];
    pb1 = *(const uint4*)&wb[gr1*256 + gq0*8];
    *(uint4*)&sb16[bw0] = pb0;
    *(uint4*)&sb16[bw1] = pb1;
    pb0 = *(const uint4*)&wb[gr0*256 + 32 + gq0*8];
    pb1 = *(const uint4*)&wb[gr1*256 + 32 + gq0*8];
    __syncthreads();
    for (int kc = 0; kc < 8; ++kc) {
        if (kc < 7) {
            *(uint4*)&sb16[((kc+1)&1)*4096 + bw0] = pb0;
            *(uint4*)&sb16[((kc+1)&1)*4096 + bw1] = pb1;
            if (kc < 6) {
                pb0 = *(const uint4*)&wb[gr0*256 + (kc+2)*32 + gq0*8];
                pb1 = *(const uint4*)&wb[gr1*256 + (kc+2)*32 + gq0*8];
            }
        }
        half8 af[2], bf2[2];
        #pragma unroll
        for (int mf = 0; mf < 2; ++mf) {
            int ra = mf*16 + fr;
            af[mf] = (kc < 4)
                ? *(const half8*)&xbuf[kc*1024 + ra*32 + ((kg ^ SWZ(ra))*8)]
                : *(const half8*)&bbuf[(kc-4)*1024 + ra*32 + ((kg ^ SWZ(ra))*8)];
        }
        #pragma unroll
        for (int nf = 0; nf < 2; ++nf) {
            int rb = wn + nf*16 + fr;
            bf2[nf] = *(const half8*)&sb16[(kc&1)*4096 + rb*32 + ((kg ^ SWZ(rb))*8)];
        }
        #pragma unroll
        for (int mf = 0; mf < 2; ++mf)
            #pragma unroll
            for (int nf = 0; nf < 2; ++nf)
                acc3[mf][nf] = __builtin_amdgcn_mfma_f32_16x16x32_f16(af[mf], bf2[nf], acc3[mf][nf], 0, 0, 0);
        __syncthreads();
    }
    _Float16* yst = sb16;
    #pragma unroll
    for (int mf = 0; mf < 2; ++mf) {
        #pragma unroll
        for (int rg = 0; rg < 4; ++rg) {
            int m = mf*16 + kg*4 + rg;
            #pragma unroll
            for (int nf = 0; nf < 2; ++nf) {
                int t = wn + nf*16 + fr;
                yst[m*136 + t] = (_Float16)gelu_fast(acc3[mf][nf][rg]);
            }
        }
    }
    __syncthreads();
    {
        int r = tid >> 3, tc = (tid & 7) * 16;
        size_t gb = ((size_t)((b0 + (r>>4))*H + hh))*L + (r&15)*128;
        *(half8*)&y16[gb + tc]     = *(half8*)&yst[r*136 + tc];
        *(half8*)&y16[gb + tc + 8] = *(half8*)&yst[r*136 + tc + 8];
    }
}

// ---------------- GLU MFMA fp16 -> fp16 zc, coalesced epilogue; grid (B*L/128, 4) ----------------
__global__ __launch_bounds__(256) void k_glu16(const _Float16* __restrict__ yt,
        const _Float16* __restrict__ wg, const float* __restrict__ bias,
        _Float16* __restrict__ zc) {
    __shared__ _Float16 a_lds[128*32];
    __shared__ _Float16 b_lds[128*32];
    __shared__ float    ep[32*64];
    const int tid = threadIdx.x;
    const int mbase = blockIdx.x * 128;
    const int o0 = blockIdx.y * 64;
    const int lane = tid & 63;
    const int w = tid >> 6;
    const int wm = (w >> 1) * 64, wn = (w & 1) * 32;
    const int fr = lane & 15, kg = lane >> 4;
    const int r0s = tid >> 2, q0 = tid & 3;
    const int r1s = 64 + r0s;
    const int aw0 = r0s*32 + ((q0 ^ SWZ(r0s)) * 8);
    const int aw1 = r1s*32 + ((q0 ^ SWZ(r1s)) * 8);
    const int og0 = o0 + r0s;
    const int og1 = 256 + o0 + r0s;

    f32x4 accg[4][2], accs[4][2];
    #pragma unroll
    for (int i = 0; i < 4; ++i)
        #pragma unroll
        for (int j = 0; j < 2; ++j)
            #pragma unroll
            for (int k = 0; k < 4; ++k) { accg[i][j][k] = 0.f; accs[i][j][k] = 0.f; }

    uint4 pa0, pa1, pb0, pb1;
    auto loadstep = [&](int kc, uint4& a0, uint4& a1, uint4& b0, uint4& b1) {
        const int cb = kc*32 + q0*8;
        a0 = *(const uint4*)&yt[((size_t)(mbase + r0s))*256 + cb];
        a1 = *(const uint4*)&yt[((size_t)(mbase + r1s))*256 + cb];
        b0 = *(const uint4*)&wg[((size_t)og0)*256 + cb];
        b1 = *(const uint4*)&wg[((size_t)og1)*256 + cb];
    };
    loadstep(0, pa0, pa1, pb0, pb1);
    for (int kc = 0; kc < 8; ++kc) {
        __syncthreads();
        *(uint4*)&a_lds[aw0] = pa0;
        *(uint4*)&a_lds[aw1] = pa1;
        *(uint4*)&b_lds[aw0] = pb0;
        *(uint4*)&b_lds[aw1] = pb1;
        uint4 na0 = make_uint4(0,0,0,0), na1 = na0, nb0 = na0, nb1 = na0;
        if (kc < 7) loadstep(kc+1, na0, na1, nb0, nb1);
        __syncthreads();
        half8 af[4], bg[2], bs[2];
        #pragma unroll
        for (int mf = 0; mf < 4; ++mf) {
            int ra = wm + mf*16 + fr;
            af[mf] = *(const half8*)&a_lds[ra*32 + ((kg ^ SWZ(ra)) * 8)];
        }
        #pragma unroll
        for (int nf = 0; nf < 2; ++nf) {
            int rb = wn + nf*16 + fr;
            bg[nf] = *(const half8*)&b_lds[rb*32 + ((kg ^ SWZ(rb)) * 8)];
            int rb2 = 64 + rb;
            bs[nf] = *(const half8*)&b_lds[rb2*32 + ((kg ^ SWZ(rb2)) * 8)];
        }
        #pragma unroll
        for (int mf = 0; mf < 4; ++mf)
            #pragma unroll
            for (int nf = 0; nf < 2; ++nf) {
                accg[mf][nf] = __builtin_amdgcn_mfma_f32_16x16x32_f16(af[mf], bg[nf], accg[mf][nf], 0, 0, 0);
                accs[mf][nf] = __builtin_amdgcn_mfma_f32_16x16x32_f16(af[mf], bs[nf], accs[mf][nf], 0, 0, 0);
            }
        pa0 = na0; pa1 = na1; pb0 = nb0; pb1 = nb1;
    }
    float b0v[2], b1v[2];
    #pragma unroll
    for (int nf = 0; nf < 2; ++nf) {
        int o = o0 + wn + nf*16 + fr;
        b0v[nf] = bias[o]; b1v[nf] = bias[256 + o];
    }
    const int er = tid >> 3, eoc = (tid & 7) * 8;
    #pragma unroll
    for (int mf = 0; mf < 4; ++mf) {
        __syncthreads();
        #pragma unroll
        for (int nf = 0; nf < 2; ++nf) {
            int ol = wn + nf*16 + fr;
            int srb = (w >> 1)*16 + kg*4;
            #pragma unroll
            for (int rg = 0; rg < 4; ++rg) {
                float g = accg[mf][nf][rg] + b0v[nf];
                float s = accs[mf][nf][rg] + b1v[nf];
                ep[(srb + rg)*64 + ol] = g / (1.f + expf(-s));
            }
        }
        __syncthreads();
        size_t m = (size_t)mbase + mf*16 + (er < 16 ? er : 48 + er);
        float4 v0 = *(float4*)&ep[er*64 + eoc];
        float4 v1 = *(float4*)&ep[er*64 + eoc + 4];
        half8 hv;
        hv[0]=(_Float16)v0.x; hv[1]=(_Float16)v0.y; hv[2]=(_Float16)v0.z; hv[3]=(_Float16)v0.w;
        hv[4]=(_Float16)v1.x; hv[5]=(_Float16)v1.y; hv[6]=(_Float16)v1.z; hv[7]=(_Float16)v1.w;
        *(half8*)&zc[m*256 + o0 + eoc] = hv;
    }
}

// ---------------- LayerNorm: fp16 residual stream; last layer adds species + outseq f32 ----------------
template<bool SP>
__global__ __launch_bounds__(256) void k_ln2(const _Float16* __restrict__ zc,
        _Float16* __restrict__ hm, const float* __restrict__ g, const float* __restrict__ bb,
        const int* __restrict__ xs, const float* __restrict__ emb,
        float* __restrict__ outseq) {
    __shared__ float tl[8992];
    int tid = threadIdx.x;
    int b = blockIdx.y;
    int l0 = blockIdx.x * 32;
    for (int j = tid; j < 1024; j += 256) {
        int c = j >> 2, l8 = (j & 3) * 8;
        half8 v = *(const half8*)&hm[((size_t)(b*H + c))*L + l0 + l8];
        #pragma unroll
        for (int e = 0; e < 8; ++e) tl[LDIDX(l8 + e, c)] = (float)v[e];
    }
    __syncthreads();
    int r = tid >> 3, p = tid & 7;
    float v[32];
    float sum = 0.f, ss = 0.f;
    const _Float16* zrow = &zc[((size_t)(b*L + l0 + r))*256 + p*32];
    #pragma unroll
    for (int q = 0; q < 4; ++q) {
        half8 z8 = *(const half8*)&zrow[q*8];
        #pragma unroll
        for (int i = 0; i < 8; ++i) {
            float hv = tl[LDIDX(r, p*32 + q*8 + i)];
            float vv = (float)z8[i] + hv;
            v[q*8+i] = vv;
            sum += vv; ss = fmaf(vv, vv, ss);
        }
    }
    sum += __shfl_xor(sum, 1); ss += __shfl_xor(ss, 1);
    sum += __shfl_xor(sum, 2); ss += __shfl_xor(ss, 2);
    sum += __shfl_xor(sum, 4); ss += __shfl_xor(ss, 4);
    float mu = sum * (1.f/256.f);
    float var = ss * (1.f/256.f) - mu*mu;
    float rs = rsqrtf(var + 1e-5f);
    int sp = SP ? xs[b] : 0;
    #pragma unroll
    for (int q = 0; q < 32; ++q) {
        int c = p*32 + q;
        float val = (v[q] - mu) * rs * g[c] + bb[c];
        if (SP) val += emb[sp*H + c];
        tl[LDIDX(r, c)] = val;
    }
    __syncthreads();
    for (int j = tid; j < 1024; j += 256) {
        int c = j >> 2, l8 = (j & 3) * 8;
        float fv[8];
        half8 hv;
        #pragma unroll
        for (int e = 0; e < 8; ++e) {
            fv[e] = tl[LDIDX(l8 + e, c)];
            hv[e] = (_Float16)fv[e];
        }
        *(half8*)&hm[((size_t)(b*H + c))*L + l0 + l8] = hv;
        if (SP) {
            *(float4*)&outseq[((size_t)(b*H + c))*L + l0 + l8] = make_float4(fv[0],fv[1],fv[2],fv[3]);
            *(float4*)&outseq[((size_t)(b*H + c))*L + l0 + l8 + 4] = make_float4(fv[4],fv[5],fv[6],fv[7]);
        }
    }
}

// ---------------- MFMA decoder conv K=15 ----------------
__global__ __launch_bounds__(128) void k_dec(const _Float16* __restrict__ ht,
        const _Float16* __restrict__ wdk, const float* __restrict__ bias,
        float* __restrict__ outdec) {
    __shared__ _Float16 a_lds[160*32];
    __shared__ _Float16 b_lds[15*16*32];
    const int tid = threadIdx.x;
    const int mbase = blockIdx.x * 128;
    const int b = mbase >> 11;
    const int lbase = mbase & 2047;
    const int lane = tid & 63;
    const int w = tid >> 6;
    const int fr = lane & 15, kg = lane >> 4;
    const int rs = tid >> 2, q0 = tid & 3;
    f32x4 acc[4];
    #pragma unroll
    for (int i = 0; i < 4; ++i)
        #pragma unroll
        for (int k = 0; k < 4; ++k) acc[i][k] = 0.f;
    for (int cc = 0; cc < 8; ++cc) {
        __syncthreads();
        #pragma unroll
        for (int ps = 0; ps < 5; ++ps) {
            int r = ps*32 + rs;
            if (r < 142) {
                int l = lbase - 7 + r;
                uint4 v = (l >= 0 && l < L) ? *(const uint4*)&ht[((size_t)(b*L + l))*256 + cc*32 + q0*8]
                                            : make_uint4(0,0,0,0);
                *(uint4*)&a_lds[r*32 + ((q0 ^ SWZ(r))*8)] = v;
            }
        }
        for (int jj = tid; jj < 960; jj += 128)
            *(uint4*)&b_lds[jj*8] = *(const uint4*)&wdk[cc*7680 + jj*8];
        __syncthreads();
        #pragma unroll
        for (int k = 0; k < 15; ++k) {
            half8 bfr = *(const half8*)&b_lds[(k*16 + fr)*32 + ((kg ^ SWZ(fr))*8)];
            #pragma unroll
            for (int mf = 0; mf < 4; ++mf) {
                int ra = w*64 + mf*16 + fr + k;
                half8 af = *(const half8*)&a_lds[ra*32 + ((kg ^ SWZ(ra))*8)];
                acc[mf] = __builtin_amdgcn_mfma_f32_16x16x32_f16(af, bfr, acc[mf], 0, 0, 0);
            }
        }
    }
    if (fr < DOUT) {
        float bo = bias[fr];
        #pragma unroll
        for (int mf = 0; mf < 4; ++mf)
            #pragma unroll
            for (int rg = 0; rg < 4; ++rg) {
                int m = mbase + w*64 + mf*16 + kg*4 + rg;
                outdec[((size_t)(b*DOUT + fr))*L + (m & 2047)] = acc[mf][rg] + bo;
            }
    }
}

// ---------------- mean over L (fp16 input) ----------------
__global__ __launch_bounds__(256) void k_agg(const _Float16* __restrict__ h, float* __restrict__ agg) {
    __shared__ float red[256];
    int bc = blockIdx.x;
    int tid = threadIdx.x;
    half8 v = *(const half8*)&h[(size_t)bc*L + tid*8];
    float s = 0.f;
    #pragma unroll
    for (int e = 0; e < 8; ++e) s += (float)v[e];
    red[tid] = s; __syncthreads();
    for (int k = 128; k > 0; k >>= 1) {
        if (tid < k) red[tid] += red[tid+k];
        __syncthreads();
    }
    if (tid == 0) agg[bc] = red[0] * (1.f/(float)L);
}

// ---------------- regression MLP ----------------
__global__ __launch_bounds__(128) void k_mlp(const float* __restrict__ agg,
        const float* __restrict__ w1, const float* __restrict__ b1,
        const float* __restrict__ w2, const float* __restrict__ b2,
        const float* __restrict__ w3, const float* __restrict__ b3,
        const float* __restrict__ w4, const float* __restrict__ b4,
        float* __restrict__ outreg) {
    __shared__ float a0[256], r1[128], r2[64], r3[32];
    int b = blockIdx.x, tid = threadIdx.x;
    a0[tid] = agg[b*256 + tid];
    a0[tid+128] = agg[b*256 + tid + 128];
    __syncthreads();
    {
        float s = b1[tid];
        for (int k = 0; k < 256; ++k) s = fmaf(w1[tid*256+k], a0[k], s);
        r1[tid] = s > 0.f ? s : expm1f(s);
    }
    __syncthreads();
    if (tid < 64) {
        float s = b2[tid];
        for (int k = 0; k < 128; ++k) s = fmaf(w2[tid*128+k], r1[k], s);
        r2[tid] = s > 0.f ? s : expm1f(s);
    }
    __syncthreads();
    if (tid < 32) {
        float s = b3[tid];
        for (int k = 0; k < 64; ++k) s = fmaf(w3[tid*64+k], r2[k], s);
        r3[tid] = s > 0.f ? s : expm1f(s);
    }
    __syncthreads();
    if (tid == 0) {
        float s = b4[0];
        for (int k = 0; k < 32; ++k) s = fmaf(w4[k], r3[k], s);
        outreg[b] = s;
    }
}

extern "C" void kernel_launch(void* const* d_in, const int* in_sizes, int n_in,
                              void* d_out, int out_size, void* d_ws, size_t ws_size,
                              hipStream_t stream) {
    const float* x      = (const float*)d_in[0];
    const int*   xs     = (const int*)d_in[1];
    const float* enc_w  = (const float*)d_in[2];
    const float* enc_b  = (const float*)d_in[3];
    const float* res_w1 = (const float*)d_in[4];
    const float* res_b1 = (const float*)d_in[5];
    const float* res_w2 = (const float*)d_in[6];
    const float* res_b2 = (const float*)d_in[7];
    const float* log_dt = (const float*)d_in[8];
    const float* lam_re = (const float*)d_in[9];
    const float* lam_im = (const float*)d_in[10];
    const float* W_re   = (const float*)d_in[11];
    const float* W_im   = (const float*)d_in[12];
    const float* Dv     = (const float*)d_in[13];
    const float* glu_w  = (const float*)d_in[14];
    const float* glu_b  = (const float*)d_in[15];
    const float* ln_g   = (const float*)d_in[16];
    const float* ln_b   = (const float*)d_in[17];
    const float* dec_w  = (const float*)d_in[18];
    const float* dec_b  = (const float*)d_in[19];
    const float* sp_emb = (const float*)d_in[20];
    const float* h1_w = (const float*)d_in[21]; const float* h1_b = (const float*)d_in[22];
    const float* h2_w = (const float*)d_in[23]; const float* h2_b = (const float*)d_in[24];
    const float* h3_w = (const float*)d_in[25]; const float* h3_b = (const float*)d_in[26];
    const float* h4_w = (const float*)d_in[27]; const float* h4_b = (const float*)d_in[28];

    float* ws   = (float*)d_ws;
    _Float16* hm16 = (_Float16*)ws;                    // fp16 chm residual (persistent)
    float* t1   = ws + (size_t)LSEQ;
    float* t2   = ws + (size_t)2*LSEQ;
    // res-phase:
    _Float16* xb  = (_Float16*)t1;
    _Float16* xa  = (_Float16*)t1 + (size_t)LSEQ;
    _Float16* wpk = (_Float16*)t2;
    // DSS-phase:
    _Float16* yt   = (_Float16*)t1;                    // fp16 chl y (t1 lower)
    _Float16* wbig = (_Float16*)t1 + (size_t)LSEQ;     // 16MB (t1 upper)
    _Float16* zp   = wbig + (size_t)H*32768;           // 8MB
    _Float16* y16  = (_Float16*)t2;                    // fp16 chm y
    _Float16* zc16 = (_Float16*)t2;                    // glu out fp16 chl (y16 dead)
    _Float16* dect = (_Float16*)t1;                    // decoder chl input
    // tail:
    float* tail = ws + (size_t)3*LSEQ;
    _Float16* wg  = (_Float16*)tail;
    float4* zwb = (float4*)(tail + 65536);
    float* aggb = tail + 65536 + 32768;
    _Float16* wdk = (_Float16*)(aggb + 8192);
    _Float16* wenc = wdk + 61440;

    float* outdec = (float*)d_out;
    float* outseq = outdec + B*DOUT*L;
    float* outreg = outseq + (size_t)LSEQ;

    // encoder
    k_wenc<<<96, 256, 0, stream>>>(enc_w, wenc);
    k_enc<<<dim3(B*L/128, 2), 256, 0, stream>>>(x, wenc, enc_b, xa);

    // residual stack
    k_wpack<<<(NRES*2*3*65536 + 255)/256, 256, 0, stream>>>(res_w1, res_w2, wpk);
    for (int r = 0; r < NRES; ++r) {
        k_cv3<false><<<B*L/128, 256, 0, stream>>>(
            xa, wpk + (size_t)(r*2+0)*3*65536, res_b1 + r*H, nullptr, xb);
        k_cv3<true><<<B*L/128, 256, 0, stream>>>(
            xb, wpk + (size_t)(r*2+1)*3*65536, res_b2 + r*H, xa, xa);
    }
    k_t_cf16<<<dim3(L/64, H/64, B), 256, 0, stream>>>(xa, hm16);

    // DSS blocks
    for (int i = 0; i < NLAYERS; ++i) {
        k_wkern<<<H, 128, 0, stream>>>(log_dt, lam_re, lam_im, W_re, W_im, Dv, glu_w,
                                       wbig, wg, zp, zwb, i);
        k_dss<<<dim3(H, 16), 256, 0, stream>>>(hm16, zp, wbig, zwb, y16, i);
        k_t16<<<dim3(L/64, H/64, B), 256, 0, stream>>>(y16, yt);
        k_glu16<<<dim3(B*L/128, 4), 256, 0, stream>>>(yt, wg, glu_b + i*512, zc16);
        if (i < NLAYERS - 1)
            k_ln2<false><<<dim3(L/32, B), 256, 0, stream>>>(zc16, hm16, ln_g + i*H, ln_b + i*H,
                                                            nullptr, nullptr, nullptr);
        else
            k_ln2<true><<<dim3(L/32, B), 256, 0, stream>>>(zc16, hm16, ln_g + i*H, ln_b + i*H,
                                                           xs, sp_emb, outseq);
    }

    // aggregate + regression head
    k_agg<<<B*H, 256, 0, stream>>>(hm16, aggb);
    k_mlp<<<B, 128, 0, stream>>>(aggb, h1_w, h1_b, h2_w, h2_b, h3_w, h3_b, h4_w, h4_b, outreg);
    // decoder
    k_t16<<<dim3(L/64, H/64, B), 256, 0, stream>>>(hm16, dect);
    k_wdec<<<(15*16*256 + 255)/256, 256, 0, stream>>>(dec_w, wdk);
    k_dec<<<B*L/128, 128, 0, stream>>>(dect, wdk, dec_b, outdec);
}

// Round 16
// 995.424 us; speedup vs baseline: 1.2518x; 1.0840x over previous
//
#include <hip/hip_runtime.h>
#include <math.h>

#define B 32
#define L 2048
#define DIN 5
#define DOUT 5
#define H 256
#define NST 32
#define NLAYERS 4
#define NRES 3
#define CHUNK 128
#define NCH 16            // L / CHUNK
#define LSEQ (B*H*L)      // 16777216

typedef __attribute__((ext_vector_type(8))) _Float16 half8;
typedef __attribute__((ext_vector_type(4))) float f32x4;

// A&S 7.1.26: |erf err| < 1.5e-7 -> gelu err ~1e-7, invisible vs fp16 rounding (5e-4)
__device__ __forceinline__ float gelu_fast(float v) {
    float x = v * 0.7071067811865475f;
    float ax = fabsf(x);
    float t = 1.f / fmaf(0.3275911f, ax, 1.f);
    float poly = t*(0.254829592f + t*(-0.284496736f + t*(1.421413741f +
                 t*(-1.453152027f + t*1.061405429f))));
    float e = __expf(-ax*ax);
    float erfv = copysignf(1.f - poly*e, x);
    return 0.5f * v * (1.f + erfv);
}
#define SWZ(r) ((((r) ^ ((r) >> 2)) & 3))
#define LDIDX(l, c) ((l)*281 + ((c)>>5)*35 + ((c)&31))

// ---------------- encoder weight pack ----------------
__global__ void k_wenc(const float* __restrict__ ew, _Float16* __restrict__ wenc) {
    int idx = blockIdx.x*256 + threadIdx.x;
    if (idx >= 256*96) return;
    int o = idx / 96, kk = idx % 96;
    int ci = kk >> 4, k = kk & 15;
    float v = (ci < DIN && k < 15) ? ew[(o*DIN + ci)*15 + k] : 0.f;
    wenc[idx] = (_Float16)v;
}

// ---------------- MFMA encoder conv K=15 Cin=5 ----------------
__global__ __launch_bounds__(256) void k_enc(const float* __restrict__ x,
        const _Float16* __restrict__ wenc, const float* __restrict__ bias,
        _Float16* __restrict__ out) {
    __shared__ _Float16 a_lds[3*128*32];
    __shared__ _Float16 b_lds[3*128*32];
    const int tid = threadIdx.x;
    const int mbase = blockIdx.x * 128;
    const int oh = blockIdx.y;
    const int b = mbase >> 11;
    const int lbase = mbase & 2047;
    const int lane = tid & 63;
    const int w = tid >> 6;
    const int wm = (w >> 1) * 64, wn = (w & 1) * 64;
    const int fr = lane & 15, kg = lane >> 4;

    #pragma unroll
    for (int i = 0; i < 6; ++i) {
        int g = i*256 + tid;
        int r = g / 12, rem = g % 12;
        int ks = rem >> 2, q = rem & 3;
        int kk0 = ks*32 + q*8;
        int ci = kk0 >> 4, k0 = kk0 & 15;
        half8 va;
        #pragma unroll
        for (int e = 0; e < 8; ++e) {
            int k = k0 + e;
            int l = lbase + r - 7 + k;
            float v = (ci < DIN && k < 15 && l >= 0 && l < L)
                        ? x[((size_t)(b*DIN + ci))*L + l] : 0.f;
            va[e] = (_Float16)v;
        }
        *(half8*)&a_lds[ks*4096 + r*32 + ((q ^ SWZ(r))*8)] = va;
        uint4 vb = *(const uint4*)&wenc[(size_t)(oh*128 + r)*96 + kk0];
        *(uint4*)&b_lds[ks*4096 + r*32 + ((q ^ SWZ(r))*8)] = vb;
    }
    __syncthreads();
    f32x4 acc[4][4];
    #pragma unroll
    for (int i = 0; i < 4; ++i)
        #pragma unroll
        for (int j = 0; j < 4; ++j)
            #pragma unroll
            for (int k = 0; k < 4; ++k) acc[i][j][k] = 0.f;
    #pragma unroll
    for (int ks = 0; ks < 3; ++ks) {
        half8 af[4], bfr[4];
        #pragma unroll
        for (int mf = 0; mf < 4; ++mf) {
            int ra = wm + mf*16 + fr;
            af[mf] = *(const half8*)&a_lds[ks*4096 + ra*32 + ((kg ^ SWZ(ra))*8)];
        }
        #pragma unroll
        for (int nf = 0; nf < 4; ++nf) {
            int rb = wn + nf*16 + fr;
            bfr[nf] = *(const half8*)&b_lds[ks*4096 + rb*32 + ((kg ^ SWZ(rb))*8)];
        }
        #pragma unroll
        for (int mf = 0; mf < 4; ++mf)
            #pragma unroll
            for (int nf = 0; nf < 4; ++nf)
                acc[mf][nf] = __builtin_amdgcn_mfma_f32_16x16x32_f16(af[mf], bfr[nf], acc[mf][nf], 0, 0, 0);
    }
    #pragma unroll
    for (int nf = 0; nf < 4; ++nf) {
        int o = oh*128 + wn + nf*16 + fr;
        float bo = bias[o];
        #pragma unroll
        for (int mf = 0; mf < 4; ++mf)
            #pragma unroll
            for (int rg = 0; rg < 4; ++rg) {
                size_t m = (size_t)mbase + wm + mf*16 + kg*4 + rg;
                out[m*256 + o] = (_Float16)(acc[mf][nf][rg] + bo);
            }
    }
}

// ---------------- res weight pack ----------------
__global__ void k_wpack(const float* __restrict__ w1, const float* __restrict__ w2,
                        _Float16* __restrict__ wpk) {
    int idx = blockIdx.x*256 + threadIdx.x;
    if (idx >= NRES*2*3*65536) return;
    int ci = idx & 255;
    int o  = (idx >> 8) & 255;
    int k  = (idx >> 16) % 3;
    int cv = idx / (3*65536);
    const float* src = (cv & 1) ? w2 : w1;
    wpk[idx] = (_Float16)src[(((cv>>1)*H + o)*H + ci)*3 + k];
}

// ---------------- transpose fp16 chl -> fp16 chm (half8 global both sides) ----------------
__global__ __launch_bounds__(256) void k_t_cf16(const _Float16* __restrict__ in,
        _Float16* __restrict__ out) {
    __shared__ float t[64][65];
    int tid = threadIdx.x;
    int l0 = blockIdx.x*64, c0 = blockIdx.y*64, b = blockIdx.z;
    #pragma unroll
    for (int i = 0; i < 2; ++i) {
        int g = i*256 + tid;
        int c8 = (g & 7) * 8, l = g >> 3;
        half8 v = *(const half8*)&in[((size_t)b*L + l0 + l)*256 + c0 + c8];
        #pragma unroll
        for (int e = 0; e < 8; ++e) t[c8 + e][l] = (float)v[e];
    }
    __syncthreads();
    #pragma unroll
    for (int i = 0; i < 2; ++i) {
        int g = i*256 + tid;
        int l8 = (g & 7) * 8, c = g >> 3;
        half8 hv;
        #pragma unroll
        for (int e = 0; e < 8; ++e) hv[e] = (_Float16)t[c][l8 + e];
        *(half8*)&out[((size_t)(b*H + c0 + c))*L + l0 + l8] = hv;
    }
}

// ---------------- transpose fp16 chm -> fp16 chl (half8 global both sides) ----------------
__global__ __launch_bounds__(256) void k_t16(const _Float16* __restrict__ in,
                                             _Float16* __restrict__ out) {
    __shared__ float t[64][65];
    int tid = threadIdx.x;
    int l0 = blockIdx.x*64, c0 = blockIdx.y*64, b = blockIdx.z;
    #pragma unroll
    for (int i = 0; i < 2; ++i) {
        int g = i*256 + tid;
        int l8 = (g & 7) * 8, c = g >> 3;
        half8 v = *(const half8*)&in[((size_t)(b*H + c0 + c))*L + l0 + l8];
        #pragma unroll
        for (int e = 0; e < 8; ++e) t[c][l8 + e] = (float)v[e];
    }
    __syncthreads();
    #pragma unroll
    for (int i = 0; i < 2; ++i) {
        int g = i*256 + tid;
        int c8 = (g & 7) * 8, l = g >> 3;
        half8 hv;
        #pragma unroll
        for (int e = 0; e < 8; ++e) hv[e] = (_Float16)t[c8 + e][l];
        *(half8*)&out[((size_t)b*L + l0 + l)*256 + c0 + c8] = hv;
    }
}

// ---------------- MFMA residual conv K=3: full-N tile 128m x 256o, coalesced epilogue ----------------
template<bool RESID>
__global__ __launch_bounds__(256, 2) void k_cv3(const _Float16* __restrict__ xin,
        const _Float16* __restrict__ wpk, const float* __restrict__ bias,
        const _Float16* __restrict__ resid, _Float16* __restrict__ out) {
    __shared__ _Float16 a_lds[128*32];
    __shared__ _Float16 b_lds[256*32];
    __shared__ float    ep[32*256];
    const int tid = threadIdx.x;
    const int mbase = blockIdx.x * 128;
    const int lane = tid & 63;
    const int w = tid >> 6;
    const int wm = (w >> 1) * 64, wo = (w & 1) * 128;
    const int fr = lane & 15, kg = lane >> 4;

    const int r0s = tid >> 2, q0 = tid & 3;
    const int sq = SWZ(r0s);
    const int awA0 = r0s*32 + ((q0 ^ sq) * 8);
    const int awA1 = (64 + r0s)*32 + ((q0 ^ SWZ(64 + r0s)) * 8);

    f32x4 acc[4][8];
    #pragma unroll
    for (int i = 0; i < 4; ++i)
        #pragma unroll
        for (int j = 0; j < 8; ++j)
            #pragma unroll
            for (int k = 0; k < 4; ++k) acc[i][j][k] = 0.f;

    uint4 pa0, pa1, pb[4];
    auto loadstep = [&](int kk, uint4& a0, uint4& a1, uint4 (&bb)[4]) {
        const int koff = kk >> 3, cic = kk & 7;
        const int cb = cic*32 + q0*8;
        {
            int m = mbase + r0s;
            int ll = (m & (L-1)) + koff - 1;
            a0 = (ll >= 0 && ll < L) ? *(const uint4*)&xin[((size_t)(m + koff - 1))*256 + cb]
                                     : make_uint4(0,0,0,0);
            int m1 = mbase + 64 + r0s;
            int l1 = (m1 & (L-1)) + koff - 1;
            a1 = (l1 >= 0 && l1 < L) ? *(const uint4*)&xin[((size_t)(m1 + koff - 1))*256 + cb]
                                     : make_uint4(0,0,0,0);
        }
        #pragma unroll
        for (int u = 0; u < 4; ++u)
            bb[u] = *(const uint4*)&wpk[((size_t)(koff*256 + u*64 + r0s))*256 + cb];
    };
    loadstep(0, pa0, pa1, pb);
    for (int kk = 0; kk < 24; ++kk) {
        __syncthreads();
        *(uint4*)&a_lds[awA0] = pa0;
        *(uint4*)&a_lds[awA1] = pa1;
        #pragma unroll
        for (int u = 0; u < 4; ++u)
            *(uint4*)&b_lds[(u*64 + r0s)*32 + ((q0 ^ sq)*8)] = pb[u];
        uint4 na0 = make_uint4(0,0,0,0), na1 = na0, nb[4] = {na0, na0, na0, na0};
        if (kk < 23) loadstep(kk+1, na0, na1, nb);
        __syncthreads();
        half8 af[4];
        #pragma unroll
        for (int mf = 0; mf < 4; ++mf) {
            int ra = wm + mf*16 + fr;
            af[mf] = *(const half8*)&a_lds[ra*32 + ((kg ^ SWZ(ra)) * 8)];
        }
        #pragma unroll
        for (int nf = 0; nf < 8; ++nf) {
            int rb = wo + nf*16 + fr;
            half8 bfr = *(const half8*)&b_lds[rb*32 + ((kg ^ SWZ(rb)) * 8)];
            #pragma unroll
            for (int mf = 0; mf < 4; ++mf)
                acc[mf][nf] = __builtin_amdgcn_mfma_f32_16x16x32_f16(af[mf], bfr, acc[mf][nf], 0, 0, 0);
        }
        pa0 = na0; pa1 = na1;
        #pragma unroll
        for (int u = 0; u < 4; ++u) pb[u] = nb[u];
    }
    float bo8[8];
    #pragma unroll
    for (int nf = 0; nf < 8; ++nf) bo8[nf] = bias[wo + nf*16 + fr];
    const int er = tid >> 3, eoc = (tid & 7) * 32;
    #pragma unroll
    for (int mf = 0; mf < 4; ++mf) {
        __syncthreads();
        #pragma unroll
        for (int nf = 0; nf < 8; ++nf) {
            int o = wo + nf*16 + fr;
            int srb = (w >> 1)*16 + kg*4;
            #pragma unroll
            for (int rg = 0; rg < 4; ++rg)
                ep[(srb + rg)*256 + o] = acc[mf][nf][rg] + bo8[nf];
        }
        __syncthreads();
        size_t m = (size_t)mbase + mf*16 + (er < 16 ? er : 48 + er);
        #pragma unroll
        for (int u = 0; u < 4; ++u) {
            float4 v0 = *(float4*)&ep[er*256 + eoc + u*8];
            float4 v1 = *(float4*)&ep[er*256 + eoc + u*8 + 4];
            float vv[8] = {v0.x, v0.y, v0.z, v0.w, v1.x, v1.y, v1.z, v1.w};
            if (RESID) {
                half8 rv = *(const half8*)&resid[m*256 + eoc + u*8];
                #pragma unroll
                for (int e = 0; e < 8; ++e) vv[e] += (float)rv[e];
            }
            half8 hv;
            #pragma unroll
            for (int e = 0; e < 8; ++e) hv[e] = (_Float16)fmaxf(vv[e], 0.f);
            *(half8*)&out[m*256 + eoc + u*8] = hv;
        }
    }
}

// ---------------- W_big + zp + zwb + wg for ALL layers: grid (H, NLAYERS) ----------------
__global__ __launch_bounds__(128) void k_wkern(const float* __restrict__ log_dt,
        const float* __restrict__ lam_re, const float* __restrict__ lam_im,
        const float* __restrict__ W_re, const float* __restrict__ W_im,
        const float* __restrict__ Dv, const float* __restrict__ gw,
        _Float16* __restrict__ wbigA, _Float16* __restrict__ wbigB,
        _Float16* __restrict__ wg_all,
        _Float16* __restrict__ zp_all, float4* __restrict__ zwb_all) {
    __shared__ float kf[128], kb[128];
    __shared__ _Float16 E16[128*130];
    const int hh = blockIdx.x;
    const int layer = blockIdx.y;
    const int t = threadIdx.x;
    float dt = expf(log_dt[layer*H + hh]);
    float skf = 0.f, skb = 0.f;
    for (int n = 0; n < 32; ++n) {
        float a  = dt * lam_re[layer*NST + n];
        float bi = dt * lam_im[layer*NST + n];
        float wfr = W_re[((layer*2+0)*H + hh)*NST + n];
        float wfi = W_im[((layer*2+0)*H + hh)*NST + n];
        float wbr = W_re[((layer*2+1)*H + hh)*NST + n];
        float wbi = W_im[((layer*2+1)*H + hh)*NST + n];
        float e0 = expf(a*t), s0, c0; sincosf(bi*t, &s0, &c0);
        float zr0 = e0*c0, zi0 = e0*s0;
        skf = fmaf(wfr, zr0, skf) - wfi*zi0;
        skb = fmaf(wbr, zr0, skb) - wbi*zi0;
        float e1 = expf(a*(t+1)), s1, c1; sincosf(bi*(t+1), &s1, &c1);
        float zr1 = e1*c1, zi1 = e1*s1;
        E16[t*130 + n]      = (_Float16)(wfr*zr1 - wfi*zi1);
        E16[t*130 + 32 + n] = (_Float16)(-(wfr*zi1 + wfi*zr1));
        float e2 = expf(a*(127-t)), s2, c2; sincosf(bi*(127-t), &s2, &c2);
        float zr2 = e2*c2, zi2 = e2*s2;
        E16[t*130 + 64 + n] = (_Float16)(wbr*zr2 - wbi*zi2);
        E16[t*130 + 96 + n] = (_Float16)(-(wbr*zi2 + wbi*zr2));
    }
    kf[t] = skf + ((t == 0) ? Dv[layer*H + hh] : 0.f);
    kb[t] = skb;
    __syncthreads();
    _Float16* dst = (layer < 2 ? wbigA + (size_t)layer*H*32768
                               : wbigB + (size_t)(layer-2)*H*32768)
                    + (size_t)hh*32768;
    for (int idx = t; idx < 128*256; idx += 128) {
        int tt = idx >> 8, k = idx & 255;
        if (k < 128) dst[idx] = (_Float16)((k <= tt) ? kf[tt - k] : kb[k - tt - 1]);
        else         dst[idx] = E16[tt*130 + (k - 128)];
    }
    const float* gsrc = &gw[(size_t)layer*131072 + (size_t)hh*512];
    _Float16* gdst = &wg_all[(size_t)layer*131072 + (size_t)hh*512];
    for (int j = t; j < 512; j += 128) gdst[j] = (_Float16)gsrc[j];
    // zp + zwb
    {
        int dn = t >> 1, c = t & 1, dir = dn >> 5, n = dn & 31;
        float a  = dt * lam_re[layer*NST + n];
        float bi = dt * lam_im[layer*NST + n];
        float er = expf(a);
        float zre = er * cosf(bi), zim = er * sinf(bi);
        if (c == 0 && dir == 0) {
            float eC = expf(a * (float)CHUNK);
            float s, co; sincosf(bi * (float)CHUNK, &s, &co);
            zwb_all[layer*H*NST + hh*NST + n] = make_float4(zre, zim, eC*co, eC*s);
        }
        _Float16* zdst = &zp_all[(size_t)layer*H*16384 + (size_t)hh*16384 + t*128];
        float cr = 1.f, ci = 0.f;
        for (int p = 0; p < 128; ++p) {
            float val = c ? ci : cr;
            zdst[dir ? p : (127 - p)] = (_Float16)val;
            float nr = cr*zre - ci*zim;
            float ni = cr*zim + ci*zre;
            cr = nr; ci = ni;
        }
    }
}

// ---------------- decoder weight pack ----------------
__global__ void k_wdec(const float* __restrict__ dw, _Float16* __restrict__ wdk) {
    int idx = blockIdx.x*256 + threadIdx.x;
    if (idx >= 15*16*256) return;
    int cfull = idx & 255;
    int o = (idx >> 8) & 15;
    int k = idx >> 12;
    float v = (o < DOUT) ? dw[(o*H + cfull)*15 + k] : 0.f;
    int cc = cfull >> 5, cl = cfull & 31;
    int cq = cl >> 3, cb = cl & 7;
    wdk[cc*7680 + (k*16 + o)*32 + ((cq ^ SWZ(o))*8) + cb] = (_Float16)v;
}

// ---------------- FUSED DSS v3: M=32 (grid H x 16), 40KB LDS, single-barrier dbuf ----------------
__global__ __launch_bounds__(256, 4) void k_dss(const _Float16* __restrict__ hm16,
        const _Float16* __restrict__ zp, const _Float16* __restrict__ wbig,
        const float4* __restrict__ zwb, _Float16* __restrict__ y16) {
    __shared__ _Float16 xbuf[4*32*32];
    __shared__ _Float16 bbuf[2*128*32];
    __shared__ float    sbuf[32*128];
    _Float16* sb16 = (_Float16*)sbuf;

    const int tid = threadIdx.x;
    const int hh = blockIdx.x;
    const int b0 = blockIdx.y * 2;
    const int lane = tid & 63;
    const int w = tid >> 6;
    const int wn = w * 32;
    const int fr = lane & 15, kg = lane >> 4;

    #pragma unroll
    for (int i = 0; i < 2; ++i) {
        int g = i*256 + tid;
        int m = g >> 4, gi = g & 15;
        int kc = gi >> 2, q = gi & 3;
        uint4 v = *(const uint4*)&hm16[((size_t)((b0 + (m>>4))*H + hh))*L
                                       + (m&15)*128 + kc*32 + q*8];
        *(uint4*)&xbuf[kc*1024 + m*32 + ((q ^ SWZ(m))*8)] = v;
    }

    // ---- phase 1: S = x . zp^T ----
    f32x4 acc1[2][2];
    #pragma unroll
    for (int i = 0; i < 2; ++i)
        #pragma unroll
        for (int j = 0; j < 2; ++j)
            #pragma unroll
            for (int k = 0; k < 4; ++k) acc1[i][j][k] = 0.f;
    const _Float16* zb = &zp[(size_t)hh*16384];
    const int gr0 = tid >> 2, gq0 = tid & 3;
    const int gr1 = 64 + gr0;
    const int bw0 = gr0*32 + ((gq0 ^ SWZ(gr0))*8);
    const int bw1 = gr1*32 + ((gq0 ^ SWZ(gr1))*8);
    uint4 pb0 = *(const uint4*)&zb[gr0*128 + gq0*8];
    uint4 pb1 = *(const uint4*)&zb[gr1*128 + gq0*8];
    *(uint4*)&bbuf[bw0] = pb0;
    *(uint4*)&bbuf[bw1] = pb1;
    pb0 = *(const uint4*)&zb[gr0*128 + 32 + gq0*8];
    pb1 = *(const uint4*)&zb[gr1*128 + 32 + gq0*8];
    __syncthreads();
    for (int kc = 0; kc < 4; ++kc) {
        if (kc < 3) {
            *(uint4*)&bbuf[((kc+1)&1)*4096 + bw0] = pb0;
            *(uint4*)&bbuf[((kc+1)&1)*4096 + bw1] = pb1;
            if (kc < 2) {
                pb0 = *(const uint4*)&zb[gr0*128 + (kc+2)*32 + gq0*8];
                pb1 = *(const uint4*)&zb[gr1*128 + (kc+2)*32 + gq0*8];
            }
        }
        half8 af[2], bf2[2];
        #pragma unroll
        for (int mf = 0; mf < 2; ++mf) {
            int ra = mf*16 + fr;
            af[mf] = *(const half8*)&xbuf[kc*1024 + ra*32 + ((kg ^ SWZ(ra))*8)];
        }
        #pragma unroll
        for (int nf = 0; nf < 2; ++nf) {
            int rb = wn + nf*16 + fr;
            bf2[nf] = *(const half8*)&bbuf[(kc&1)*4096 + rb*32 + ((kg ^ SWZ(rb))*8)];
        }
        #pragma unroll
        for (int mf = 0; mf < 2; ++mf)
            #pragma unroll
            for (int nf = 0; nf < 2; ++nf)
                acc1[mf][nf] = __builtin_amdgcn_mfma_f32_16x16x32_f16(af[mf], bf2[nf], acc1[mf][nf], 0, 0, 0);
        __syncthreads();
    }
    #pragma unroll
    for (int mf = 0; mf < 2; ++mf)
        #pragma unroll
        for (int nf = 0; nf < 2; ++nf)
            #pragma unroll
            for (int rg = 0; rg < 4; ++rg)
                sbuf[(mf*16 + kg*4 + rg)*128 + wn + nf*16 + fr] = acc1[mf][nf][rg];
    __syncthreads();

    // ---- phase 2: in-LDS cross-chunk scan ----
    {
        int b_loc = tid >> 6, dn = tid & 63;
        if (b_loc < 2) {
            int dir = dn >> 5, n = dn & 31;
            float4 z4 = zwb[hh*NST + n];
            float zcre = z4.z, zcim = z4.w;
            int q1 = n >> 3, e1 = n & 7;
            float pre = 0.f, pim = 0.f;
            for (int s = 0; s < NCH; ++s) {
                int ch = dir ? (NCH - 1 - s) : s;
                int m = b_loc*16 + ch;
                bbuf[(dir*2 + 0)*1024 + m*32 + ((q1 ^ SWZ(m))*8) + e1] = (_Float16)pre;
                bbuf[(dir*2 + 1)*1024 + m*32 + ((q1 ^ SWZ(m))*8) + e1] = (_Float16)pim;
                float cre = sbuf[m*128 + dn*2];
                float cim = sbuf[m*128 + dn*2 + 1];
                float nre = fmaf(zcre, pre, fmaf(-zcim, pim, cre));
                float nim = fmaf(zcre, pim, fmaf(zcim, pre, cim));
                pre = nre; pim = nim;
            }
        }
    }
    __syncthreads();

    // ---- phase 3: y = [x | stp] . wbig^T ----
    f32x4 acc3[2][2];
    #pragma unroll
    for (int i = 0; i < 2; ++i)
        #pragma unroll
        for (int j = 0; j < 2; ++j)
            #pragma unroll
            for (int k = 0; k < 4; ++k) acc3[i][j][k] = 0.f;
    const _Float16* wb = &wbig[(size_t)hh*32768];
    pb0 = *(const uint4*)&wb[gr0*256 + gq0*8];
    pb1 = *(const uint4*)&wb[gr1*256 + gq0*8];
    *(uint4*)&sb16[bw0] = pb0;
    *(uint4*)&sb16[bw1] = pb1;
    pb0 = *(const uint4*)&wb[gr0*256 + 32 + gq0*8];
    pb1 = *(const uint4*)&wb[gr1*256 + 32 + gq0*8];
    __syncthreads();
    for (int kc = 0; kc < 8; ++kc) {
        if (kc < 7) {
            *(uint4*)&sb16[((kc+1)&1)*4096 + bw0] = pb0;
            *(uint4*)&sb16[((kc+1)&1)*4096 + bw1] = pb1;
            if (kc < 6) {
                pb0 = *(const uint4*)&wb[gr0*256 + (kc+2)*32 + gq0*8];
                pb1 = *(const uint4*)&wb[gr1*256 + (kc+2)*32 + gq0*8];
            }
        }
        half8 af[2], bf2[2];
        #pragma unroll
        for (int mf = 0; mf < 2; ++mf) {
            int ra = mf*16 + fr;
            af[mf] = (kc < 4)
                ? *(const half8*)&xbuf[kc*1024 + ra*32 + ((kg ^ SWZ(ra))*8)]
                : *(const half8*)&bbuf[(kc-4)*1024 + ra*32 + ((kg ^ SWZ(ra))*8)];
        }
        #pragma unroll
        for (int nf = 0; nf < 2; ++nf) {
            int rb = wn + nf*16 + fr;
            bf2[nf] = *(const half8*)&sb16[(kc&1)*4096 + rb*32 + ((kg ^ SWZ(rb))*8)];
        }
        #pragma unroll
        for (int mf = 0; mf < 2; ++mf)
            #pragma unroll
            for (int nf = 0; nf < 2; ++nf)
                acc3[mf][nf] = __builtin_amdgcn_mfma_f32_16x16x32_f16(af[mf], bf2[nf], acc3[mf][nf], 0, 0, 0);
        __syncthreads();
    }
    _Float16* yst = sb16;
    #pragma unroll
    for (int mf = 0; mf < 2; ++mf) {
        #pragma unroll
        for (int rg = 0; rg < 4; ++rg) {
            int m = mf*16 + kg*4 + rg;
            #pragma unroll
            for (int nf = 0; nf < 2; ++nf) {
                int t = wn + nf*16 + fr;
                yst[m*136 + t] = (_Float16)gelu_fast(acc3[mf][nf][rg]);
            }
        }
    }
    __syncthreads();
    {
        int r = tid >> 3, tc = (tid & 7) * 16;
        size_t gb = ((size_t)((b0 + (r>>4))*H + hh))*L + (r&15)*128;
        *(half8*)&y16[gb + tc]     = *(half8*)&yst[r*136 + tc];
        *(half8*)&y16[gb + tc + 8] = *(half8*)&yst[r*136 + tc + 8];
    }
}

// ---------------- GLU MFMA fp16 -> fp16 zc, coalesced epilogue; grid (B*L/128, 4) ----------------
__global__ __launch_bounds__(256) void k_glu16(const _Float16* __restrict__ yt,
        const _Float16* __restrict__ wg, const float* __restrict__ bias,
        _Float16* __restrict__ zc) {
    __shared__ _Float16 a_lds[128*32];
    __shared__ _Float16 b_lds[128*32];
    __shared__ float    ep[32*64];
    const int tid = threadIdx.x;
    const int mbase = blockIdx.x * 128;
    const int o0 = blockIdx.y * 64;
    const int lane = tid & 63;
    const int w = tid >> 6;
    const int wm = (w >> 1) * 64, wn = (w & 1) * 32;
    const int fr = lane & 15, kg = lane >> 4;
    const int r0s = tid >> 2, q0 = tid & 3;
    const int r1s = 64 + r0s;
    const int aw0 = r0s*32 + ((q0 ^ SWZ(r0s)) * 8);
    const int aw1 = r1s*32 + ((q0 ^ SWZ(r1s)) * 8);
    const int og0 = o0 + r0s;
    const int og1 = 256 + o0 + r0s;

    f32x4 accg[4][2], accs[4][2];
    #pragma unroll
    for (int i = 0; i < 4; ++i)
        #pragma unroll
        for (int j = 0; j < 2; ++j)
            #pragma unroll
            for (int k = 0; k < 4; ++k) { accg[i][j][k] = 0.f; accs[i][j][k] = 0.f; }

    uint4 pa0, pa1, pb0, pb1;
    auto loadstep = [&](int kc, uint4& a0, uint4& a1, uint4& b0, uint4& b1) {
        const int cb = kc*32 + q0*8;
        a0 = *(const uint4*)&yt[((size_t)(mbase + r0s))*256 + cb];
        a1 = *(const uint4*)&yt[((size_t)(mbase + r1s))*256 + cb];
        b0 = *(const uint4*)&wg[((size_t)og0)*256 + cb];
        b1 = *(const uint4*)&wg[((size_t)og1)*256 + cb];
    };
    loadstep(0, pa0, pa1, pb0, pb1);
    for (int kc = 0; kc < 8; ++kc) {
        __syncthreads();
        *(uint4*)&a_lds[aw0] = pa0;
        *(uint4*)&a_lds[aw1] = pa1;
        *(uint4*)&b_lds[aw0] = pb0;
        *(uint4*)&b_lds[aw1] = pb1;
        uint4 na0 = make_uint4(0,0,0,0), na1 = na0, nb0 = na0, nb1 = na0;
        if (kc < 7) loadstep(kc+1, na0, na1, nb0, nb1);
        __syncthreads();
        half8 af[4], bg[2], bs[2];
        #pragma unroll
        for (int mf = 0; mf < 4; ++mf) {
            int ra = wm + mf*16 + fr;
            af[mf] = *(const half8*)&a_lds[ra*32 + ((kg ^ SWZ(ra)) * 8)];
        }
        #pragma unroll
        for (int nf = 0; nf < 2; ++nf) {
            int rb = wn + nf*16 + fr;
            bg[nf] = *(const half8*)&b_lds[rb*32 + ((kg ^ SWZ(rb)) * 8)];
            int rb2 = 64 + rb;
            bs[nf] = *(const half8*)&b_lds[rb2*32 + ((kg ^ SWZ(rb2)) * 8)];
        }
        #pragma unroll
        for (int mf = 0; mf < 4; ++mf)
            #pragma unroll
            for (int nf = 0; nf < 2; ++nf) {
                accg[mf][nf] = __builtin_amdgcn_mfma_f32_16x16x32_f16(af[mf], bg[nf], accg[mf][nf], 0, 0, 0);
                accs[mf][nf] = __builtin_amdgcn_mfma_f32_16x16x32_f16(af[mf], bs[nf], accs[mf][nf], 0, 0, 0);
            }
        pa0 = na0; pa1 = na1; pb0 = nb0; pb1 = nb1;
    }
    float b0v[2], b1v[2];
    #pragma unroll
    for (int nf = 0; nf < 2; ++nf) {
        int o = o0 + wn + nf*16 + fr;
        b0v[nf] = bias[o]; b1v[nf] = bias[256 + o];
    }
    const int er = tid >> 3, eoc = (tid & 7) * 8;
    #pragma unroll
    for (int mf = 0; mf < 4; ++mf) {
        __syncthreads();
        #pragma unroll
        for (int nf = 0; nf < 2; ++nf) {
            int ol = wn + nf*16 + fr;
            int srb = (w >> 1)*16 + kg*4;
            #pragma unroll
            for (int rg = 0; rg < 4; ++rg) {
                float g = accg[mf][nf][rg] + b0v[nf];
                float s = accs[mf][nf][rg] + b1v[nf];
                ep[(srb + rg)*64 + ol] = g / (1.f + expf(-s));
            }
        }
        __syncthreads();
        size_t m = (size_t)mbase + mf*16 + (er < 16 ? er : 48 + er);
        float4 v0 = *(float4*)&ep[er*64 + eoc];
        float4 v1 = *(float4*)&ep[er*64 + eoc + 4];
        half8 hv;
        hv[0]=(_Float16)v0.x; hv[1]=(_Float16)v0.y; hv[2]=(_Float16)v0.z; hv[3]=(_Float16)v0.w;
        hv[4]=(_Float16)v1.x; hv[5]=(_Float16)v1.y; hv[6]=(_Float16)v1.z; hv[7]=(_Float16)v1.w;
        *(half8*)&zc[m*256 + o0 + eoc] = hv;
    }
}

// ---------------- LayerNorm: fp16 residual stream; last layer adds species + outseq f32 ----------------
template<bool SP>
__global__ __launch_bounds__(256) void k_ln2(const _Float16* __restrict__ zc,
        _Float16* __restrict__ hm, const float* __restrict__ g, const float* __restrict__ bb,
        const int* __restrict__ xs, const float* __restrict__ emb,
        float* __restrict__ outseq) {
    __shared__ float tl[8992];
    int tid = threadIdx.x;
    int b = blockIdx.y;
    int l0 = blockIdx.x * 32;
    for (int j = tid; j < 1024; j += 256) {
        int c = j >> 2, l8 = (j & 3) * 8;
        half8 v = *(const half8*)&hm[((size_t)(b*H + c))*L + l0 + l8];
        #pragma unroll
        for (int e = 0; e < 8; ++e) tl[LDIDX(l8 + e, c)] = (float)v[e];
    }
    __syncthreads();
    int r = tid >> 3, p = tid & 7;
    float v[32];
    float sum = 0.f, ss = 0.f;
    const _Float16* zrow = &zc[((size_t)(b*L + l0 + r))*256 + p*32];
    #pragma unroll
    for (int q = 0; q < 4; ++q) {
        half8 z8 = *(const half8*)&zrow[q*8];
        #pragma unroll
        for (int i = 0; i < 8; ++i) {
            float hv = tl[LDIDX(r, p*32 + q*8 + i)];
            float vv = (float)z8[i] + hv;
            v[q*8+i] = vv;
            sum += vv; ss = fmaf(vv, vv, ss);
        }
    }
    sum += __shfl_xor(sum, 1); ss += __shfl_xor(ss, 1);
    sum += __shfl_xor(sum, 2); ss += __shfl_xor(ss, 2);
    sum += __shfl_xor(sum, 4); ss += __shfl_xor(ss, 4);
    float mu = sum * (1.f/256.f);
    float var = ss * (1.f/256.f) - mu*mu;
    float rs = rsqrtf(var + 1e-5f);
    int sp = SP ? xs[b] : 0;
    #pragma unroll
    for (int q = 0; q < 32; ++q) {
        int c = p*32 + q;
        float val = (v[q] - mu) * rs * g[c] + bb[c];
        if (SP) val += emb[sp*H + c];
        tl[LDIDX(r, c)] = val;
    }
    __syncthreads();
    for (int j = tid; j < 1024; j += 256) {
        int c = j >> 2, l8 = (j & 3) * 8;
        float fv[8];
        half8 hv;
        #pragma unroll
        for (int e = 0; e < 8; ++e) {
            fv[e] = tl[LDIDX(l8 + e, c)];
            hv[e] = (_Float16)fv[e];
        }
        *(half8*)&hm[((size_t)(b*H + c))*L + l0 + l8] = hv;
        if (SP) {
            *(float4*)&outseq[((size_t)(b*H + c))*L + l0 + l8] = make_float4(fv[0],fv[1],fv[2],fv[3]);
            *(float4*)&outseq[((size_t)(b*H + c))*L + l0 + l8 + 4] = make_float4(fv[4],fv[5],fv[6],fv[7]);
        }
    }
}

// ---------------- MFMA decoder conv K=15 ----------------
__global__ __launch_bounds__(128) void k_dec(const _Float16* __restrict__ ht,
        const _Float16* __restrict__ wdk, const float* __restrict__ bias,
        float* __restrict__ outdec) {
    __shared__ _Float16 a_lds[160*32];
    __shared__ _Float16 b_lds[15*16*32];
    const int tid = threadIdx.x;
    const int mbase = blockIdx.x * 128;
    const int b = mbase >> 11;
    const int lbase = mbase & 2047;
    const int lane = tid & 63;
    const int w = tid >> 6;
    const int fr = lane & 15, kg = lane >> 4;
    const int rs = tid >> 2, q0 = tid & 3;
    f32x4 acc[4];
    #pragma unroll
    for (int i = 0; i < 4; ++i)
        #pragma unroll
        for (int k = 0; k < 4; ++k) acc[i][k] = 0.f;
    for (int cc = 0; cc < 8; ++cc) {
        __syncthreads();
        #pragma unroll
        for (int ps = 0; ps < 5; ++ps) {
            int r = ps*32 + rs;
            if (r < 142) {
                int l = lbase - 7 + r;
                uint4 v = (l >= 0 && l < L) ? *(const uint4*)&ht[((size_t)(b*L + l))*256 + cc*32 + q0*8]
                                            : make_uint4(0,0,0,0);
                *(uint4*)&a_lds[r*32 + ((q0 ^ SWZ(r))*8)] = v;
            }
        }
        for (int jj = tid; jj < 960; jj += 128)
            *(uint4*)&b_lds[jj*8] = *(const uint4*)&wdk[cc*7680 + jj*8];
        __syncthreads();
        #pragma unroll
        for (int k = 0; k < 15; ++k) {
            half8 bfr = *(const half8*)&b_lds[(k*16 + fr)*32 + ((kg ^ SWZ(fr))*8)];
            #pragma unroll
            for (int mf = 0; mf < 4; ++mf) {
                int ra = w*64 + mf*16 + fr + k;
                half8 af = *(const half8*)&a_lds[ra*32 + ((kg ^ SWZ(ra))*8)];
                acc[mf] = __builtin_amdgcn_mfma_f32_16x16x32_f16(af, bfr, acc[mf], 0, 0, 0);
            }
        }
    }
    if (fr < DOUT) {
        float bo = bias[fr];
        #pragma unroll
        for (int mf = 0; mf < 4; ++mf)
            #pragma unroll
            for (int rg = 0; rg < 4; ++rg) {
                int m = mbase + w*64 + mf*16 + kg*4 + rg;
                outdec[((size_t)(b*DOUT + fr))*L + (m & 2047)] = acc[mf][rg] + bo;
            }
    }
}

// ---------------- mean over L (fp16 input) ----------------
__global__ __launch_bounds__(256) void k_agg(const _Float16* __restrict__ h, float* __restrict__ agg) {
    __shared__ float red[256];
    int bc = blockIdx.x;
    int tid = threadIdx.x;
    half8 v = *(const half8*)&h[(size_t)bc*L + tid*8];
    float s = 0.f;
    #pragma unroll
    for (int e = 0; e < 8; ++e) s += (float)v[e];
    red[tid] = s; __syncthreads();
    for (int k = 128; k > 0; k >>= 1) {
        if (tid < k) red[tid] += red[tid+k];
        __syncthreads();
    }
    if (tid == 0) agg[bc] = red[0] * (1.f/(float)L);
}

// ---------------- regression MLP ----------------
__global__ __launch_bounds__(128) void k_mlp(const float* __restrict__ agg,
        const float* __restrict__ w1, const float* __restrict__ b1,
        const float* __restrict__ w2, const float* __restrict__ b2,
        const float* __restrict__ w3, const float* __restrict__ b3,
        const float* __restrict__ w4, const float* __restrict__ b4,
        float* __restrict__ outreg) {
    __shared__ float a0[256], r1[128], r2[64], r3[32];
    int b = blockIdx.x, tid = threadIdx.x;
    a0[tid] = agg[b*256 + tid];
    a0[tid+128] = agg[b*256 + tid + 128];
    __syncthreads();
    {
        float s = b1[tid];
        for (int k = 0; k < 256; ++k) s = fmaf(w1[tid*256+k], a0[k], s);
        r1[tid] = s > 0.f ? s : expm1f(s);
    }
    __syncthreads();
    if (tid < 64) {
        float s = b2[tid];
        for (int k = 0; k < 128; ++k) s = fmaf(w2[tid*128+k], r1[k], s);
        r2[tid] = s > 0.f ? s : expm1f(s);
    }
    __syncthreads();
    if (tid < 32) {
        float s = b3[tid];
        for (int k = 0; k < 64; ++k) s = fmaf(w3[tid*64+k], r2[k], s);
        r3[tid] = s > 0.f ? s : expm1f(s);
    }
    __syncthreads();
    if (tid == 0) {
        float s = b4[0];
        for (int k = 0; k < 32; ++k) s = fmaf(w4[k], r3[k], s);
        outreg[b] = s;
    }
}

extern "C" void kernel_launch(void* const* d_in, const int* in_sizes, int n_in,
                              void* d_out, int out_size, void* d_ws, size_t ws_size,
                              hipStream_t stream) {
    const float* x      = (const float*)d_in[0];
    const int*   xs     = (const int*)d_in[1];
    const float* enc_w  = (const float*)d_in[2];
    const float* enc_b  = (const float*)d_in[3];
    const float* res_w1 = (const float*)d_in[4];
    const float* res_b1 = (const float*)d_in[5];
    const float* res_w2 = (const float*)d_in[6];
    const float* res_b2 = (const float*)d_in[7];
    const float* log_dt = (const float*)d_in[8];
    const float* lam_re = (const float*)d_in[9];
    const float* lam_im = (const float*)d_in[10];
    const float* W_re   = (const float*)d_in[11];
    const float* W_im   = (const float*)d_in[12];
    const float* Dv     = (const float*)d_in[13];
    const float* glu_w  = (const float*)d_in[14];
    const float* glu_b  = (const float*)d_in[15];
    const float* ln_g   = (const float*)d_in[16];
    const float* ln_b   = (const float*)d_in[17];
    const float* dec_w  = (const float*)d_in[18];
    const float* dec_b  = (const float*)d_in[19];
    const float* sp_emb = (const float*)d_in[20];
    const float* h1_w = (const float*)d_in[21]; const float* h1_b = (const float*)d_in[22];
    const float* h2_w = (const float*)d_in[23]; const float* h2_b = (const float*)d_in[24];
    const float* h3_w = (const float*)d_in[25]; const float* h3_b = (const float*)d_in[26];
    const float* h4_w = (const float*)d_in[27]; const float* h4_b = (const float*)d_in[28];

    float* ws   = (float*)d_ws;
    _Float16* hm16 = (_Float16*)ws;                    // fp16 chm residual (32MB, ws lower)
    _Float16* zp_all = (_Float16*)(ws + (size_t)LSEQ/2); // ws upper 32MB: 4 x H*16384 fp16
    float* t1   = ws + (size_t)LSEQ;
    float* t2   = ws + (size_t)2*LSEQ;
    // res-phase:
    _Float16* xb  = (_Float16*)t1;
    _Float16* xa  = (_Float16*)t1 + (size_t)LSEQ;
    _Float16* wpk = (_Float16*)t2;
    // DSS-phase:
    _Float16* yt     = (_Float16*)t1;                  // fp16 chl y (t1 lower)
    _Float16* wbigA  = (_Float16*)t1 + (size_t)LSEQ;   // t1 upper 32MB: wbig layers 0,1
    _Float16* y16    = (_Float16*)t2;                  // fp16 chm y (t2 lower)
    _Float16* zc16   = (_Float16*)t2;                  // glu out (y16 dead)
    _Float16* wbigB  = (_Float16*)t2 + (size_t)LSEQ;   // t2 upper 32MB: wbig layers 2,3
    _Float16* dect   = (_Float16*)t1;                  // decoder chl input
    // tail:
    float* tail = ws + (size_t)3*LSEQ;
    _Float16* wg_all = (_Float16*)tail;                // 4*131072 fp16 = 1MB
    float4* zwb_all  = (float4*)(tail + 262144);       // 4*H*NST float4 = 512KB
    float* aggb = tail + 262144 + 131072;
    _Float16* wdk = (_Float16*)(aggb + 8192);
    _Float16* wenc = wdk + 61440;

    float* outdec = (float*)d_out;
    float* outseq = outdec + B*DOUT*L;
    float* outreg = outseq + (size_t)LSEQ;

    // encoder
    k_wenc<<<96, 256, 0, stream>>>(enc_w, wenc);
    k_enc<<<dim3(B*L/128, 2), 256, 0, stream>>>(x, wenc, enc_b, xa);

    // residual stack
    k_wpack<<<(NRES*2*3*65536 + 255)/256, 256, 0, stream>>>(res_w1, res_w2, wpk);
    for (int r = 0; r < NRES; ++r) {
        k_cv3<false><<<B*L/128, 256, 0, stream>>>(
            xa, wpk + (size_t)(r*2+0)*3*65536, res_b1 + r*H, nullptr, xb);
        k_cv3<true><<<B*L/128, 256, 0, stream>>>(
            xb, wpk + (size_t)(r*2+1)*3*65536, res_b2 + r*H, xa, xa);
    }
    k_t_cf16<<<dim3(L/64, H/64, B), 256, 0, stream>>>(xa, hm16);

    // all-layer DSS weight prep (one launch)
    k_wkern<<<dim3(H, NLAYERS), 128, 0, stream>>>(log_dt, lam_re, lam_im, W_re, W_im,
                                                  Dv, glu_w, wbigA, wbigB, wg_all,
                                                  zp_all, zwb_all);

    // DSS blocks
    for (int i = 0; i < NLAYERS; ++i) {
        _Float16* wbig_i = (i < 2) ? (wbigA + (size_t)i*H*32768)
                                   : (wbigB + (size_t)(i-2)*H*32768);
        k_dss<<<dim3(H, 16), 256, 0, stream>>>(hm16,
                zp_all + (size_t)i*H*16384, wbig_i,
                zwb_all + (size_t)i*H*NST, y16);
        k_t16<<<dim3(L/64, H/64, B), 256, 0, stream>>>(y16, yt);
        k_glu16<<<dim3(B*L/128, 4), 256, 0, stream>>>(yt, wg_all + (size_t)i*131072,
                                                      glu_b + i*512, zc16);
        if (i < NLAYERS - 1)
            k_ln2<false><<<dim3(L/32, B), 256, 0, stream>>>(zc16, hm16, ln_g + i*H, ln_b + i*H,
                                                            nullptr, nullptr, nullptr);
        else
            k_ln2<true><<<dim3(L/32, B), 256, 0, stream>>>(zc16, hm16, ln_g + i*H, ln_b + i*H,
                                                           xs, sp_emb, outseq);
    }

    // aggregate + regression head
    k_agg<<<B*H, 256, 0, stream>>>(hm16, aggb);
    k_mlp<<<B, 128, 0, stream>>>(aggb, h1_w, h1_b, h2_w, h2_b, h3_w, h3_b, h4_w, h4_b, outreg);
    // decoder
    k_t16<<<dim3(L/64, H/64, B), 256, 0, stream>>>(hm16, dect);
    k_wdec<<<(15*16*256 + 255)/256, 256, 0, stream>>>(dec_w, wdk);
    k_dec<<<B*L/128, 128, 0, stream>>>(dect, wdk, dec_b, outdec);
}

// Round 17
// 936.654 us; speedup vs baseline: 1.3303x; 1.0627x over previous
//
#include <hip/hip_runtime.h>
#include <math.h>

#define B 32
#define L 2048
#define DIN 5
#define DOUT 5
#define H 256
#define NST 32
#define NLAYERS 4
#define NRES 3
#define CHUNK 128
#define NCH 16            // L / CHUNK
#define LSEQ (B*H*L)      // 16777216

typedef __attribute__((ext_vector_type(8))) _Float16 half8;
typedef __attribute__((ext_vector_type(4))) float f32x4;

// A&S 7.1.26: |erf err| < 1.5e-7 -> gelu err ~1e-7, invisible vs fp16 rounding (5e-4)
__device__ __forceinline__ float gelu_fast(float v) {
    float x = v * 0.7071067811865475f;
    float ax = fabsf(x);
    float t = 1.f / fmaf(0.3275911f, ax, 1.f);
    float poly = t*(0.254829592f + t*(-0.284496736f + t*(1.421413741f +
                 t*(-1.453152027f + t*1.061405429f))));
    float e = __expf(-ax*ax);
    float erfv = copysignf(1.f - poly*e, x);
    return 0.5f * v * (1.f + erfv);
}
#define SWZ(r) ((((r) ^ ((r) >> 2)) & 3))
#define LDIDX(l, c) ((l)*281 + ((c)>>5)*35 + ((c)&31))

// ---------------- encoder weight pack ----------------
__global__ void k_wenc(const float* __restrict__ ew, _Float16* __restrict__ wenc) {
    int idx = blockIdx.x*256 + threadIdx.x;
    if (idx >= 256*96) return;
    int o = idx / 96, kk = idx % 96;
    int ci = kk >> 4, k = kk & 15;
    float v = (ci < DIN && k < 15) ? ew[(o*DIN + ci)*15 + k] : 0.f;
    wenc[idx] = (_Float16)v;
}

// ---------------- MFMA encoder conv K=15 Cin=5 ----------------
__global__ __launch_bounds__(256) void k_enc(const float* __restrict__ x,
        const _Float16* __restrict__ wenc, const float* __restrict__ bias,
        _Float16* __restrict__ out) {
    __shared__ _Float16 a_lds[3*128*32];
    __shared__ _Float16 b_lds[3*128*32];
    const int tid = threadIdx.x;
    const int mbase = blockIdx.x * 128;
    const int oh = blockIdx.y;
    const int b = mbase >> 11;
    const int lbase = mbase & 2047;
    const int lane = tid & 63;
    const int w = tid >> 6;
    const int wm = (w >> 1) * 64, wn = (w & 1) * 64;
    const int fr = lane & 15, kg = lane >> 4;

    #pragma unroll
    for (int i = 0; i < 6; ++i) {
        int g = i*256 + tid;
        int r = g / 12, rem = g % 12;
        int ks = rem >> 2, q = rem & 3;
        int kk0 = ks*32 + q*8;
        int ci = kk0 >> 4, k0 = kk0 & 15;
        half8 va;
        #pragma unroll
        for (int e = 0; e < 8; ++e) {
            int k = k0 + e;
            int l = lbase + r - 7 + k;
            float v = (ci < DIN && k < 15 && l >= 0 && l < L)
                        ? x[((size_t)(b*DIN + ci))*L + l] : 0.f;
            va[e] = (_Float16)v;
        }
        *(half8*)&a_lds[ks*4096 + r*32 + ((q ^ SWZ(r))*8)] = va;
        uint4 vb = *(const uint4*)&wenc[(size_t)(oh*128 + r)*96 + kk0];
        *(uint4*)&b_lds[ks*4096 + r*32 + ((q ^ SWZ(r))*8)] = vb;
    }
    __syncthreads();
    f32x4 acc[4][4];
    #pragma unroll
    for (int i = 0; i < 4; ++i)
        #pragma unroll
        for (int j = 0; j < 4; ++j)
            #pragma unroll
            for (int k = 0; k < 4; ++k) acc[i][j][k] = 0.f;
    #pragma unroll
    for (int ks = 0; ks < 3; ++ks) {
        half8 af[4], bfr[4];
        #pragma unroll
        for (int mf = 0; mf < 4; ++mf) {
            int ra = wm + mf*16 + fr;
            af[mf] = *(const half8*)&a_lds[ks*4096 + ra*32 + ((kg ^ SWZ(ra))*8)];
        }
        #pragma unroll
        for (int nf = 0; nf < 4; ++nf) {
            int rb = wn + nf*16 + fr;
            bfr[nf] = *(const half8*)&b_lds[ks*4096 + rb*32 + ((kg ^ SWZ(rb))*8)];
        }
        #pragma unroll
        for (int mf = 0; mf < 4; ++mf)
            #pragma unroll
            for (int nf = 0; nf < 4; ++nf)
                acc[mf][nf] = __builtin_amdgcn_mfma_f32_16x16x32_f16(af[mf], bfr[nf], acc[mf][nf], 0, 0, 0);
    }
    #pragma unroll
    for (int nf = 0; nf < 4; ++nf) {
        int o = oh*128 + wn + nf*16 + fr;
        float bo = bias[o];
        #pragma unroll
        for (int mf = 0; mf < 4; ++mf)
            #pragma unroll
            for (int rg = 0; rg < 4; ++rg) {
                size_t m = (size_t)mbase + wm + mf*16 + kg*4 + rg;
                out[m*256 + o] = (_Float16)(acc[mf][nf][rg] + bo);
            }
    }
}

// ---------------- res weight pack ----------------
__global__ void k_wpack(const float* __restrict__ w1, const float* __restrict__ w2,
                        _Float16* __restrict__ wpk) {
    int idx = blockIdx.x*256 + threadIdx.x;
    if (idx >= NRES*2*3*65536) return;
    int ci = idx & 255;
    int o  = (idx >> 8) & 255;
    int k  = (idx >> 16) % 3;
    int cv = idx / (3*65536);
    const float* src = (cv & 1) ? w2 : w1;
    wpk[idx] = (_Float16)src[(((cv>>1)*H + o)*H + ci)*3 + k];
}

// ---------------- transpose fp16 chl -> fp16 chm (half8 global both sides) ----------------
__global__ __launch_bounds__(256) void k_t_cf16(const _Float16* __restrict__ in,
        _Float16* __restrict__ out) {
    __shared__ float t[64][65];
    int tid = threadIdx.x;
    int l0 = blockIdx.x*64, c0 = blockIdx.y*64, b = blockIdx.z;
    #pragma unroll
    for (int i = 0; i < 2; ++i) {
        int g = i*256 + tid;
        int c8 = (g & 7) * 8, l = g >> 3;
        half8 v = *(const half8*)&in[((size_t)b*L + l0 + l)*256 + c0 + c8];
        #pragma unroll
        for (int e = 0; e < 8; ++e) t[c8 + e][l] = (float)v[e];
    }
    __syncthreads();
    #pragma unroll
    for (int i = 0; i < 2; ++i) {
        int g = i*256 + tid;
        int l8 = (g & 7) * 8, c = g >> 3;
        half8 hv;
        #pragma unroll
        for (int e = 0; e < 8; ++e) hv[e] = (_Float16)t[c][l8 + e];
        *(half8*)&out[((size_t)(b*H + c0 + c))*L + l0 + l8] = hv;
    }
}

// ---------------- transpose fp16 chm -> fp16 chl (half8 global both sides) ----------------
__global__ __launch_bounds__(256) void k_t16(const _Float16* __restrict__ in,
                                             _Float16* __restrict__ out) {
    __shared__ float t[64][65];
    int tid = threadIdx.x;
    int l0 = blockIdx.x*64, c0 = blockIdx.y*64, b = blockIdx.z;
    #pragma unroll
    for (int i = 0; i < 2; ++i) {
        int g = i*256 + tid;
        int l8 = (g & 7) * 8, c = g >> 3;
        half8 v = *(const half8*)&in[((size_t)(b*H + c0 + c))*L + l0 + l8];
        #pragma unroll
        for (int e = 0; e < 8; ++e) t[c][l8 + e] = (float)v[e];
    }
    __syncthreads();
    #pragma unroll
    for (int i = 0; i < 2; ++i) {
        int g = i*256 + tid;
        int c8 = (g & 7) * 8, l = g >> 3;
        half8 hv;
        #pragma unroll
        for (int e = 0; e < 8; ++e) hv[e] = (_Float16)t[c8 + e][l];
        *(half8*)&out[((size_t)b*L + l0 + l)*256 + c0 + c8] = hv;
    }
}

// ---------------- MFMA residual conv K=3: full-N tile 128m x 256o, coalesced epilogue ----------------
template<bool RESID>
__global__ __launch_bounds__(256, 2) void k_cv3(const _Float16* __restrict__ xin,
        const _Float16* __restrict__ wpk, const float* __restrict__ bias,
        const _Float16* __restrict__ resid, _Float16* __restrict__ out) {
    __shared__ _Float16 a_lds[128*32];
    __shared__ _Float16 b_lds[256*32];
    __shared__ float    ep[32*256];
    const int tid = threadIdx.x;
    const int mbase = blockIdx.x * 128;
    const int lane = tid & 63;
    const int w = tid >> 6;
    const int wm = (w >> 1) * 64, wo = (w & 1) * 128;
    const int fr = lane & 15, kg = lane >> 4;

    const int r0s = tid >> 2, q0 = tid & 3;
    const int sq = SWZ(r0s);
    const int awA0 = r0s*32 + ((q0 ^ sq) * 8);
    const int awA1 = (64 + r0s)*32 + ((q0 ^ SWZ(64 + r0s)) * 8);

    f32x4 acc[4][8];
    #pragma unroll
    for (int i = 0; i < 4; ++i)
        #pragma unroll
        for (int j = 0; j < 8; ++j)
            #pragma unroll
            for (int k = 0; k < 4; ++k) acc[i][j][k] = 0.f;

    uint4 pa0, pa1, pb[4];
    auto loadstep = [&](int kk, uint4& a0, uint4& a1, uint4 (&bb)[4]) {
        const int koff = kk >> 3, cic = kk & 7;
        const int cb = cic*32 + q0*8;
        {
            int m = mbase + r0s;
            int ll = (m & (L-1)) + koff - 1;
            a0 = (ll >= 0 && ll < L) ? *(const uint4*)&xin[((size_t)(m + koff - 1))*256 + cb]
                                     : make_uint4(0,0,0,0);
            int m1 = mbase + 64 + r0s;
            int l1 = (m1 & (L-1)) + koff - 1;
            a1 = (l1 >= 0 && l1 < L) ? *(const uint4*)&xin[((size_t)(m1 + koff - 1))*256 + cb]
                                     : make_uint4(0,0,0,0);
        }
        #pragma unroll
        for (int u = 0; u < 4; ++u)
            bb[u] = *(const uint4*)&wpk[((size_t)(koff*256 + u*64 + r0s))*256 + cb];
    };
    loadstep(0, pa0, pa1, pb);
    for (int kk = 0; kk < 24; ++kk) {
        __syncthreads();
        *(uint4*)&a_lds[awA0] = pa0;
        *(uint4*)&a_lds[awA1] = pa1;
        #pragma unroll
        for (int u = 0; u < 4; ++u)
            *(uint4*)&b_lds[(u*64 + r0s)*32 + ((q0 ^ sq)*8)] = pb[u];
        uint4 na0 = make_uint4(0,0,0,0), na1 = na0, nb[4] = {na0, na0, na0, na0};
        if (kk < 23) loadstep(kk+1, na0, na1, nb);
        __syncthreads();
        half8 af[4];
        #pragma unroll
        for (int mf = 0; mf < 4; ++mf) {
            int ra = wm + mf*16 + fr;
            af[mf] = *(const half8*)&a_lds[ra*32 + ((kg ^ SWZ(ra)) * 8)];
        }
        #pragma unroll
        for (int nf = 0; nf < 8; ++nf) {
            int rb = wo + nf*16 + fr;
            half8 bfr = *(const half8*)&b_lds[rb*32 + ((kg ^ SWZ(rb)) * 8)];
            #pragma unroll
            for (int mf = 0; mf < 4; ++mf)
                acc[mf][nf] = __builtin_amdgcn_mfma_f32_16x16x32_f16(af[mf], bfr, acc[mf][nf], 0, 0, 0);
        }
        pa0 = na0; pa1 = na1;
        #pragma unroll
        for (int u = 0; u < 4; ++u) pb[u] = nb[u];
    }
    float bo8[8];
    #pragma unroll
    for (int nf = 0; nf < 8; ++nf) bo8[nf] = bias[wo + nf*16 + fr];
    const int er = tid >> 3, eoc = (tid & 7) * 32;
    #pragma unroll
    for (int mf = 0; mf < 4; ++mf) {
        __syncthreads();
        #pragma unroll
        for (int nf = 0; nf < 8; ++nf) {
            int o = wo + nf*16 + fr;
            int srb = (w >> 1)*16 + kg*4;
            #pragma unroll
            for (int rg = 0; rg < 4; ++rg)
                ep[(srb + rg)*256 + o] = acc[mf][nf][rg] + bo8[nf];
        }
        __syncthreads();
        size_t m = (size_t)mbase + mf*16 + (er < 16 ? er : 48 + er);
        #pragma unroll
        for (int u = 0; u < 4; ++u) {
            float4 v0 = *(float4*)&ep[er*256 + eoc + u*8];
            float4 v1 = *(float4*)&ep[er*256 + eoc + u*8 + 4];
            float vv[8] = {v0.x, v0.y, v0.z, v0.w, v1.x, v1.y, v1.z, v1.w};
            if (RESID) {
                half8 rv = *(const half8*)&resid[m*256 + eoc + u*8];
                #pragma unroll
                for (int e = 0; e < 8; ++e) vv[e] += (float)rv[e];
            }
            half8 hv;
            #pragma unroll
            for (int e = 0; e < 8; ++e) hv[e] = (_Float16)fmaxf(vv[e], 0.f);
            *(half8*)&out[m*256 + eoc + u*8] = hv;
        }
    }
}

// ---------------- W_big + zp + zwb + wg for ALL layers: grid (H, NLAYERS), vectorized stores ----------------
__global__ __launch_bounds__(128) void k_wkern(const float* __restrict__ log_dt,
        const float* __restrict__ lam_re, const float* __restrict__ lam_im,
        const float* __restrict__ W_re, const float* __restrict__ W_im,
        const float* __restrict__ Dv, const float* __restrict__ gw,
        _Float16* __restrict__ wbigA, _Float16* __restrict__ wbigB,
        _Float16* __restrict__ wg_all,
        _Float16* __restrict__ zp_all, float4* __restrict__ zwb_all) {
    __shared__ float kf[128], kb[128];
    __shared__ _Float16 E16[128*130];
    const int hh = blockIdx.x;
    const int layer = blockIdx.y;
    const int t = threadIdx.x;
    float dt = expf(log_dt[layer*H + hh]);
    float skf = 0.f, skb = 0.f;
    for (int n = 0; n < 32; ++n) {
        float a  = dt * lam_re[layer*NST + n];
        float bi = dt * lam_im[layer*NST + n];
        float wfr = W_re[((layer*2+0)*H + hh)*NST + n];
        float wfi = W_im[((layer*2+0)*H + hh)*NST + n];
        float wbr = W_re[((layer*2+1)*H + hh)*NST + n];
        float wbi = W_im[((layer*2+1)*H + hh)*NST + n];
        float e0 = expf(a*t), s0, c0; sincosf(bi*t, &s0, &c0);
        float zr0 = e0*c0, zi0 = e0*s0;
        skf = fmaf(wfr, zr0, skf) - wfi*zi0;
        skb = fmaf(wbr, zr0, skb) - wbi*zi0;
        float e1 = expf(a*(t+1)), s1, c1; sincosf(bi*(t+1), &s1, &c1);
        float zr1 = e1*c1, zi1 = e1*s1;
        E16[t*130 + n]      = (_Float16)(wfr*zr1 - wfi*zi1);
        E16[t*130 + 32 + n] = (_Float16)(-(wfr*zi1 + wfi*zr1));
        float e2 = expf(a*(127-t)), s2, c2; sincosf(bi*(127-t), &s2, &c2);
        float zr2 = e2*c2, zi2 = e2*s2;
        E16[t*130 + 64 + n] = (_Float16)(wbr*zr2 - wbi*zi2);
        E16[t*130 + 96 + n] = (_Float16)(-(wbr*zi2 + wbi*zr2));
    }
    kf[t] = skf + ((t == 0) ? Dv[layer*H + hh] : 0.f);
    kb[t] = skb;
    __syncthreads();
    _Float16* dst = (layer < 2 ? wbigA + (size_t)layer*H*32768
                               : wbigB + (size_t)(layer-2)*H*32768)
                    + (size_t)hh*32768;
    // vectorized wbig store: 8 consecutive k per half8 (split at k=128 is 8-aligned)
    for (int g = t; g < 4096; g += 128) {
        int tt = g >> 5;
        int k0 = (g & 31) * 8;
        half8 hv;
        if (k0 < 128) {
            #pragma unroll
            for (int e = 0; e < 8; ++e) {
                int k = k0 + e;
                hv[e] = (_Float16)((k <= tt) ? kf[tt - k] : kb[k - tt - 1]);
            }
        } else {
            #pragma unroll
            for (int e = 0; e < 8; ++e)
                hv[e] = E16[tt*130 + (k0 - 128) + e];
        }
        *(half8*)&dst[g*8] = hv;
    }
    const float* gsrc = &gw[(size_t)layer*131072 + (size_t)hh*512];
    _Float16* gdst = &wg_all[(size_t)layer*131072 + (size_t)hh*512];
    {
        int j8 = t * 4;          // 128 threads x 4 = 512
        float4 v = *(const float4*)&gsrc[j8];
        _Float16 h4[4] = {(_Float16)v.x, (_Float16)v.y, (_Float16)v.z, (_Float16)v.w};
        *(uint2*)&gdst[j8] = *(uint2*)h4;
    }
    // zp + zwb (vectorized half8 stores, batched recurrence)
    {
        int dn = t >> 1, c = t & 1, dir = dn >> 5, n = dn & 31;
        float a  = dt * lam_re[layer*NST + n];
        float bi = dt * lam_im[layer*NST + n];
        float er = expf(a);
        float zre = er * cosf(bi), zim = er * sinf(bi);
        if (c == 0 && dir == 0) {
            float eC = expf(a * (float)CHUNK);
            float s, co; sincosf(bi * (float)CHUNK, &s, &co);
            zwb_all[layer*H*NST + hh*NST + n] = make_float4(zre, zim, eC*co, eC*s);
        }
        _Float16* zdst = &zp_all[(size_t)layer*H*16384 + (size_t)hh*16384 + t*128];
        float cr = 1.f, ci = 0.f;
        for (int p8 = 0; p8 < 128; p8 += 8) {
            half8 buf;
            #pragma unroll
            for (int e = 0; e < 8; ++e) {
                float val = c ? ci : cr;
                if (dir) buf[e] = (_Float16)val;
                else     buf[7 - e] = (_Float16)val;
                float nr = cr*zre - ci*zim;
                float ni = cr*zim + ci*zre;
                cr = nr; ci = ni;
            }
            if (dir) *(half8*)&zdst[p8] = buf;
            else     *(half8*)&zdst[120 - p8] = buf;
        }
    }
}

// ---------------- decoder weight pack ----------------
__global__ void k_wdec(const float* __restrict__ dw, _Float16* __restrict__ wdk) {
    int idx = blockIdx.x*256 + threadIdx.x;
    if (idx >= 15*16*256) return;
    int cfull = idx & 255;
    int o = (idx >> 8) & 15;
    int k = idx >> 12;
    float v = (o < DOUT) ? dw[(o*H + cfull)*15 + k] : 0.f;
    int cc = cfull >> 5, cl = cfull & 31;
    int cq = cl >> 3, cb = cl & 7;
    wdk[cc*7680 + (k*16 + o)*32 + ((cq ^ SWZ(o))*8) + cb] = (_Float16)v;
}

// ---------------- FUSED DSS v3: M=32 (grid H x 16), 40KB LDS, single-barrier dbuf ----------------
__global__ __launch_bounds__(256, 4) void k_dss(const _Float16* __restrict__ hm16,
        const _Float16* __restrict__ zp, const _Float16* __restrict__ wbig,
        const float4* __restrict__ zwb, _Float16* __restrict__ y16) {
    __shared__ _Float16 xbuf[4*32*32];
    __shared__ _Float16 bbuf[2*128*32];
    __shared__ float    sbuf[32*128];
    _Float16* sb16 = (_Float16*)sbuf;

    const int tid = threadIdx.x;
    const int hh = blockIdx.x;
    const int b0 = blockIdx.y * 2;
    const int lane = tid & 63;
    const int w = tid >> 6;
    const int wn = w * 32;
    const int fr = lane & 15, kg = lane >> 4;

    #pragma unroll
    for (int i = 0; i < 2; ++i) {
        int g = i*256 + tid;
        int m = g >> 4, gi = g & 15;
        int kc = gi >> 2, q = gi & 3;
        uint4 v = *(const uint4*)&hm16[((size_t)((b0 + (m>>4))*H + hh))*L
                                       + (m&15)*128 + kc*32 + q*8];
        *(uint4*)&xbuf[kc*1024 + m*32 + ((q ^ SWZ(m))*8)] = v;
    }

    // ---- phase 1: S = x . zp^T ----
    f32x4 acc1[2][2];
    #pragma unroll
    for (int i = 0; i < 2; ++i)
        #pragma unroll
        for (int j = 0; j < 2; ++j)
            #pragma unroll
            for (int k = 0; k < 4; ++k) acc1[i][j][k] = 0.f;
    const _Float16* zb = &zp[(size_t)hh*16384];
    const int gr0 = tid >> 2, gq0 = tid & 3;
    const int gr1 = 64 + gr0;
    const int bw0 = gr0*32 + ((gq0 ^ SWZ(gr0))*8);
    const int bw1 = gr1*32 + ((gq0 ^ SWZ(gr1))*8);
    uint4 pb0 = *(const uint4*)&zb[gr0*128 + gq0*8];
    uint4 pb1 = *(const uint4*)&zb[gr1*128 + gq0*8];
    *(uint4*)&bbuf[bw0] = pb0;
    *(uint4*)&bbuf[bw1] = pb1;
    pb0 = *(const uint4*)&zb[gr0*128 + 32 + gq0*8];
    pb1 = *(const uint4*)&zb[gr1*128 + 32 + gq0*8];
    __syncthreads();
    for (int kc = 0; kc < 4; ++kc) {
        if (kc < 3) {
            *(uint4*)&bbuf[((kc+1)&1)*4096 + bw0] = pb0;
            *(uint4*)&bbuf[((kc+1)&1)*4096 + bw1] = pb1;
            if (kc < 2) {
                pb0 = *(const uint4*)&zb[gr0*128 + (kc+2)*32 + gq0*8];
                pb1 = *(const uint4*)&zb[gr1*128 + (kc+2)*32 + gq0*8];
            }
        }
        half8 af[2], bf2[2];
        #pragma unroll
        for (int mf = 0; mf < 2; ++mf) {
            int ra = mf*16 + fr;
            af[mf] = *(const half8*)&xbuf[kc*1024 + ra*32 + ((kg ^ SWZ(ra))*8)];
        }
        #pragma unroll
        for (int nf = 0; nf < 2; ++nf) {
            int rb = wn + nf*16 + fr;
            bf2[nf] = *(const half8*)&bbuf[(kc&1)*4096 + rb*32 + ((kg ^ SWZ(rb))*8)];
        }
        #pragma unroll
        for (int mf = 0; mf < 2; ++mf)
            #pragma unroll
            for (int nf = 0; nf < 2; ++nf)
                acc1[mf][nf] = __builtin_amdgcn_mfma_f32_16x16x32_f16(af[mf], bf2[nf], acc1[mf][nf], 0, 0, 0);
        __syncthreads();
    }
    #pragma unroll
    for (int mf = 0; mf < 2; ++mf)
        #pragma unroll
        for (int nf = 0; nf < 2; ++nf)
            #pragma unroll
            for (int rg = 0; rg < 4; ++rg)
                sbuf[(mf*16 + kg*4 + rg)*128 + wn + nf*16 + fr] = acc1[mf][nf][rg];
    __syncthreads();

    // ---- phase 2: in-LDS cross-chunk scan ----
    {
        int b_loc = tid >> 6, dn = tid & 63;
        if (b_loc < 2) {
            int dir = dn >> 5, n = dn & 31;
            float4 z4 = zwb[hh*NST + n];
            float zcre = z4.z, zcim = z4.w;
            int q1 = n >> 3, e1 = n & 7;
            float pre = 0.f, pim = 0.f;
            for (int s = 0; s < NCH; ++s) {
                int ch = dir ? (NCH - 1 - s) : s;
                int m = b_loc*16 + ch;
                bbuf[(dir*2 + 0)*1024 + m*32 + ((q1 ^ SWZ(m))*8) + e1] = (_Float16)pre;
                bbuf[(dir*2 + 1)*1024 + m*32 + ((q1 ^ SWZ(m))*8) + e1] = (_Float16)pim;
                float cre = sbuf[m*128 + dn*2];
                float cim = sbuf[m*128 + dn*2 + 1];
                float nre = fmaf(zcre, pre, fmaf(-zcim, pim, cre));
                float nim = fmaf(zcre, pim, fmaf(zcim, pre, cim));
                pre = nre; pim = nim;
            }
        }
    }
    __syncthreads();

    // ---- phase 3: y = [x | stp] . wbig^T ----
    f32x4 acc3[2][2];
    #pragma unroll
    for (int i = 0; i < 2; ++i)
        #pragma unroll
        for (int j = 0; j < 2; ++j)
            #pragma unroll
            for (int k = 0; k < 4; ++k) acc3[i][j][k] = 0.f;
    const _Float16* wb = &wbig[(size_t)hh*32768];
    pb0 = *(const uint4*)&wb[gr0*256 + gq0*8];
    pb1 = *(const uint4*)&wb[gr1*256 + gq0*8];
    *(uint4*)&sb16[bw0] = pb0;
    *(uint4*)&sb16[bw1] = pb1;
    pb0 = *(const uint4*)&wb[gr0*256 + 32 + gq0*8];
    pb1 = *(const uint4*)&wb[gr1*256 + 32 + gq0*8];
    __syncthreads();
    for (int kc = 0; kc < 8; ++kc) {
        if (kc < 7) {
            *(uint4*)&sb16[((kc+1)&1)*4096 + bw0] = pb0;
            *(uint4*)&sb16[((kc+1)&1)*4096 + bw1] = pb1;
            if (kc < 6) {
                pb0 = *(const uint4*)&wb[gr0*256 + (kc+2)*32 + gq0*8];
                pb1 = *(const uint4*)&wb[gr1*256 + (kc+2)*32 + gq0*8];
            }
        }
        half8 af[2], bf2[2];
        #pragma unroll
        for (int mf = 0; mf < 2; ++mf) {
            int ra = mf*16 + fr;
            af[mf] = (kc < 4)
                ? *(const half8*)&xbuf[kc*1024 + ra*32 + ((kg ^ SWZ(ra))*8)]
                : *(const half8*)&bbuf[(kc-4)*1024 + ra*32 + ((kg ^ SWZ(ra))*8)];
        }
        #pragma unroll
        for (int nf = 0; nf < 2; ++nf) {
            int rb = wn + nf*16 + fr;
            bf2[nf] = *(const half8*)&sb16[(kc&1)*4096 + rb*32 + ((kg ^ SWZ(rb))*8)];
        }
        #pragma unroll
        for (int mf = 0; mf < 2; ++mf)
            #pragma unroll
            for (int nf = 0; nf < 2; ++nf)
                acc3[mf][nf] = __builtin_amdgcn_mfma_f32_16x16x32_f16(af[mf], bf2[nf], acc3[mf][nf], 0, 0, 0);
        __syncthreads();
    }
    _Float16* yst = sb16;
    #pragma unroll
    for (int mf = 0; mf < 2; ++mf) {
        #pragma unroll
        for (int rg = 0; rg < 4; ++rg) {
            int m = mf*16 + kg*4 + rg;
            #pragma unroll
            for (int nf = 0; nf < 2; ++nf) {
                int t = wn + nf*16 + fr;
                yst[m*136 + t] = (_Float16)gelu_fast(acc3[mf][nf][rg]);
            }
        }
    }
    __syncthreads();
    {
        int r = tid >> 3, tc = (tid & 7) * 16;
        size_t gb = ((size_t)((b0 + (r>>4))*H + hh))*L + (r&15)*128;
        *(half8*)&y16[gb + tc]     = *(half8*)&yst[r*136 + tc];
        *(half8*)&y16[gb + tc + 8] = *(half8*)&yst[r*136 + tc + 8];
    }
}

// ---------------- GLU MFMA fp16 -> fp16 zc, coalesced epilogue; grid (B*L/128, 4) ----------------
__global__ __launch_bounds__(256) void k_glu16(const _Float16* __restrict__ yt,
        const _Float16* __restrict__ wg, const float* __restrict__ bias,
        _Float16* __restrict__ zc) {
    __shared__ _Float16 a_lds[128*32];
    __shared__ _Float16 b_lds[128*32];
    __shared__ float    ep[32*64];
    const int tid = threadIdx.x;
    const int mbase = blockIdx.x * 128;
    const int o0 = blockIdx.y * 64;
    const int lane = tid & 63;
    const int w = tid >> 6;
    const int wm = (w >> 1) * 64, wn = (w & 1) * 32;
    const int fr = lane & 15, kg = lane >> 4;
    const int r0s = tid >> 2, q0 = tid & 3;
    const int r1s = 64 + r0s;
    const int aw0 = r0s*32 + ((q0 ^ SWZ(r0s)) * 8);
    const int aw1 = r1s*32 + ((q0 ^ SWZ(r1s)) * 8);
    const int og0 = o0 + r0s;
    const int og1 = 256 + o0 + r0s;

    f32x4 accg[4][2], accs[4][2];
    #pragma unroll
    for (int i = 0; i < 4; ++i)
        #pragma unroll
        for (int j = 0; j < 2; ++j)
            #pragma unroll
            for (int k = 0; k < 4; ++k) { accg[i][j][k] = 0.f; accs[i][j][k] = 0.f; }

    uint4 pa0, pa1, pb0, pb1;
    auto loadstep = [&](int kc, uint4& a0, uint4& a1, uint4& b0, uint4& b1) {
        const int cb = kc*32 + q0*8;
        a0 = *(const uint4*)&yt[((size_t)(mbase + r0s))*256 + cb];
        a1 = *(const uint4*)&yt[((size_t)(mbase + r1s))*256 + cb];
        b0 = *(const uint4*)&wg[((size_t)og0)*256 + cb];
        b1 = *(const uint4*)&wg[((size_t)og1)*256 + cb];
    };
    loadstep(0, pa0, pa1, pb0, pb1);
    for (int kc = 0; kc < 8; ++kc) {
        __syncthreads();
        *(uint4*)&a_lds[aw0] = pa0;
        *(uint4*)&a_lds[aw1] = pa1;
        *(uint4*)&b_lds[aw0] = pb0;
        *(uint4*)&b_lds[aw1] = pb1;
        uint4 na0 = make_uint4(0,0,0,0), na1 = na0, nb0 = na0, nb1 = na0;
        if (kc < 7) loadstep(kc+1, na0, na1, nb0, nb1);
        __syncthreads();
        half8 af[4], bg[2], bs[2];
        #pragma unroll
        for (int mf = 0; mf < 4; ++mf) {
            int ra = wm + mf*16 + fr;
            af[mf] = *(const half8*)&a_lds[ra*32 + ((kg ^ SWZ(ra)) * 8)];
        }
        #pragma unroll
        for (int nf = 0; nf < 2; ++nf) {
            int rb = wn + nf*16 + fr;
            bg[nf] = *(const half8*)&b_lds[rb*32 + ((kg ^ SWZ(rb)) * 8)];
            int rb2 = 64 + rb;
            bs[nf] = *(const half8*)&b_lds[rb2*32 + ((kg ^ SWZ(rb2)) * 8)];
        }
        #pragma unroll
        for (int mf = 0; mf < 4; ++mf)
            #pragma unroll
            for (int nf = 0; nf < 2; ++nf) {
                accg[mf][nf] = __builtin_amdgcn_mfma_f32_16x16x32_f16(af[mf], bg[nf], accg[mf][nf], 0, 0, 0);
                accs[mf][nf] = __builtin_amdgcn_mfma_f32_16x16x32_f16(af[mf], bs[nf], accs[mf][nf], 0, 0, 0);
            }
        pa0 = na0; pa1 = na1; pb0 = nb0; pb1 = nb1;
    }
    float b0v[2], b1v[2];
    #pragma unroll
    for (int nf = 0; nf < 2; ++nf) {
        int o = o0 + wn + nf*16 + fr;
        b0v[nf] = bias[o]; b1v[nf] = bias[256 + o];
    }
    const int er = tid >> 3, eoc = (tid & 7) * 8;
    #pragma unroll
    for (int mf = 0; mf < 4; ++mf) {
        __syncthreads();
        #pragma unroll
        for (int nf = 0; nf < 2; ++nf) {
            int ol = wn + nf*16 + fr;
            int srb = (w >> 1)*16 + kg*4;
            #pragma unroll
            for (int rg = 0; rg < 4; ++rg) {
                float g = accg[mf][nf][rg] + b0v[nf];
                float s = accs[mf][nf][rg] + b1v[nf];
                ep[(srb + rg)*64 + ol] = g / (1.f + expf(-s));
            }
        }
        __syncthreads();
        size_t m = (size_t)mbase + mf*16 + (er < 16 ? er : 48 + er);
        float4 v0 = *(float4*)&ep[er*64 + eoc];
        float4 v1 = *(float4*)&ep[er*64 + eoc + 4];
        half8 hv;
        hv[0]=(_Float16)v0.x; hv[1]=(_Float16)v0.y; hv[2]=(_Float16)v0.z; hv[3]=(_Float16)v0.w;
        hv[4]=(_Float16)v1.x; hv[5]=(_Float16)v1.y; hv[6]=(_Float16)v1.z; hv[7]=(_Float16)v1.w;
        *(half8*)&zc[m*256 + o0 + eoc] = hv;
    }
}

// ---------------- LayerNorm: fp16 residual stream; last layer adds species + outseq f32 ----------------
template<bool SP>
__global__ __launch_bounds__(256) void k_ln2(const _Float16* __restrict__ zc,
        _Float16* __restrict__ hm, const float* __restrict__ g, const float* __restrict__ bb,
        const int* __restrict__ xs, const float* __restrict__ emb,
        float* __restrict__ outseq) {
    __shared__ float tl[8992];
    int tid = threadIdx.x;
    int b = blockIdx.y;
    int l0 = blockIdx.x * 32;
    for (int j = tid; j < 1024; j += 256) {
        int c = j >> 2, l8 = (j & 3) * 8;
        half8 v = *(const half8*)&hm[((size_t)(b*H + c))*L + l0 + l8];
        #pragma unroll
        for (int e = 0; e < 8; ++e) tl[LDIDX(l8 + e, c)] = (float)v[e];
    }
    __syncthreads();
    int r = tid >> 3, p = tid & 7;
    float v[32];
    float sum = 0.f, ss = 0.f;
    const _Float16* zrow = &zc[((size_t)(b*L + l0 + r))*256 + p*32];
    #pragma unroll
    for (int q = 0; q < 4; ++q) {
        half8 z8 = *(const half8*)&zrow[q*8];
        #pragma unroll
        for (int i = 0; i < 8; ++i) {
            float hv = tl[LDIDX(r, p*32 + q*8 + i)];
            float vv = (float)z8[i] + hv;
            v[q*8+i] = vv;
            sum += vv; ss = fmaf(vv, vv, ss);
        }
    }
    sum += __shfl_xor(sum, 1); ss += __shfl_xor(ss, 1);
    sum += __shfl_xor(sum, 2); ss += __shfl_xor(ss, 2);
    sum += __shfl_xor(sum, 4); ss += __shfl_xor(ss, 4);
    float mu = sum * (1.f/256.f);
    float var = ss * (1.f/256.f) - mu*mu;
    float rs = rsqrtf(var + 1e-5f);
    int sp = SP ? xs[b] : 0;
    #pragma unroll
    for (int q = 0; q < 32; ++q) {
        int c = p*32 + q;
        float val = (v[q] - mu) * rs * g[c] + bb[c];
        if (SP) val += emb[sp*H + c];
        tl[LDIDX(r, c)] = val;
    }
    __syncthreads();
    for (int j = tid; j < 1024; j += 256) {
        int c = j >> 2, l8 = (j & 3) * 8;
        float fv[8];
        half8 hv;
        #pragma unroll
        for (int e = 0; e < 8; ++e) {
            fv[e] = tl[LDIDX(l8 + e, c)];
            hv[e] = (_Float16)fv[e];
        }
        *(half8*)&hm[((size_t)(b*H + c))*L + l0 + l8] = hv;
        if (SP) {
            *(float4*)&outseq[((size_t)(b*H + c))*L + l0 + l8] = make_float4(fv[0],fv[1],fv[2],fv[3]);
            *(float4*)&outseq[((size_t)(b*H + c))*L + l0 + l8 + 4] = make_float4(fv[4],fv[5],fv[6],fv[7]);
        }
    }
}

// ---------------- MFMA decoder conv K=15 ----------------
__global__ __launch_bounds__(128) void k_dec(const _Float16* __restrict__ ht,
        const _Float16* __restrict__ wdk, const float* __restrict__ bias,
        float* __restrict__ outdec) {
    __shared__ _Float16 a_lds[160*32];
    __shared__ _Float16 b_lds[15*16*32];
    const int tid = threadIdx.x;
    const int mbase = blockIdx.x * 128;
    const int b = mbase >> 11;
    const int lbase = mbase & 2047;
    const int lane = tid & 63;
    const int w = tid >> 6;
    const int fr = lane & 15, kg = lane >> 4;
    const int rs = tid >> 2, q0 = tid & 3;
    f32x4 acc[4];
    #pragma unroll
    for (int i = 0; i < 4; ++i)
        #pragma unroll
        for (int k = 0; k < 4; ++k) acc[i][k] = 0.f;
    for (int cc = 0; cc < 8; ++cc) {
        __syncthreads();
        #pragma unroll
        for (int ps = 0; ps < 5; ++ps) {
            int r = ps*32 + rs;
            if (r < 142) {
                int l = lbase - 7 + r;
                uint4 v = (l >= 0 && l < L) ? *(const uint4*)&ht[((size_t)(b*L + l))*256 + cc*32 + q0*8]
                                            : make_uint4(0,0,0,0);
                *(uint4*)&a_lds[r*32 + ((q0 ^ SWZ(r))*8)] = v;
            }
        }
        for (int jj = tid; jj < 960; jj += 128)
            *(uint4*)&b_lds[jj*8] = *(const uint4*)&wdk[cc*7680 + jj*8];
        __syncthreads();
        #pragma unroll
        for (int k = 0; k < 15; ++k) {
            half8 bfr = *(const half8*)&b_lds[(k*16 + fr)*32 + ((kg ^ SWZ(fr))*8)];
            #pragma unroll
            for (int mf = 0; mf < 4; ++mf) {
                int ra = w*64 + mf*16 + fr + k;
                half8 af = *(const half8*)&a_lds[ra*32 + ((kg ^ SWZ(ra))*8)];
                acc[mf] = __builtin_amdgcn_mfma_f32_16x16x32_f16(af, bfr, acc[mf], 0, 0, 0);
            }
        }
    }
    if (fr < DOUT) {
        float bo = bias[fr];
        #pragma unroll
        for (int mf = 0; mf < 4; ++mf)
            #pragma unroll
            for (int rg = 0; rg < 4; ++rg) {
                int m = mbase + w*64 + mf*16 + kg*4 + rg;
                outdec[((size_t)(b*DOUT + fr))*L + (m & 2047)] = acc[mf][rg] + bo;
            }
    }
}

// ---------------- mean over L (fp16 input) ----------------
__global__ __launch_bounds__(256) void k_agg(const _Float16* __restrict__ h, float* __restrict__ agg) {
    __shared__ float red[256];
    int bc = blockIdx.x;
    int tid = threadIdx.x;
    half8 v = *(const half8*)&h[(size_t)bc*L + tid*8];
    float s = 0.f;
    #pragma unroll
    for (int e = 0; e < 8; ++e) s += (float)v[e];
    red[tid] = s; __syncthreads();
    for (int k = 128; k > 0; k >>= 1) {
        if (tid < k) red[tid] += red[tid+k];
        __syncthreads();
    }
    if (tid == 0) agg[bc] = red[0] * (1.f/(float)L);
}

// ---------------- regression MLP ----------------
__global__ __launch_bounds__(128) void k_mlp(const float* __restrict__ agg,
        const float* __restrict__ w1, const float* __restrict__ b1,
        const float* __restrict__ w2, const float* __restrict__ b2,
        const float* __restrict__ w3, const float* __restrict__ b3,
        const float* __restrict__ w4, const float* __restrict__ b4,
        float* __restrict__ outreg) {
    __shared__ float a0[256], r1[128], r2[64], r3[32];
    int b = blockIdx.x, tid = threadIdx.x;
    a0[tid] = agg[b*256 + tid];
    a0[tid+128] = agg[b*256 + tid + 128];
    __syncthreads();
    {
        float s = b1[tid];
        for (int k = 0; k < 256; ++k) s = fmaf(w1[tid*256+k], a0[k], s);
        r1[tid] = s > 0.f ? s : expm1f(s);
    }
    __syncthreads();
    if (tid < 64) {
        float s = b2[tid];
        for (int k = 0; k < 128; ++k) s = fmaf(w2[tid*128+k], r1[k], s);
        r2[tid] = s > 0.f ? s : expm1f(s);
    }
    __syncthreads();
    if (tid < 32) {
        float s = b3[tid];
        for (int k = 0; k < 64; ++k) s = fmaf(w3[tid*64+k], r2[k], s);
        r3[tid] = s > 0.f ? s : expm1f(s);
    }
    __syncthreads();
    if (tid == 0) {
        float s = b4[0];
        for (int k = 0; k < 32; ++k) s = fmaf(w4[k], r3[k], s);
        outreg[b] = s;
    }
}

extern "C" void kernel_launch(void* const* d_in, const int* in_sizes, int n_in,
                              void* d_out, int out_size, void* d_ws, size_t ws_size,
                              hipStream_t stream) {
    const float* x      = (const float*)d_in[0];
    const int*   xs     = (const int*)d_in[1];
    const float* enc_w  = (const float*)d_in[2];
    const float* enc_b  = (const float*)d_in[3];
    const float* res_w1 = (const float*)d_in[4];
    const float* res_b1 = (const float*)d_in[5];
    const float* res_w2 = (const float*)d_in[6];
    const float* res_b2 = (const float*)d_in[7];
    const float* log_dt = (const float*)d_in[8];
    const float* lam_re = (const float*)d_in[9];
    const float* lam_im = (const float*)d_in[10];
    const float* W_re   = (const float*)d_in[11];
    const float* W_im   = (const float*)d_in[12];
    const float* Dv     = (const float*)d_in[13];
    const float* glu_w  = (const float*)d_in[14];
    const float* glu_b  = (const float*)d_in[15];
    const float* ln_g   = (const float*)d_in[16];
    const float* ln_b   = (const float*)d_in[17];
    const float* dec_w  = (const float*)d_in[18];
    const float* dec_b  = (const float*)d_in[19];
    const float* sp_emb = (const float*)d_in[20];
    const float* h1_w = (const float*)d_in[21]; const float* h1_b = (const float*)d_in[22];
    const float* h2_w = (const float*)d_in[23]; const float* h2_b = (const float*)d_in[24];
    const float* h3_w = (const float*)d_in[25]; const float* h3_b = (const float*)d_in[26];
    const float* h4_w = (const float*)d_in[27]; const float* h4_b = (const float*)d_in[28];

    float* ws   = (float*)d_ws;
    _Float16* hm16 = (_Float16*)ws;                    // fp16 chm residual (32MB, ws lower)
    _Float16* zp_all = (_Float16*)(ws + (size_t)LSEQ/2); // ws upper 32MB: 4 x H*16384 fp16
    float* t1   = ws + (size_t)LSEQ;
    float* t2   = ws + (size_t)2*LSEQ;
    // res-phase:
    _Float16* xb  = (_Float16*)t1;
    _Float16* xa  = (_Float16*)t1 + (size_t)LSEQ;
    _Float16* wpk = (_Float16*)t2;
    // DSS-phase:
    _Float16* yt     = (_Float16*)t1;                  // fp16 chl y (t1 lower)
    _Float16* wbigA  = (_Float16*)t1 + (size_t)LSEQ;   // t1 upper 32MB: wbig layers 0,1
    _Float16* y16    = (_Float16*)t2;                  // fp16 chm y (t2 lower)
    _Float16* zc16   = (_Float16*)t2;                  // glu out (y16 dead)
    _Float16* wbigB  = (_Float16*)t2 + (size_t)LSEQ;   // t2 upper 32MB: wbig layers 2,3
    _Float16* dect   = (_Float16*)t1;                  // decoder chl input
    // tail:
    float* tail = ws + (size_t)3*LSEQ;
    _Float16* wg_all = (_Float16*)tail;                // 4*131072 fp16 = 1MB
    float4* zwb_all  = (float4*)(tail + 262144);       // 4*H*NST float4 = 512KB
    float* aggb = tail + 262144 + 131072;
    _Float16* wdk = (_Float16*)(aggb + 8192);
    _Float16* wenc = wdk + 61440;

    float* outdec = (float*)d_out;
    float* outseq = outdec + B*DOUT*L;
    float* outreg = outseq + (size_t)LSEQ;

    // encoder
    k_wenc<<<96, 256, 0, stream>>>(enc_w, wenc);
    k_enc<<<dim3(B*L/128, 2), 256, 0, stream>>>(x, wenc, enc_b, xa);

    // residual stack
    k_wpack<<<(NRES*2*3*65536 + 255)/256, 256, 0, stream>>>(res_w1, res_w2, wpk);
    for (int r = 0; r < NRES; ++r) {
        k_cv3<false><<<B*L/128, 256, 0, stream>>>(
            xa, wpk + (size_t)(r*2+0)*3*65536, res_b1 + r*H, nullptr, xb);
        k_cv3<true><<<B*L/128, 256, 0, stream>>>(
            xb, wpk + (size_t)(r*2+1)*3*65536, res_b2 + r*H, xa, xa);
    }
    k_t_cf16<<<dim3(L/64, H/64, B), 256, 0, stream>>>(xa, hm16);

    // all-layer DSS weight prep (one launch, vectorized stores)
    k_wkern<<<dim3(H, NLAYERS), 128, 0, stream>>>(log_dt, lam_re, lam_im, W_re, W_im,
                                                  Dv, glu_w, wbigA, wbigB, wg_all,
                                                  zp_all, zwb_all);

    // DSS blocks
    for (int i = 0; i < NLAYERS; ++i) {
        _Float16* wbig_i = (i < 2) ? (wbigA + (size_t)i*H*32768)
                                   : (wbigB + (size_t)(i-2)*H*32768);
        k_dss<<<dim3(H, 16), 256, 0, stream>>>(hm16,
                zp_all + (size_t)i*H*16384, wbig_i,
                zwb_all + (size_t)i*H*NST, y16);
        k_t16<<<dim3(L/64, H/64, B), 256, 0, stream>>>(y16, yt);
        k_glu16<<<dim3(B*L/128, 4), 256, 0, stream>>>(yt, wg_all + (size_t)i*131072,
                                                      glu_b + i*512, zc16);
        if (i < NLAYERS - 1)
            k_ln2<false><<<dim3(L/32, B), 256, 0, stream>>>(zc16, hm16, ln_g + i*H, ln_b + i*H,
                                                            nullptr, nullptr, nullptr);
        else
            k_ln2<true><<<dim3(L/32, B), 256, 0, stream>>>(zc16, hm16, ln_g + i*H, ln_b + i*H,
                                                           xs, sp_emb, outseq);
    }

    // aggregate + regression head
    k_agg<<<B*H, 256, 0, stream>>>(hm16, aggb);
    k_mlp<<<B, 128, 0, stream>>>(aggb, h1_w, h1_b, h2_w, h2_b, h3_w, h3_b, h4_w, h4_b, outreg);
    // decoder
    k_t16<<<dim3(L/64, H/64, B), 256, 0, stream>>>(hm16, dect);
    k_wdec<<<(15*16*256 + 255)/256, 256, 0, stream>>>(dec_w, wdk);
    k_dec<<<B*L/128, 128, 0, stream>>>(dect, wdk, dec_b, outdec);
}